// Round 6
// baseline (672.747 us; speedup 1.0000x reference)
//
#include <hip/hip_runtime.h>

// ---------------- constants ----------------
#define B_ 4
#define Hh_ 32
#define Ww_ 32
#define L_ 1024
#define HID_ 512
#define DI_ 1024
#define N_ 64
#define R_ 32
#define K_ 4
#define MLP_ 2048

typedef __bf16 bf16x8 __attribute__((ext_vector_type(8)));
typedef float f32x4 __attribute__((ext_vector_type(4)));
typedef float v2f __attribute__((ext_vector_type(2)));

__device__ __forceinline__ unsigned short f2bf(float f) {
  unsigned int u = __builtin_bit_cast(unsigned int, f);
  return (unsigned short)((u + 0x7FFFu + ((u >> 16) & 1u)) >> 16);
}
__device__ __forceinline__ float bf2f(unsigned short h) {
  return __builtin_bit_cast(float, (unsigned int)h << 16);
}

// quad_perm DPP add: x + x[lane ^ (1 or 2)] on the VALU pipe (no DS)
template <int CTRL>
__device__ __forceinline__ float dpp_qadd(float x) {
  int i = __builtin_bit_cast(int, x);
  int j = __builtin_amdgcn_update_dpp(i, i, CTRL, 0xF, 0xF, false);
  return x + __builtin_bit_cast(float, j);
}

// ---------------- transpose + cast weights: src (K,N) f32 -> dst (N,K) bf16 ----------------
__global__ __launch_bounds__(256) void transpose_cast(
    const float* __restrict__ src, unsigned short* __restrict__ dst, int K, int N) {
  __shared__ float t[32][33];
  int nb = blockIdx.x * 32, kb = blockIdx.y * 32;
  int tx = threadIdx.x & 31, ty = threadIdx.x >> 5;
  for (int r = ty; r < 32; r += 8) t[r][tx] = src[(size_t)(kb + r) * N + nb + tx];
  __syncthreads();
  for (int r = ty; r < 32; r += 8) dst[(size_t)(nb + r) * K + kb + tx] = f2bf(t[tx][r]);
}

// ---------------- LayerNorm over 512, wave per row; grid.y selects (in,out) pair ----------------
__global__ __launch_bounds__(256) void ln_kernel(
    const float* __restrict__ in0, float* __restrict__ out0,
    const float* __restrict__ in1, float* __restrict__ out1,
    const float* __restrict__ w, const float* __restrict__ bb) {
  const float* in = blockIdx.y ? in1 : in0;
  float* out = blockIdx.y ? out1 : out0;
  int row = blockIdx.x * 4 + (threadIdx.x >> 6);
  int lane = threadIdx.x & 63;
  const float* p = in + (size_t)row * HID_;
  float4 v0 = *(const float4*)(p + lane * 4);
  float4 v1 = *(const float4*)(p + 256 + lane * 4);
  float s = v0.x + v0.y + v0.z + v0.w + v1.x + v1.y + v1.z + v1.w;
  float q = v0.x * v0.x + v0.y * v0.y + v0.z * v0.z + v0.w * v0.w +
            v1.x * v1.x + v1.y * v1.y + v1.z * v1.z + v1.w * v1.w;
  #pragma unroll
  for (int m = 1; m < 64; m <<= 1) { s += __shfl_xor(s, m, 64); q += __shfl_xor(q, m, 64); }
  float mean = s * (1.f / 512.f);
  float var = q * (1.f / 512.f) - mean * mean;
  float rstd = rsqrtf(var + 1e-5f);
  float4 w0 = *(const float4*)(w + lane * 4);
  float4 w1 = *(const float4*)(w + 256 + lane * 4);
  float4 b0 = *(const float4*)(bb + lane * 4);
  float4 b1 = *(const float4*)(bb + 256 + lane * 4);
  float* o = out + (size_t)row * HID_;
  float4 r0, r1;
  r0.x = (v0.x - mean) * rstd * w0.x + b0.x;
  r0.y = (v0.y - mean) * rstd * w0.y + b0.y;
  r0.z = (v0.z - mean) * rstd * w0.z + b0.z;
  r0.w = (v0.w - mean) * rstd * w0.w + b0.w;
  r1.x = (v1.x - mean) * rstd * w1.x + b1.x;
  r1.y = (v1.y - mean) * rstd * w1.y + b1.y;
  r1.z = (v1.z - mean) * rstd * w1.z + b1.z;
  r1.w = (v1.w - mean) * rstd * w1.w + b1.w;
  *(float4*)(o + lane * 4) = r0;
  *(float4*)(o + 256 + lane * 4) = r1;
}

// ---------------- MFMA GEMM 128x128: A (M,K) f32, BT (N,K) bf16, C (M,N) f32 ----------------
// EPI: 0 = plain, 1 = +resid, 2 = +bias then exact gelu, 3 = +bias +resid
#define BM 128
#define BN 128
#define BK 32
#define LST 40  // LDS row stride in bf16 units

template <int EPI>
__global__ __launch_bounds__(256) void gemm_kernel(
    const float* __restrict__ A, const unsigned short* __restrict__ BT,
    float* __restrict__ C, int M, int N, int K,
    const float* __restrict__ bias, const float* __restrict__ resid) {
  __shared__ __align__(16) unsigned short As[BM * LST];
  __shared__ __align__(16) unsigned short Bs[BN * LST];
  int tid = threadIdx.x;
  int lane = tid & 63, wv = tid >> 6;
  int wm = wv >> 1, wn = wv & 1;
  int m0 = blockIdx.y * BM, n0 = blockIdx.x * BN;
  f32x4 acc[4][4] = {};
  int sr = tid >> 3, sc = (tid & 7) * 4;
  int kk = (lane >> 4) * 8;
  int rA = wm * 64 + (lane & 15);
  int rB = wn * 64 + (lane & 15);
  for (int k0 = 0; k0 < K; k0 += BK) {
    __syncthreads();
    #pragma unroll
    for (int p = 0; p < 4; ++p) {
      int r = sr + p * 32;
      float4 av = *(const float4*)(A + (size_t)(m0 + r) * K + k0 + sc);
      unsigned int lo = (unsigned int)f2bf(av.x) | ((unsigned int)f2bf(av.y) << 16);
      unsigned int hi = (unsigned int)f2bf(av.z) | ((unsigned int)f2bf(av.w) << 16);
      *(uint2*)&As[r * LST + sc] = make_uint2(lo, hi);
      uint2 bv = *(const uint2*)(BT + (size_t)(n0 + r) * K + k0 + sc);
      *(uint2*)&Bs[r * LST + sc] = bv;
    }
    __syncthreads();
    bf16x8 fa[4], fb[4];
    #pragma unroll
    for (int i = 0; i < 4; ++i) {
      fa[i] = *(const bf16x8*)&As[(rA + i * 16) * LST + kk];
      fb[i] = *(const bf16x8*)&Bs[(rB + i * 16) * LST + kk];
    }
    #pragma unroll
    for (int i = 0; i < 4; ++i)
      #pragma unroll
      for (int j = 0; j < 4; ++j)
        acc[i][j] = __builtin_amdgcn_mfma_f32_16x16x32_bf16(fa[i], fb[j], acc[i][j], 0, 0, 0);
  }
  int crow0 = m0 + wm * 64 + (lane >> 4) * 4, ccol0 = n0 + wn * 64 + (lane & 15);
  #pragma unroll
  for (int i = 0; i < 4; ++i) {
    #pragma unroll
    for (int j = 0; j < 4; ++j) {
      int col = ccol0 + j * 16;
      #pragma unroll
      for (int r = 0; r < 4; ++r) {
        int row = crow0 + i * 16 + r;
        float v = acc[i][j][r];
        if (EPI == 1) v += resid[(size_t)row * N + col];
        if (EPI == 2) { v += bias[col]; v = 0.5f * v * (1.f + erff(v * 0.70710678f)); }
        if (EPI == 3) v += bias[col] + resid[(size_t)row * N + col];
        C[(size_t)row * N + col] = v;
      }
    }
  }
}

// ---------------- MFMA GEMM 64x128 (for small-N GEMMs; more blocks) ----------------
template <int EPI>
__global__ __launch_bounds__(256) void gemm64_kernel(
    const float* __restrict__ A, const unsigned short* __restrict__ BT,
    float* __restrict__ C, int M, int N, int K,
    const float* __restrict__ bias, const float* __restrict__ resid) {
  __shared__ __align__(16) unsigned short As[64 * LST];
  __shared__ __align__(16) unsigned short Bs[128 * LST];
  int tid = threadIdx.x;
  int lane = tid & 63, wv = tid >> 6;
  int wm = wv >> 1, wn = wv & 1;
  int m0 = blockIdx.y * 64, n0 = blockIdx.x * BN;
  f32x4 acc[2][4] = {};
  int sr = tid >> 3, sc = (tid & 7) * 4;
  int kk = (lane >> 4) * 8;
  int rA = wm * 32 + (lane & 15);
  int rB = wn * 64 + (lane & 15);
  for (int k0 = 0; k0 < K; k0 += BK) {
    __syncthreads();
    #pragma unroll
    for (int p = 0; p < 2; ++p) {
      int r = sr + p * 32;
      float4 av = *(const float4*)(A + (size_t)(m0 + r) * K + k0 + sc);
      unsigned int lo = (unsigned int)f2bf(av.x) | ((unsigned int)f2bf(av.y) << 16);
      unsigned int hi = (unsigned int)f2bf(av.z) | ((unsigned int)f2bf(av.w) << 16);
      *(uint2*)&As[r * LST + sc] = make_uint2(lo, hi);
    }
    #pragma unroll
    for (int p = 0; p < 4; ++p) {
      int r = sr + p * 32;
      uint2 bv = *(const uint2*)(BT + (size_t)(n0 + r) * K + k0 + sc);
      *(uint2*)&Bs[r * LST + sc] = bv;
    }
    __syncthreads();
    bf16x8 fa[2], fb[4];
    #pragma unroll
    for (int i = 0; i < 2; ++i) fa[i] = *(const bf16x8*)&As[(rA + i * 16) * LST + kk];
    #pragma unroll
    for (int j = 0; j < 4; ++j) fb[j] = *(const bf16x8*)&Bs[(rB + j * 16) * LST + kk];
    #pragma unroll
    for (int i = 0; i < 2; ++i)
      #pragma unroll
      for (int j = 0; j < 4; ++j)
        acc[i][j] = __builtin_amdgcn_mfma_f32_16x16x32_bf16(fa[i], fb[j], acc[i][j], 0, 0, 0);
  }
  int crow0 = m0 + wm * 32 + (lane >> 4) * 4, ccol0 = n0 + wn * 64 + (lane & 15);
  #pragma unroll
  for (int i = 0; i < 2; ++i) {
    #pragma unroll
    for (int j = 0; j < 4; ++j) {
      int col = ccol0 + j * 16;
      #pragma unroll
      for (int r = 0; r < 4; ++r) {
        int row = crow0 + i * 16 + r;
        float v = acc[i][j][r];
        if (EPI == 1) v += resid[(size_t)row * N + col];
        if (EPI == 2) { v += bias[col]; v = 0.5f * v * (1.f + erff(v * 0.70710678f)); }
        if (EPI == 3) v += bias[col] + resid[(size_t)row * N + col];
        C[(size_t)row * N + col] = v;
      }
    }
  }
}

// ---------------- depthwise 3x3 conv + bias + SiLU (channels-last) ----------------
__global__ __launch_bounds__(256) void conv_kernel(
    const float* __restrict__ xz, const float* __restrict__ cw,
    const float* __restrict__ cb, float* __restrict__ xa) {
  int idx = blockIdx.x * 256 + threadIdx.x;  // (b,l,d), d fastest
  int d = idx & (DI_ - 1);
  int l = (idx >> 10) & (L_ - 1);
  int b = idx >> 20;
  int hh = l >> 5, ww = l & 31;
  float acc = cb[d];
  #pragma unroll
  for (int dh = -1; dh <= 1; ++dh) {
    int y = hh + dh;
    if ((unsigned)y >= 32u) continue;
    #pragma unroll
    for (int dw = -1; dw <= 1; ++dw) {
      int x = ww + dw;
      if ((unsigned)x >= 32u) continue;
      acc = fmaf(xz[((size_t)b * L_ + y * 32 + x) * (2 * DI_) + d],
                 cw[d * 9 + (dh + 1) * 3 + (dw + 1)], acc);
    }
  }
  float sv = acc / (1.f + __expf(-acc));
  xa[idx] = sv;
}

// ---------------- dt projection + softplus -> delta [b][k][l][d] (bf16) ----------------
__global__ __launch_bounds__(256) void delta_kernel(
    const float* __restrict__ sp, const float* __restrict__ dtw,
    const float* __restrict__ dtb, unsigned short* __restrict__ delta) {
  int bk = blockIdx.x;
  int b = bk >> 2, k = bk & 3;
  int dc = blockIdx.y * 256;
  int l0 = blockIdx.z * 128;
  __shared__ float wl[32 * 257];
  __shared__ float rl[128 * 32];
  int tid = threadIdx.x;
  for (int i = tid; i < 256 * 32; i += 256) {
    int dl = i >> 5, r = i & 31;
    wl[r * 257 + dl] = dtw[((size_t)k * DI_ + dc + dl) * R_ + r];
  }
  for (int i = tid; i < 128 * 32; i += 256) {
    int ll = i >> 5, r = i & 31;
    rl[ll * 32 + r] = sp[((size_t)b * L_ + l0 + ll) * 384 + k * R_ + r];
  }
  __syncthreads();
  float bias = dtb[k * DI_ + dc + tid];
  for (int ll = 0; ll < 128; ++ll) {
    float acc = bias;
    #pragma unroll
    for (int r = 0; r < 32; ++r)
      acc = fmaf(rl[ll * 32 + r], wl[r * 257 + tid], acc);
    float dlt = (acc > 15.f) ? acc : log1pf(__expf(acc));
    delta[(((size_t)(b * 4 + k) * L_) + l0 + ll) * DI_ + dc + tid] = f2bf(dlt);
  }
}

// ---------------- selective scan (packed-VALU, 4 waves/SIMD) ----------------
// lane = dg*16 + ng: dg = lane>>4 (4 d per wave), ng = lane&15 (owns n = ng*4..+3).
// Block: 512 thr = 8 waves = 32 d. Grid (DI/32, K, B) = 512 blocks -> 4 waves/SIMD.
// Per step DS: b64 (dlt,u) + b64 B(bf16x4) + b64 C(bf16x4) + 2 ds_swizzle.
// h/y updates in float2 -> v_pk_mul/fma_f32. Reduce: xor1,2 DPP; xor4,8 swizzle.
#define CH 16
#define NCH (L_ / CH)
__global__ __launch_bounds__(512) void scan_kernel(
    unsigned short* __restrict__ ybuf, const float* __restrict__ xa,
    const float* __restrict__ sp, const float* __restrict__ Cs,
    const unsigned short* __restrict__ dltb,
    const float* __restrict__ A_logs, const float* __restrict__ Ds) {
  int dblk = blockIdx.x;  // 32 blocks of 32 d's
  int k = blockIdx.y, b = blockIdx.z;
  int tid = threadIdx.x, lane = tid & 63, wv = tid >> 6;
  int dg = lane >> 4, ng = lane & 15;
  int wd = wv * 4 + dg;                // d within block's 32
  int gd = k * DI_ + dblk * 32 + wd;
  v2f a2p[2], h2[2];
  #pragma unroll
  for (int j = 0; j < 2; ++j) {
    a2p[j].x = -__expf(A_logs[(size_t)gd * N_ + ng * 4 + 2 * j]) * 1.44269504f;
    a2p[j].y = -__expf(A_logs[(size_t)gd * N_ + ng * 4 + 2 * j + 1]) * 1.44269504f;
    h2[j].x = 0.f; h2[j].y = 0.f;
  }
  float dsv = Ds[gd];

  __shared__ unsigned int Bsh[2][CH][32];   // 2 bf16 per uint: [li][n>>1]
  __shared__ unsigned int Csh[2][CH][32];
  __shared__ float DLU[2][CH][32][2];       // (dlt,u) per [li][d]

  const size_t spB = (size_t)b * L_ * 384 + 128 + k * 64;  // B part of style proj
  const size_t csB = (size_t)b * L_ * 256 + k * 64;
  const size_t dlB = ((size_t)(b * 4 + k) * L_) * DI_ + dblk * 32;
  const size_t xaB = (size_t)b * L_ * DI_ + dblk * 32;

  // staging: every thread stages 1 uint of B, 1 uint of C, 1 DLU pair per chunk
  int liS = tid >> 5, js = tid & 31;
  auto posf = [&](int l) {
    int lr = 1023 - l;
    return (k == 0) ? l
         : (k == 1) ? ((l & 31) * 32 + (l >> 5))
         : (k == 2) ? lr
                    : ((lr & 31) * 32 + (lr >> 5));
  };

  // stage chunk 0
  {
    float2 fB = *(const float2*)(sp + spB + (size_t)liS * 384 + js * 2);
    float2 fC = *(const float2*)(Cs + csB + (size_t)liS * 256 + js * 2);
    Bsh[0][liS][js] = (unsigned int)f2bf(fB.x) | ((unsigned int)f2bf(fB.y) << 16);
    Csh[0][liS][js] = (unsigned int)f2bf(fC.x) | ((unsigned int)f2bf(fC.y) << 16);
    float dlt = bf2f(dltb[dlB + (size_t)liS * DI_ + js]);
    float u = xa[xaB + (size_t)posf(liS) * DI_ + js];
    DLU[0][liS][js][0] = dlt;
    DLU[0][liS][js][1] = u;
  }
  __syncthreads();

  int cur = 0;
  for (int c = 0; c < NCH; ++c) {
    float2 pB, pC;
    unsigned short pD;
    float pU;
    if (c < NCH - 1) {  // prefetch chunk c+1 into registers
      int lb = (c + 1) * CH + liS;
      pB = *(const float2*)(sp + spB + (size_t)lb * 384 + js * 2);
      pC = *(const float2*)(Cs + csB + (size_t)lb * 256 + js * 2);
      pD = dltb[dlB + (size_t)lb * DI_ + js];
      pU = xa[xaB + (size_t)posf(lb) * DI_ + js];
    }
    #pragma unroll
    for (int li = 0; li < CH; ++li) {
      float2 du2l = *(const float2*)&DLU[cur][li][wd][0];
      float dlt = du2l.x, u = du2l.y;
      float du = dlt * u;
      uint2 bq = *(const uint2*)&Bsh[cur][li][ng * 2];
      uint2 cq = *(const uint2*)&Csh[cur][li][ng * 2];
      v2f bv0, bv1, cv0, cv1;
      bv0.x = __builtin_bit_cast(float, bq.x << 16);
      bv0.y = __builtin_bit_cast(float, bq.x & 0xFFFF0000u);
      bv1.x = __builtin_bit_cast(float, bq.y << 16);
      bv1.y = __builtin_bit_cast(float, bq.y & 0xFFFF0000u);
      cv0.x = __builtin_bit_cast(float, cq.x << 16);
      cv0.y = __builtin_bit_cast(float, cq.x & 0xFFFF0000u);
      cv1.x = __builtin_bit_cast(float, cq.y << 16);
      cv1.y = __builtin_bit_cast(float, cq.y & 0xFFFF0000u);
      v2f dlt2; dlt2.x = dlt; dlt2.y = dlt;
      v2f du2; du2.x = du; du2.y = du;
      v2f arg0 = dlt2 * a2p[0];
      v2f arg1 = dlt2 * a2p[1];
      v2f e0, e1;
      e0.x = __builtin_amdgcn_exp2f(arg0.x);
      e0.y = __builtin_amdgcn_exp2f(arg0.y);
      e1.x = __builtin_amdgcn_exp2f(arg1.x);
      e1.y = __builtin_amdgcn_exp2f(arg1.y);
      h2[0] = e0 * h2[0] + du2 * bv0;   // v_pk_fma chains
      h2[1] = e1 * h2[1] + du2 * bv1;
      v2f yp2 = h2[0] * cv0 + h2[1] * cv1;
      float yp = yp2.x + yp2.y;
      // reduce over 16 ng lanes: xor1, xor2 on VALU (DPP); xor4, xor8 on DS
      yp = dpp_qadd<0xB1>(yp);  // quad_perm [1,0,3,2]
      yp = dpp_qadd<0x4E>(yp);  // quad_perm [2,3,0,1]
      {
        int i0 = __builtin_bit_cast(int, yp);
        int j0 = __builtin_amdgcn_ds_swizzle(i0, 0x101F);  // xor4
        yp += __builtin_bit_cast(float, j0);
        int i1 = __builtin_bit_cast(int, yp);
        int j1 = __builtin_amdgcn_ds_swizzle(i1, 0x201F);  // xor8
        yp += __builtin_bit_cast(float, j1);
      }
      if (ng == 0) {  // lanes 0,16,32,48 write 4 consecutive bf16 d's
        ybuf[dlB + (size_t)(c * CH + li) * DI_ + wd] = f2bf(fmaf(u, dsv, yp));
      }
    }
    __syncthreads();  // chunk consumed
    if (c < NCH - 1) {
      int nxt = cur ^ 1;
      Bsh[nxt][liS][js] = (unsigned int)f2bf(pB.x) | ((unsigned int)f2bf(pB.y) << 16);
      Csh[nxt][liS][js] = (unsigned int)f2bf(pC.x) | ((unsigned int)f2bf(pC.y) << 16);
      DLU[nxt][liS][js][0] = bf2f(pD);
      DLU[nxt][liS][js][1] = pU;
    }
    __syncthreads();  // staging visible
    cur ^= 1;
  }
}

// ---------------- fuse: ygz = (sum_k yk) * z  (yk bf16) ----------------
__global__ __launch_bounds__(256) void fuse_ygz(
    const unsigned short* __restrict__ yk, const float* __restrict__ xz,
    float* __restrict__ ygz) {
  size_t i = ((size_t)blockIdx.x * 256 + threadIdx.x) * 8;  // 8 d per thread
  size_t b = i >> 20, ld = i & ((1u << 20) - 1);
  float acc[8] = {};
  #pragma unroll
  for (int k = 0; k < 4; ++k) {
    uint4 v = *(const uint4*)(yk + ((size_t)(b * 4 + k) << 20) + ld);
    unsigned int w[4] = {v.x, v.y, v.z, v.w};
    #pragma unroll
    for (int t = 0; t < 4; ++t) {
      acc[t * 2 + 0] += __builtin_bit_cast(float, w[t] << 16);
      acc[t * 2 + 1] += __builtin_bit_cast(float, w[t] & 0xFFFF0000u);
    }
  }
  const float* zp = xz + (i >> 10) * (2 * DI_) + DI_ + (i & (DI_ - 1));
  float4 z0 = *(const float4*)zp;
  float4 z1 = *(const float4*)(zp + 4);
  float4 o0, o1;
  o0.x = acc[0] * z0.x; o0.y = acc[1] * z0.y; o0.z = acc[2] * z0.z; o0.w = acc[3] * z0.w;
  o1.x = acc[4] * z1.x; o1.y = acc[5] * z1.y; o1.z = acc[6] * z1.z; o1.w = acc[7] * z1.w;
  *(float4*)(ygz + i) = o0;
  *(float4*)(ygz + i + 4) = o1;
}

// ---------------- host ----------------
extern "C" void kernel_launch(void* const* d_in, const int* in_sizes, int n_in,
                              void* d_out, int out_size, void* d_ws, size_t ws_size,
                              hipStream_t stream) {
  (void)in_sizes; (void)n_in; (void)out_size; (void)ws_size;
  const float* content   = (const float*)d_in[0];
  const float* style     = (const float*)d_in[1];
  const float* norm1_w   = (const float*)d_in[2];
  const float* norm1_b   = (const float*)d_in[3];
  const float* in_proj_w = (const float*)d_in[4];
  const float* conv_w    = (const float*)d_in[5];
  const float* conv_b    = (const float*)d_in[6];
  const float* style_proj_w   = (const float*)d_in[7];
  const float* content_proj_w = (const float*)d_in[8];
  const float* dtw       = (const float*)d_in[9];
  const float* dtb       = (const float*)d_in[10];
  const float* A_logs    = (const float*)d_in[11];
  const float* Ds        = (const float*)d_in[12];
  const float* out_proj_w = (const float*)d_in[13];
  const float* norm2_w   = (const float*)d_in[14];
  const float* norm2_b   = (const float*)d_in[15];
  const float* mlp_w1    = (const float*)d_in[16];
  const float* mlp_b1    = (const float*)d_in[17];
  const float* mlp_w2    = (const float*)d_in[18];
  const float* mlp_b2    = (const float*)d_in[19];
  float* out = (float*)d_out;

  float* ws = (float*)d_ws;
  const size_t ROWS = (size_t)B_ * L_;  // 4096
  const size_t SCAN_ELEMS = (size_t)B_ * K_ * L_ * DI_;  // 16.78M
  size_t o = 0;
  float* cn    = ws + o; o += ROWS * HID_;        // reused as x1
  float* sn    = ws + o; o += ROWS * HID_;        // reused as xn
  float* xz    = ws + o; o += ROWS * 2 * DI_;
  float* sp    = ws + o; o += ROWS * 384;
  float* xa    = ws + o; o += ROWS * DI_;
  float* csb   = ws + o; o += ROWS * 256;
  unsigned short* dltb = (unsigned short*)(ws + o); o += SCAN_ELEMS / 2;  // bf16 delta
  unsigned short* ybuf = (unsigned short*)(ws + o); o += SCAN_ELEMS / 2;  // bf16 y; reused as hmid
  float* ygz   = ws + o; o += ROWS * DI_;
  unsigned short* wt = (unsigned short*)(ws + o);
  unsigned short* inpT = wt;                    // (2048,512)
  unsigned short* styT = inpT + 2048 * 512;     // (384,512)
  unsigned short* conT = styT + 384 * 512;      // (256,1024)
  unsigned short* outT = conT + 256 * 1024;     // (512,1024)
  unsigned short* w1T  = outT + 512 * 1024;     // (2048,512)
  unsigned short* w2T  = w1T + 2048 * 512;      // (512,2048)
  float* x1 = cn;
  float* xn = sn;
  float* hmid = (float*)ybuf;  // 4096x2048 f32 fits in ybuf region

  // weight transpose+cast to bf16 (N,K)
  transpose_cast<<<dim3(2048 / 32, 512 / 32), 256, 0, stream>>>(in_proj_w, inpT, 512, 2048);
  transpose_cast<<<dim3(384 / 32, 512 / 32), 256, 0, stream>>>(style_proj_w, styT, 512, 384);
  transpose_cast<<<dim3(256 / 32, 1024 / 32), 256, 0, stream>>>(content_proj_w, conT, 1024, 256);
  transpose_cast<<<dim3(512 / 32, 1024 / 32), 256, 0, stream>>>(out_proj_w, outT, 1024, 512);
  transpose_cast<<<dim3(2048 / 32, 512 / 32), 256, 0, stream>>>(mlp_w1, w1T, 512, 2048);
  transpose_cast<<<dim3(512 / 32, 2048 / 32), 256, 0, stream>>>(mlp_w2, w2T, 2048, 512);

  // norm1 on content and style (one launch)
  ln_kernel<<<dim3(ROWS / 4, 2), 256, 0, stream>>>(content, cn, style, sn, norm1_w, norm1_b);

  // xz = cn @ in_proj
  gemm_kernel<0><<<dim3(2048 / BN, ROWS / BM), 256, 0, stream>>>(
      cn, inpT, xz, ROWS, 2048, 512, nullptr, nullptr);
  // sp = sn @ style_proj
  gemm64_kernel<0><<<dim3(384 / BN, ROWS / 64), 256, 0, stream>>>(
      sn, styT, sp, ROWS, 384, 512, nullptr, nullptr);
  // conv + silu -> xa
  conv_kernel<<<(ROWS * DI_) / 256, 256, 0, stream>>>(xz, conv_w, conv_b, xa);
  // Cs = xa @ content_proj
  gemm64_kernel<0><<<dim3(256 / BN, ROWS / 64), 256, 0, stream>>>(
      xa, conT, csb, ROWS, 256, 1024, nullptr, nullptr);
  // delta = softplus(rank @ dtw + bias) -> bf16
  delta_kernel<<<dim3(B_ * K_, DI_ / 256, L_ / 128), 256, 0, stream>>>(sp, dtw, dtb, dltb);
  // selective scan -> ybuf (bf16)
  scan_kernel<<<dim3(DI_ / 32, K_, B_), 512, 0, stream>>>(
      ybuf, xa, sp, csb, dltb, A_logs, Ds);
  // ygz = (sum_k y) * z
  fuse_ygz<<<(ROWS * DI_) / (256 * 8), 256, 0, stream>>>(ybuf, xz, ygz);
  // x1 = content + ygz @ out_proj
  gemm64_kernel<1><<<dim3(512 / BN, ROWS / 64), 256, 0, stream>>>(
      ygz, outT, x1, ROWS, 512, 1024, nullptr, content);
  // norm2
  ln_kernel<<<dim3(ROWS / 4, 1), 256, 0, stream>>>(x1, xn, nullptr, nullptr, norm2_w, norm2_b);
  // mlp
  gemm_kernel<2><<<dim3(2048 / BN, ROWS / BM), 256, 0, stream>>>(
      xn, w1T, hmid, ROWS, 2048, 512, mlp_b1, nullptr);
  gemm64_kernel<3><<<dim3(512 / BN, ROWS / 64), 256, 0, stream>>>(
      hmid, w2T, out, ROWS, 512, 2048, mlp_b2, x1);
}

// Round 7
// 564.382 us; speedup vs baseline: 1.1920x; 1.1920x over previous
//
#include <hip/hip_runtime.h>

// ---------------- constants ----------------
#define B_ 4
#define Hh_ 32
#define Ww_ 32
#define L_ 1024
#define HID_ 512
#define DI_ 1024
#define N_ 64
#define R_ 32
#define K_ 4
#define MLP_ 2048

typedef __bf16 bf16x8 __attribute__((ext_vector_type(8)));
typedef float f32x4 __attribute__((ext_vector_type(4)));

__device__ __forceinline__ unsigned short f2bf(float f) {
  unsigned int u = __builtin_bit_cast(unsigned int, f);
  return (unsigned short)((u + 0x7FFFu + ((u >> 16) & 1u)) >> 16);
}
__device__ __forceinline__ float bf2f(unsigned short h) {
  return __builtin_bit_cast(float, (unsigned int)h << 16);
}

// quad_perm DPP add: x + x[lane ^ (1 or 2)] on the VALU pipe (no DS)
template <int CTRL>
__device__ __forceinline__ float dpp_qadd(float x) {
  int i = __builtin_bit_cast(int, x);
  int j = __builtin_amdgcn_update_dpp(i, i, CTRL, 0xF, 0xF, false);
  return x + __builtin_bit_cast(float, j);
}

// ---------------- all 6 weight transposes in ONE launch ----------------
// src (K,N) f32 -> dst (N,K) bf16
__global__ __launch_bounds__(256) void transpose_all(
    const float* __restrict__ s0, const float* __restrict__ s1,
    const float* __restrict__ s2, const float* __restrict__ s3,
    const float* __restrict__ s4, const float* __restrict__ s5,
    unsigned short* __restrict__ t0, unsigned short* __restrict__ t1,
    unsigned short* __restrict__ t2, unsigned short* __restrict__ t3,
    unsigned short* __restrict__ t4, unsigned short* __restrict__ t5) {
  __shared__ float t[32][33];
  int bid = blockIdx.x;
  const float* src; unsigned short* dst; int K, N, bx, by;
  if (bid < 1024)      { src = s0; dst = t0; K = 512;  N = 2048; int r = bid;        bx = r & 63; by = r >> 6; }
  else if (bid < 1216) { src = s1; dst = t1; K = 512;  N = 384;  int r = bid - 1024; bx = r % 12; by = r / 12; }
  else if (bid < 1472) { src = s2; dst = t2; K = 1024; N = 256;  int r = bid - 1216; bx = r & 7;  by = r >> 3; }
  else if (bid < 1984) { src = s3; dst = t3; K = 1024; N = 512;  int r = bid - 1472; bx = r & 15; by = r >> 4; }
  else if (bid < 3008) { src = s4; dst = t4; K = 512;  N = 2048; int r = bid - 1984; bx = r & 63; by = r >> 6; }
  else                 { src = s5; dst = t5; K = 2048; N = 512;  int r = bid - 3008; bx = r & 15; by = r >> 4; }
  int nb = bx * 32, kb = by * 32;
  int tx = threadIdx.x & 31, ty = threadIdx.x >> 5;
  for (int r = ty; r < 32; r += 8) t[r][tx] = src[(size_t)(kb + r) * N + nb + tx];
  __syncthreads();
  for (int r = ty; r < 32; r += 8) dst[(size_t)(nb + r) * K + kb + tx] = f2bf(t[tx][r]);
}

// ---------------- LayerNorm over 512, wave per row; writes bf16 ----------------
__global__ __launch_bounds__(256) void ln_kernel(
    const float* __restrict__ in0, unsigned short* __restrict__ out0,
    const float* __restrict__ in1, unsigned short* __restrict__ out1,
    const float* __restrict__ w, const float* __restrict__ bb) {
  const float* in = blockIdx.y ? in1 : in0;
  unsigned short* out = blockIdx.y ? out1 : out0;
  int row = blockIdx.x * 4 + (threadIdx.x >> 6);
  int lane = threadIdx.x & 63;
  const float* p = in + (size_t)row * HID_;
  float4 v0 = *(const float4*)(p + lane * 4);
  float4 v1 = *(const float4*)(p + 256 + lane * 4);
  float s = v0.x + v0.y + v0.z + v0.w + v1.x + v1.y + v1.z + v1.w;
  float q = v0.x * v0.x + v0.y * v0.y + v0.z * v0.z + v0.w * v0.w +
            v1.x * v1.x + v1.y * v1.y + v1.z * v1.z + v1.w * v1.w;
  #pragma unroll
  for (int m = 1; m < 64; m <<= 1) { s += __shfl_xor(s, m, 64); q += __shfl_xor(q, m, 64); }
  float mean = s * (1.f / 512.f);
  float var = q * (1.f / 512.f) - mean * mean;
  float rstd = rsqrtf(var + 1e-5f);
  float4 w0 = *(const float4*)(w + lane * 4);
  float4 w1 = *(const float4*)(w + 256 + lane * 4);
  float4 b0 = *(const float4*)(bb + lane * 4);
  float4 b1 = *(const float4*)(bb + 256 + lane * 4);
  unsigned short* o = out + (size_t)row * HID_;
  ushort4 r0, r1;
  r0.x = f2bf((v0.x - mean) * rstd * w0.x + b0.x);
  r0.y = f2bf((v0.y - mean) * rstd * w0.y + b0.y);
  r0.z = f2bf((v0.z - mean) * rstd * w0.z + b0.z);
  r0.w = f2bf((v0.w - mean) * rstd * w0.w + b0.w);
  r1.x = f2bf((v1.x - mean) * rstd * w1.x + b1.x);
  r1.y = f2bf((v1.y - mean) * rstd * w1.y + b1.y);
  r1.z = f2bf((v1.z - mean) * rstd * w1.z + b1.z);
  r1.w = f2bf((v1.w - mean) * rstd * w1.w + b1.w);
  *(ushort4*)(o + lane * 4) = r0;
  *(ushort4*)(o + 256 + lane * 4) = r1;
}

// ---------------- MFMA GEMM 128x128: A (M,K) bf16, BT (N,K) bf16 ----------------
// EPI: 0 = plain, 1 = +resid, 2 = +bias then exact gelu, 3 = +bias +resid
// OUTBF: 1 -> C is bf16, else f32
#define BM 128
#define BN 128
#define BK 32
#define LST 40  // LDS row stride in bf16 units

template <int EPI, int OUTBF>
__global__ __launch_bounds__(256) void gemm_kernel(
    const unsigned short* __restrict__ A, const unsigned short* __restrict__ BT,
    void* __restrict__ Cv, int M, int N, int K,
    const float* __restrict__ bias, const float* __restrict__ resid) {
  __shared__ __align__(16) unsigned short As[BM * LST];
  __shared__ __align__(16) unsigned short Bs[BN * LST];
  int tid = threadIdx.x;
  int lane = tid & 63, wv = tid >> 6;
  int wm = wv >> 1, wn = wv & 1;
  int m0 = blockIdx.y * BM, n0 = blockIdx.x * BN;
  f32x4 acc[4][4] = {};
  int sr = tid >> 1, sc = (tid & 1) * 16;
  int kk = (lane >> 4) * 8;
  int rA = wm * 64 + (lane & 15);
  int rB = wn * 64 + (lane & 15);
  for (int k0 = 0; k0 < K; k0 += BK) {
    __syncthreads();
    {
      uint4 a0 = *(const uint4*)(A + (size_t)(m0 + sr) * K + k0 + sc);
      uint4 a1 = *(const uint4*)(A + (size_t)(m0 + sr) * K + k0 + sc + 8);
      *(uint4*)&As[sr * LST + sc] = a0;
      *(uint4*)&As[sr * LST + sc + 8] = a1;
      uint4 b0 = *(const uint4*)(BT + (size_t)(n0 + sr) * K + k0 + sc);
      uint4 b1 = *(const uint4*)(BT + (size_t)(n0 + sr) * K + k0 + sc + 8);
      *(uint4*)&Bs[sr * LST + sc] = b0;
      *(uint4*)&Bs[sr * LST + sc + 8] = b1;
    }
    __syncthreads();
    bf16x8 fa[4], fb[4];
    #pragma unroll
    for (int i = 0; i < 4; ++i) {
      fa[i] = *(const bf16x8*)&As[(rA + i * 16) * LST + kk];
      fb[i] = *(const bf16x8*)&Bs[(rB + i * 16) * LST + kk];
    }
    #pragma unroll
    for (int i = 0; i < 4; ++i)
      #pragma unroll
      for (int j = 0; j < 4; ++j)
        acc[i][j] = __builtin_amdgcn_mfma_f32_16x16x32_bf16(fa[i], fb[j], acc[i][j], 0, 0, 0);
  }
  int crow0 = m0 + wm * 64 + (lane >> 4) * 4, ccol0 = n0 + wn * 64 + (lane & 15);
  #pragma unroll
  for (int i = 0; i < 4; ++i) {
    #pragma unroll
    for (int j = 0; j < 4; ++j) {
      int col = ccol0 + j * 16;
      #pragma unroll
      for (int r = 0; r < 4; ++r) {
        int row = crow0 + i * 16 + r;
        float v = acc[i][j][r];
        if (EPI == 1) v += resid[(size_t)row * N + col];
        if (EPI == 2) { v += bias[col]; v = 0.5f * v * (1.f + erff(v * 0.70710678f)); }
        if (EPI == 3) v += bias[col] + resid[(size_t)row * N + col];
        if (OUTBF) ((unsigned short*)Cv)[(size_t)row * N + col] = f2bf(v);
        else       ((float*)Cv)[(size_t)row * N + col] = v;
      }
    }
  }
}

// ---------------- MFMA GEMM 64x128 ----------------
template <int EPI, int OUTBF>
__global__ __launch_bounds__(256) void gemm64_kernel(
    const unsigned short* __restrict__ A, const unsigned short* __restrict__ BT,
    void* __restrict__ Cv, int M, int N, int K,
    const float* __restrict__ bias, const float* __restrict__ resid) {
  __shared__ __align__(16) unsigned short As[64 * LST];
  __shared__ __align__(16) unsigned short Bs[128 * LST];
  int tid = threadIdx.x;
  int lane = tid & 63, wv = tid >> 6;
  int wm = wv >> 1, wn = wv & 1;
  int m0 = blockIdx.y * 64, n0 = blockIdx.x * BN;
  f32x4 acc[2][4] = {};
  int srA = tid >> 2, scA = (tid & 3) * 8;
  int srB = tid >> 1, scB = (tid & 1) * 16;
  int kk = (lane >> 4) * 8;
  int rA = wm * 32 + (lane & 15);
  int rB = wn * 64 + (lane & 15);
  for (int k0 = 0; k0 < K; k0 += BK) {
    __syncthreads();
    {
      uint4 a0 = *(const uint4*)(A + (size_t)(m0 + srA) * K + k0 + scA);
      *(uint4*)&As[srA * LST + scA] = a0;
      uint4 b0 = *(const uint4*)(BT + (size_t)(n0 + srB) * K + k0 + scB);
      uint4 b1 = *(const uint4*)(BT + (size_t)(n0 + srB) * K + k0 + scB + 8);
      *(uint4*)&Bs[srB * LST + scB] = b0;
      *(uint4*)&Bs[srB * LST + scB + 8] = b1;
    }
    __syncthreads();
    bf16x8 fa[2], fb[4];
    #pragma unroll
    for (int i = 0; i < 2; ++i) fa[i] = *(const bf16x8*)&As[(rA + i * 16) * LST + kk];
    #pragma unroll
    for (int j = 0; j < 4; ++j) fb[j] = *(const bf16x8*)&Bs[(rB + j * 16) * LST + kk];
    #pragma unroll
    for (int i = 0; i < 2; ++i)
      #pragma unroll
      for (int j = 0; j < 4; ++j)
        acc[i][j] = __builtin_amdgcn_mfma_f32_16x16x32_bf16(fa[i], fb[j], acc[i][j], 0, 0, 0);
  }
  int crow0 = m0 + wm * 32 + (lane >> 4) * 4, ccol0 = n0 + wn * 64 + (lane & 15);
  #pragma unroll
  for (int i = 0; i < 2; ++i) {
    #pragma unroll
    for (int j = 0; j < 4; ++j) {
      int col = ccol0 + j * 16;
      #pragma unroll
      for (int r = 0; r < 4; ++r) {
        int row = crow0 + i * 16 + r;
        float v = acc[i][j][r];
        if (EPI == 1) v += resid[(size_t)row * N + col];
        if (EPI == 2) { v += bias[col]; v = 0.5f * v * (1.f + erff(v * 0.70710678f)); }
        if (EPI == 3) v += bias[col] + resid[(size_t)row * N + col];
        if (OUTBF) ((unsigned short*)Cv)[(size_t)row * N + col] = f2bf(v);
        else       ((float*)Cv)[(size_t)row * N + col] = v;
      }
    }
  }
}

// ---------------- depthwise 3x3 conv + bias + SiLU; writes bf16 xa ----------------
__global__ __launch_bounds__(256) void conv_kernel(
    const float* __restrict__ xz, const float* __restrict__ cw,
    const float* __restrict__ cb, unsigned short* __restrict__ xa) {
  int idx = blockIdx.x * 256 + threadIdx.x;  // (b,l,d), d fastest
  int d = idx & (DI_ - 1);
  int l = (idx >> 10) & (L_ - 1);
  int b = idx >> 20;
  int hh = l >> 5, ww = l & 31;
  float acc = cb[d];
  #pragma unroll
  for (int dh = -1; dh <= 1; ++dh) {
    int y = hh + dh;
    if ((unsigned)y >= 32u) continue;
    #pragma unroll
    for (int dw = -1; dw <= 1; ++dw) {
      int x = ww + dw;
      if ((unsigned)x >= 32u) continue;
      acc = fmaf(xz[((size_t)b * L_ + y * 32 + x) * (2 * DI_) + d],
                 cw[d * 9 + (dh + 1) * 3 + (dw + 1)], acc);
    }
  }
  float sv = acc / (1.f + __expf(-acc));
  xa[idx] = f2bf(sv);
}

// ---------------- dt projection + softplus -> delta [b][k][l][d] (bf16) ----------------
__global__ __launch_bounds__(256) void delta_kernel(
    const float* __restrict__ sp, const float* __restrict__ dtw,
    const float* __restrict__ dtb, unsigned short* __restrict__ delta) {
  int bk = blockIdx.x;
  int b = bk >> 2, k = bk & 3;
  int dc = blockIdx.y * 256;
  int l0 = blockIdx.z * 128;
  __shared__ float wl[32 * 257];
  __shared__ float rl[128 * 32];
  int tid = threadIdx.x;
  for (int i = tid; i < 256 * 32; i += 256) {
    int dl = i >> 5, r = i & 31;
    wl[r * 257 + dl] = dtw[((size_t)k * DI_ + dc + dl) * R_ + r];
  }
  for (int i = tid; i < 128 * 32; i += 256) {
    int ll = i >> 5, r = i & 31;
    rl[ll * 32 + r] = sp[((size_t)b * L_ + l0 + ll) * 384 + k * R_ + r];
  }
  __syncthreads();
  float bias = dtb[k * DI_ + dc + tid];
  for (int ll = 0; ll < 128; ++ll) {
    float acc = bias;
    #pragma unroll
    for (int r = 0; r < 32; ++r)
      acc = fmaf(rl[ll * 32 + r], wl[r * 257 + tid], acc);
    float dlt = (acc > 15.f) ? acc : log1pf(__expf(acc));
    delta[(((size_t)(b * 4 + k) * L_) + l0 + ll) * DI_ + dc + tid] = f2bf(dlt);
  }
}

// ---------------- selective scan: f32 LDS, 4 waves/SIMD, cheap reduce ----------------
// lane = dg*16 + ng: dg = lane>>4 (4 d per wave), ng = lane&15 (4 n per lane).
// Block: 512 thr = 8 waves = 32 d. Grid (DI/32, K, B) = 512 blocks -> 2 blk/CU, 4 wv/SIMD.
// Per step: DS = b64 DLU + b128 B(f32) + b128 C(f32) + 2 swizzle. Zero unpack VALU.
// Reduce over 16 ng: xor1, xor2 via DPP (VALU); xor4, xor8 via ds_swizzle. y -> global bf16.
#define CH 16
#define NCH (L_ / CH)
__global__ __launch_bounds__(512) void scan_kernel(
    unsigned short* __restrict__ ybuf, const unsigned short* __restrict__ xa,
    const float* __restrict__ sp, const float* __restrict__ Cs,
    const unsigned short* __restrict__ dltb,
    const float* __restrict__ A_logs, const float* __restrict__ Ds) {
  int dblk = blockIdx.x;  // 32 blocks of 32 d's
  int k = blockIdx.y, b = blockIdx.z;
  int tid = threadIdx.x, lane = tid & 63, wv = tid >> 6;
  int dg = lane >> 4, ng = lane & 15;
  int wd = wv * 4 + dg;                // d within block's 32
  int gd = k * DI_ + dblk * 32 + wd;
  float a2[4], h[4];
  #pragma unroll
  for (int j = 0; j < 4; ++j) {
    a2[j] = -__expf(A_logs[(size_t)gd * N_ + ng * 4 + j]) * 1.44269504f;
    h[j] = 0.f;
  }
  float dsv = Ds[gd];

  __shared__ float Bsh[2][CH][64];
  __shared__ float Csh[2][CH][64];
  __shared__ float DLU[2][CH][32][2];  // (dlt,u) per [li][d]

  const size_t spB = (size_t)b * L_ * 384 + 128 + k * 64;
  const size_t csB = (size_t)b * L_ * 256 + k * 64;
  const size_t dlB = ((size_t)(b * 4 + k) * L_) * DI_ + dblk * 32;
  const size_t xaB = (size_t)b * L_ * DI_ + dblk * 32;

  // staging: liS = row (16), js = 0..31. Each thread: float2 of B, float2 of C, one DLU pair.
  int liS = tid >> 5, js = tid & 31;
  auto posf = [&](int l) {
    int lr = 1023 - l;
    return (k == 0) ? l
         : (k == 1) ? ((l & 31) * 32 + (l >> 5))
         : (k == 2) ? lr
                    : ((lr & 31) * 32 + (lr >> 5));
  };

  // stage chunk 0
  {
    *(float2*)&Bsh[0][liS][js * 2] = *(const float2*)(sp + spB + (size_t)liS * 384 + js * 2);
    *(float2*)&Csh[0][liS][js * 2] = *(const float2*)(Cs + csB + (size_t)liS * 256 + js * 2);
    float dlt = bf2f(dltb[dlB + (size_t)liS * DI_ + js]);
    float u = bf2f(xa[xaB + (size_t)posf(liS) * DI_ + js]);
    DLU[0][liS][js][0] = dlt;
    DLU[0][liS][js][1] = u;
  }
  __syncthreads();

  int cur = 0;
  for (int c = 0; c < NCH; ++c) {
    float2 pB, pC;
    unsigned short pD, pU;
    if (c < NCH - 1) {  // prefetch chunk c+1 into registers
      int lb = (c + 1) * CH + liS;
      pB = *(const float2*)(sp + spB + (size_t)lb * 384 + js * 2);
      pC = *(const float2*)(Cs + csB + (size_t)lb * 256 + js * 2);
      pD = dltb[dlB + (size_t)lb * DI_ + js];
      pU = xa[xaB + (size_t)posf(lb) * DI_ + js];
    }
    #pragma unroll
    for (int li = 0; li < CH; ++li) {
      float2 du2 = *(const float2*)&DLU[cur][li][wd][0];
      float dlt = du2.x, u = du2.y;
      float du = dlt * u;
      float4 bq = *(const float4*)&Bsh[cur][li][ng * 4];
      float4 cq = *(const float4*)&Csh[cur][li][ng * 4];
      float yp;
      {
        float e = __builtin_amdgcn_exp2f(dlt * a2[0]);
        h[0] = fmaf(e, h[0], du * bq.x); yp = h[0] * cq.x;
      }
      {
        float e = __builtin_amdgcn_exp2f(dlt * a2[1]);
        h[1] = fmaf(e, h[1], du * bq.y); yp = fmaf(h[1], cq.y, yp);
      }
      {
        float e = __builtin_amdgcn_exp2f(dlt * a2[2]);
        h[2] = fmaf(e, h[2], du * bq.z); yp = fmaf(h[2], cq.z, yp);
      }
      {
        float e = __builtin_amdgcn_exp2f(dlt * a2[3]);
        h[3] = fmaf(e, h[3], du * bq.w); yp = fmaf(h[3], cq.w, yp);
      }
      // reduce over 16 ng lanes: xor1, xor2 on VALU (DPP); xor4, xor8 on DS
      yp = dpp_qadd<0xB1>(yp);  // quad_perm [1,0,3,2]
      yp = dpp_qadd<0x4E>(yp);  // quad_perm [2,3,0,1]
      {
        int i0 = __builtin_bit_cast(int, yp);
        int j0 = __builtin_amdgcn_ds_swizzle(i0, 0x101F);  // xor4
        yp += __builtin_bit_cast(float, j0);
        int i1 = __builtin_bit_cast(int, yp);
        int j1 = __builtin_amdgcn_ds_swizzle(i1, 0x201F);  // xor8
        yp += __builtin_bit_cast(float, j1);
      }
      if (ng == 0) {  // lanes 0,16,32,48 -> d = wv*4 + 0..3, 4x2B contiguous
        ybuf[dlB + (size_t)(c * CH + li) * DI_ + wd] = f2bf(fmaf(u, dsv, yp));
      }
    }
    __syncthreads();  // chunk consumed
    if (c < NCH - 1) {
      int nxt = cur ^ 1;
      *(float2*)&Bsh[nxt][liS][js * 2] = pB;
      *(float2*)&Csh[nxt][liS][js * 2] = pC;
      DLU[nxt][liS][js][0] = bf2f(pD);
      DLU[nxt][liS][js][1] = bf2f(pU);
    }
    __syncthreads();  // staging visible
    cur ^= 1;
  }
}

// ---------------- fuse: ygz = (sum_k yk) * z  -> bf16 ----------------
__global__ __launch_bounds__(256) void fuse_ygz(
    const unsigned short* __restrict__ yk, const float* __restrict__ xz,
    unsigned short* __restrict__ ygz) {
  size_t i = ((size_t)blockIdx.x * 256 + threadIdx.x) * 8;  // 8 d per thread
  size_t b = i >> 20, ld = i & ((1u << 20) - 1);
  float acc[8] = {};
  #pragma unroll
  for (int k = 0; k < 4; ++k) {
    uint4 v = *(const uint4*)(yk + ((size_t)(b * 4 + k) << 20) + ld);
    unsigned int w[4] = {v.x, v.y, v.z, v.w};
    #pragma unroll
    for (int t = 0; t < 4; ++t) {
      acc[t * 2 + 0] += __builtin_bit_cast(float, w[t] << 16);
      acc[t * 2 + 1] += __builtin_bit_cast(float, w[t] & 0xFFFF0000u);
    }
  }
  const float* zp = xz + (i >> 10) * (2 * DI_) + DI_ + (i & (DI_ - 1));
  float4 z0 = *(const float4*)zp;
  float4 z1 = *(const float4*)(zp + 4);
  uint4 o;
  o.x = (unsigned int)f2bf(acc[0] * z0.x) | ((unsigned int)f2bf(acc[1] * z0.y) << 16);
  o.y = (unsigned int)f2bf(acc[2] * z0.z) | ((unsigned int)f2bf(acc[3] * z0.w) << 16);
  o.z = (unsigned int)f2bf(acc[4] * z1.x) | ((unsigned int)f2bf(acc[5] * z1.y) << 16);
  o.w = (unsigned int)f2bf(acc[6] * z1.z) | ((unsigned int)f2bf(acc[7] * z1.w) << 16);
  *(uint4*)(ygz + i) = o;
}

// ---------------- host ----------------
extern "C" void kernel_launch(void* const* d_in, const int* in_sizes, int n_in,
                              void* d_out, int out_size, void* d_ws, size_t ws_size,
                              hipStream_t stream) {
  (void)in_sizes; (void)n_in; (void)out_size; (void)ws_size;
  const float* content   = (const float*)d_in[0];
  const float* style     = (const float*)d_in[1];
  const float* norm1_w   = (const float*)d_in[2];
  const float* norm1_b   = (const float*)d_in[3];
  const float* in_proj_w = (const float*)d_in[4];
  const float* conv_w    = (const float*)d_in[5];
  const float* conv_b    = (const float*)d_in[6];
  const float* style_proj_w   = (const float*)d_in[7];
  const float* content_proj_w = (const float*)d_in[8];
  const float* dtw       = (const float*)d_in[9];
  const float* dtb       = (const float*)d_in[10];
  const float* A_logs    = (const float*)d_in[11];
  const float* Ds        = (const float*)d_in[12];
  const float* out_proj_w = (const float*)d_in[13];
  const float* norm2_w   = (const float*)d_in[14];
  const float* norm2_b   = (const float*)d_in[15];
  const float* mlp_w1    = (const float*)d_in[16];
  const float* mlp_b1    = (const float*)d_in[17];
  const float* mlp_w2    = (const float*)d_in[18];
  const float* mlp_b2    = (const float*)d_in[19];
  float* out = (float*)d_out;

  float* ws = (float*)d_ws;
  const size_t ROWS = (size_t)B_ * L_;  // 4096
  const size_t SCAN_ELEMS = (size_t)B_ * K_ * L_ * DI_;  // 16.78M
  size_t o = 0;
  unsigned short* cn  = (unsigned short*)(ws + o); o += ROWS * HID_ / 2;  // bf16
  unsigned short* sn  = (unsigned short*)(ws + o); o += ROWS * HID_ / 2;  // bf16
  unsigned short* xn  = (unsigned short*)(ws + o); o += ROWS * HID_ / 2;  // bf16
  float* xz    = ws + o; o += ROWS * 2 * DI_;
  float* sp    = ws + o; o += ROWS * 384;
  unsigned short* xa = (unsigned short*)(ws + o); o += ROWS * DI_ / 2;   // bf16
  float* csb   = ws + o; o += ROWS * 256;
  float* x1    = ws + o; o += ROWS * HID_;                                // f32
  unsigned short* dltb = (unsigned short*)(ws + o); o += SCAN_ELEMS / 2;  // bf16
  unsigned short* ybuf = (unsigned short*)(ws + o); o += SCAN_ELEMS / 2;  // bf16; hmid overlays
  unsigned short* ygz  = (unsigned short*)(ws + o); o += ROWS * DI_ / 2;  // bf16
  unsigned short* wt = (unsigned short*)(ws + o);
  unsigned short* inpT = wt;                    // (2048,512)
  unsigned short* styT = inpT + 2048 * 512;     // (384,512)
  unsigned short* conT = styT + 384 * 512;      // (256,1024)
  unsigned short* outT = conT + 256 * 1024;     // (512,1024)
  unsigned short* w1T  = outT + 512 * 1024;     // (2048,512)
  unsigned short* w2T  = w1T + 2048 * 512;      // (512,2048)
  unsigned short* hmid = ybuf;  // 4096x2048 bf16 = 16 MB fits in ybuf's 32 MB

  // all weight transposes in one launch
  transpose_all<<<4032, 256, 0, stream>>>(
      in_proj_w, style_proj_w, content_proj_w, out_proj_w, mlp_w1, mlp_w2,
      inpT, styT, conT, outT, w1T, w2T);

  // norm1 on content and style (one launch, bf16 out)
  ln_kernel<<<dim3(ROWS / 4, 2), 256, 0, stream>>>(content, cn, style, sn, norm1_w, norm1_b);

  // xz = cn @ in_proj (f32 out)
  gemm_kernel<0, 0><<<dim3(2048 / BN, ROWS / BM), 256, 0, stream>>>(
      cn, inpT, xz, ROWS, 2048, 512, nullptr, nullptr);
  // sp = sn @ style_proj (f32 out)
  gemm64_kernel<0, 0><<<dim3(384 / BN, ROWS / 64), 256, 0, stream>>>(
      sn, styT, sp, ROWS, 384, 512, nullptr, nullptr);
  // conv + silu -> xa (bf16)
  conv_kernel<<<(ROWS * DI_) / 256, 256, 0, stream>>>(xz, conv_w, conv_b, xa);
  // Cs = xa @ content_proj (f32 out)
  gemm64_kernel<0, 0><<<dim3(256 / BN, ROWS / 64), 256, 0, stream>>>(
      xa, conT, csb, ROWS, 256, 1024, nullptr, nullptr);
  // delta = softplus(rank @ dtw + bias) -> bf16
  delta_kernel<<<dim3(B_ * K_, DI_ / 256, L_ / 128), 256, 0, stream>>>(sp, dtw, dtb, dltb);
  // selective scan -> ybuf (bf16)
  scan_kernel<<<dim3(DI_ / 32, K_, B_), 512, 0, stream>>>(
      ybuf, xa, sp, csb, dltb, A_logs, Ds);
  // ygz = (sum_k y) * z -> bf16
  fuse_ygz<<<(ROWS * DI_) / (256 * 8), 256, 0, stream>>>(ybuf, xz, ygz);
  // x1 = content + ygz @ out_proj (f32 out)
  gemm64_kernel<1, 0><<<dim3(512 / BN, ROWS / 64), 256, 0, stream>>>(
      ygz, outT, x1, ROWS, 512, 1024, nullptr, content);
  // norm2 (bf16 out)
  ln_kernel<<<dim3(ROWS / 4, 1), 256, 0, stream>>>(x1, xn, nullptr, nullptr, norm2_w, norm2_b);
  // mlp: hmid = gelu(xn @ w1 + b1) (bf16 out); out = x1 + hmid @ w2 + b2 (f32)
  gemm_kernel<2, 1><<<dim3(2048 / BN, ROWS / BM), 256, 0, stream>>>(
      xn, w1T, hmid, ROWS, 2048, 512, mlp_b1, nullptr);
  gemm64_kernel<3, 0><<<dim3(512 / BN, ROWS / 64), 256, 0, stream>>>(
      hmid, w2T, out, ROWS, 512, 2048, mlp_b2, x1);
}

// Round 8
// 559.430 us; speedup vs baseline: 1.2026x; 1.0089x over previous
//
#include <hip/hip_runtime.h>

// ---------------- constants ----------------
#define B_ 4
#define Hh_ 32
#define Ww_ 32
#define L_ 1024
#define HID_ 512
#define DI_ 1024
#define N_ 64
#define R_ 32
#define K_ 4
#define MLP_ 2048

typedef __bf16 bf16x8 __attribute__((ext_vector_type(8)));
typedef float f32x4 __attribute__((ext_vector_type(4)));

__device__ __forceinline__ unsigned short f2bf(float f) {
  unsigned int u = __builtin_bit_cast(unsigned int, f);
  return (unsigned short)((u + 0x7FFFu + ((u >> 16) & 1u)) >> 16);
}
__device__ __forceinline__ float bf2f(unsigned short h) {
  return __builtin_bit_cast(float, (unsigned int)h << 16);
}

// DPP add: x + x[perm(lane)] on the VALU pipe (no DS traffic)
// CTRL: 0xB1 quad xor1, 0x4E quad xor2, 0x124 row_ror:4, 0x128 row_ror:8
template <int CTRL>
__device__ __forceinline__ float dpp_add(float x) {
  int i = __builtin_bit_cast(int, x);
  int j = __builtin_amdgcn_update_dpp(i, i, CTRL, 0xF, 0xF, false);
  return x + __builtin_bit_cast(float, j);
}

// ---------------- all 6 weight transposes in ONE launch ----------------
// src (K,N) f32 -> dst (N,K) bf16
__global__ __launch_bounds__(256) void transpose_all(
    const float* __restrict__ s0, const float* __restrict__ s1,
    const float* __restrict__ s2, const float* __restrict__ s3,
    const float* __restrict__ s4, const float* __restrict__ s5,
    unsigned short* __restrict__ t0, unsigned short* __restrict__ t1,
    unsigned short* __restrict__ t2, unsigned short* __restrict__ t3,
    unsigned short* __restrict__ t4, unsigned short* __restrict__ t5) {
  __shared__ float t[32][33];
  int bid = blockIdx.x;
  const float* src; unsigned short* dst; int K, N, bx, by;
  if (bid < 1024)      { src = s0; dst = t0; K = 512;  N = 2048; int r = bid;        bx = r & 63; by = r >> 6; }
  else if (bid < 1216) { src = s1; dst = t1; K = 512;  N = 384;  int r = bid - 1024; bx = r % 12; by = r / 12; }
  else if (bid < 1472) { src = s2; dst = t2; K = 1024; N = 256;  int r = bid - 1216; bx = r & 7;  by = r >> 3; }
  else if (bid < 1984) { src = s3; dst = t3; K = 1024; N = 512;  int r = bid - 1472; bx = r & 15; by = r >> 4; }
  else if (bid < 3008) { src = s4; dst = t4; K = 512;  N = 2048; int r = bid - 1984; bx = r & 63; by = r >> 6; }
  else                 { src = s5; dst = t5; K = 2048; N = 512;  int r = bid - 3008; bx = r & 15; by = r >> 4; }
  int nb = bx * 32, kb = by * 32;
  int tx = threadIdx.x & 31, ty = threadIdx.x >> 5;
  for (int r = ty; r < 32; r += 8) t[r][tx] = src[(size_t)(kb + r) * N + nb + tx];
  __syncthreads();
  for (int r = ty; r < 32; r += 8) dst[(size_t)(nb + r) * K + kb + tx] = f2bf(t[tx][r]);
}

// ---------------- LayerNorm over 512, wave per row; writes bf16 ----------------
__global__ __launch_bounds__(256) void ln_kernel(
    const float* __restrict__ in0, unsigned short* __restrict__ out0,
    const float* __restrict__ in1, unsigned short* __restrict__ out1,
    const float* __restrict__ w, const float* __restrict__ bb) {
  const float* in = blockIdx.y ? in1 : in0;
  unsigned short* out = blockIdx.y ? out1 : out0;
  int row = blockIdx.x * 4 + (threadIdx.x >> 6);
  int lane = threadIdx.x & 63;
  const float* p = in + (size_t)row * HID_;
  float4 v0 = *(const float4*)(p + lane * 4);
  float4 v1 = *(const float4*)(p + 256 + lane * 4);
  float s = v0.x + v0.y + v0.z + v0.w + v1.x + v1.y + v1.z + v1.w;
  float q = v0.x * v0.x + v0.y * v0.y + v0.z * v0.z + v0.w * v0.w +
            v1.x * v1.x + v1.y * v1.y + v1.z * v1.z + v1.w * v1.w;
  #pragma unroll
  for (int m = 1; m < 64; m <<= 1) { s += __shfl_xor(s, m, 64); q += __shfl_xor(q, m, 64); }
  float mean = s * (1.f / 512.f);
  float var = q * (1.f / 512.f) - mean * mean;
  float rstd = rsqrtf(var + 1e-5f);
  float4 w0 = *(const float4*)(w + lane * 4);
  float4 w1 = *(const float4*)(w + 256 + lane * 4);
  float4 b0 = *(const float4*)(bb + lane * 4);
  float4 b1 = *(const float4*)(bb + 256 + lane * 4);
  unsigned short* o = out + (size_t)row * HID_;
  ushort4 r0, r1;
  r0.x = f2bf((v0.x - mean) * rstd * w0.x + b0.x);
  r0.y = f2bf((v0.y - mean) * rstd * w0.y + b0.y);
  r0.z = f2bf((v0.z - mean) * rstd * w0.z + b0.z);
  r0.w = f2bf((v0.w - mean) * rstd * w0.w + b0.w);
  r1.x = f2bf((v1.x - mean) * rstd * w1.x + b1.x);
  r1.y = f2bf((v1.y - mean) * rstd * w1.y + b1.y);
  r1.z = f2bf((v1.z - mean) * rstd * w1.z + b1.z);
  r1.w = f2bf((v1.w - mean) * rstd * w1.w + b1.w);
  *(ushort4*)(o + lane * 4) = r0;
  *(ushort4*)(o + 256 + lane * 4) = r1;
}

// ---------------- MFMA GEMM 128x128: A (M,K) bf16, BT (N,K) bf16 ----------------
// EPI: 0 = plain, 1 = +resid, 2 = +bias then exact gelu, 3 = +bias +resid
// OUTBF: 1 -> C is bf16, else f32
#define BM 128
#define BN 128
#define BK 32
#define LST 40  // LDS row stride in bf16 units

template <int EPI, int OUTBF>
__global__ __launch_bounds__(256) void gemm_kernel(
    const unsigned short* __restrict__ A, const unsigned short* __restrict__ BT,
    void* __restrict__ Cv, int M, int N, int K,
    const float* __restrict__ bias, const float* __restrict__ resid) {
  __shared__ __align__(16) unsigned short As[BM * LST];
  __shared__ __align__(16) unsigned short Bs[BN * LST];
  int tid = threadIdx.x;
  int lane = tid & 63, wv = tid >> 6;
  int wm = wv >> 1, wn = wv & 1;
  int m0 = blockIdx.y * BM, n0 = blockIdx.x * BN;
  f32x4 acc[4][4] = {};
  int sr = tid >> 1, sc = (tid & 1) * 16;
  int kk = (lane >> 4) * 8;
  int rA = wm * 64 + (lane & 15);
  int rB = wn * 64 + (lane & 15);
  for (int k0 = 0; k0 < K; k0 += BK) {
    __syncthreads();
    {
      uint4 a0 = *(const uint4*)(A + (size_t)(m0 + sr) * K + k0 + sc);
      uint4 a1 = *(const uint4*)(A + (size_t)(m0 + sr) * K + k0 + sc + 8);
      *(uint4*)&As[sr * LST + sc] = a0;
      *(uint4*)&As[sr * LST + sc + 8] = a1;
      uint4 b0 = *(const uint4*)(BT + (size_t)(n0 + sr) * K + k0 + sc);
      uint4 b1 = *(const uint4*)(BT + (size_t)(n0 + sr) * K + k0 + sc + 8);
      *(uint4*)&Bs[sr * LST + sc] = b0;
      *(uint4*)&Bs[sr * LST + sc + 8] = b1;
    }
    __syncthreads();
    bf16x8 fa[4], fb[4];
    #pragma unroll
    for (int i = 0; i < 4; ++i) {
      fa[i] = *(const bf16x8*)&As[(rA + i * 16) * LST + kk];
      fb[i] = *(const bf16x8*)&Bs[(rB + i * 16) * LST + kk];
    }
    #pragma unroll
    for (int i = 0; i < 4; ++i)
      #pragma unroll
      for (int j = 0; j < 4; ++j)
        acc[i][j] = __builtin_amdgcn_mfma_f32_16x16x32_bf16(fa[i], fb[j], acc[i][j], 0, 0, 0);
  }
  int crow0 = m0 + wm * 64 + (lane >> 4) * 4, ccol0 = n0 + wn * 64 + (lane & 15);
  #pragma unroll
  for (int i = 0; i < 4; ++i) {
    #pragma unroll
    for (int j = 0; j < 4; ++j) {
      int col = ccol0 + j * 16;
      #pragma unroll
      for (int r = 0; r < 4; ++r) {
        int row = crow0 + i * 16 + r;
        float v = acc[i][j][r];
        if (EPI == 1) v += resid[(size_t)row * N + col];
        if (EPI == 2) { v += bias[col]; v = 0.5f * v * (1.f + erff(v * 0.70710678f)); }
        if (EPI == 3) v += bias[col] + resid[(size_t)row * N + col];
        if (OUTBF) ((unsigned short*)Cv)[(size_t)row * N + col] = f2bf(v);
        else       ((float*)Cv)[(size_t)row * N + col] = v;
      }
    }
  }
}

// ---------------- MFMA GEMM 64x128 ----------------
template <int EPI, int OUTBF>
__global__ __launch_bounds__(256) void gemm64_kernel(
    const unsigned short* __restrict__ A, const unsigned short* __restrict__ BT,
    void* __restrict__ Cv, int M, int N, int K,
    const float* __restrict__ bias, const float* __restrict__ resid) {
  __shared__ __align__(16) unsigned short As[64 * LST];
  __shared__ __align__(16) unsigned short Bs[128 * LST];
  int tid = threadIdx.x;
  int lane = tid & 63, wv = tid >> 6;
  int wm = wv >> 1, wn = wv & 1;
  int m0 = blockIdx.y * 64, n0 = blockIdx.x * BN;
  f32x4 acc[2][4] = {};
  int srA = tid >> 2, scA = (tid & 3) * 8;
  int srB = tid >> 1, scB = (tid & 1) * 16;
  int kk = (lane >> 4) * 8;
  int rA = wm * 32 + (lane & 15);
  int rB = wn * 64 + (lane & 15);
  for (int k0 = 0; k0 < K; k0 += BK) {
    __syncthreads();
    {
      uint4 a0 = *(const uint4*)(A + (size_t)(m0 + srA) * K + k0 + scA);
      *(uint4*)&As[srA * LST + scA] = a0;
      uint4 b0 = *(const uint4*)(BT + (size_t)(n0 + srB) * K + k0 + scB);
      uint4 b1 = *(const uint4*)(BT + (size_t)(n0 + srB) * K + k0 + scB + 8);
      *(uint4*)&Bs[srB * LST + scB] = b0;
      *(uint4*)&Bs[srB * LST + scB + 8] = b1;
    }
    __syncthreads();
    bf16x8 fa[2], fb[4];
    #pragma unroll
    for (int i = 0; i < 2; ++i) fa[i] = *(const bf16x8*)&As[(rA + i * 16) * LST + kk];
    #pragma unroll
    for (int j = 0; j < 4; ++j) fb[j] = *(const bf16x8*)&Bs[(rB + j * 16) * LST + kk];
    #pragma unroll
    for (int i = 0; i < 2; ++i)
      #pragma unroll
      for (int j = 0; j < 4; ++j)
        acc[i][j] = __builtin_amdgcn_mfma_f32_16x16x32_bf16(fa[i], fb[j], acc[i][j], 0, 0, 0);
  }
  int crow0 = m0 + wm * 32 + (lane >> 4) * 4, ccol0 = n0 + wn * 64 + (lane & 15);
  #pragma unroll
  for (int i = 0; i < 2; ++i) {
    #pragma unroll
    for (int j = 0; j < 4; ++j) {
      int col = ccol0 + j * 16;
      #pragma unroll
      for (int r = 0; r < 4; ++r) {
        int row = crow0 + i * 16 + r;
        float v = acc[i][j][r];
        if (EPI == 1) v += resid[(size_t)row * N + col];
        if (EPI == 2) { v += bias[col]; v = 0.5f * v * (1.f + erff(v * 0.70710678f)); }
        if (EPI == 3) v += bias[col] + resid[(size_t)row * N + col];
        if (OUTBF) ((unsigned short*)Cv)[(size_t)row * N + col] = f2bf(v);
        else       ((float*)Cv)[(size_t)row * N + col] = v;
      }
    }
  }
}

// ---------------- depthwise 3x3 conv + bias + SiLU; writes bf16 xa ----------------
__global__ __launch_bounds__(256) void conv_kernel(
    const float* __restrict__ xz, const float* __restrict__ cw,
    const float* __restrict__ cb, unsigned short* __restrict__ xa) {
  int idx = blockIdx.x * 256 + threadIdx.x;  // (b,l,d), d fastest
  int d = idx & (DI_ - 1);
  int l = (idx >> 10) & (L_ - 1);
  int b = idx >> 20;
  int hh = l >> 5, ww = l & 31;
  float acc = cb[d];
  #pragma unroll
  for (int dh = -1; dh <= 1; ++dh) {
    int y = hh + dh;
    if ((unsigned)y >= 32u) continue;
    #pragma unroll
    for (int dw = -1; dw <= 1; ++dw) {
      int x = ww + dw;
      if ((unsigned)x >= 32u) continue;
      acc = fmaf(xz[((size_t)b * L_ + y * 32 + x) * (2 * DI_) + d],
                 cw[d * 9 + (dh + 1) * 3 + (dw + 1)], acc);
    }
  }
  float sv = acc / (1.f + __expf(-acc));
  xa[idx] = f2bf(sv);
}

// ---------------- dt projection + softplus -> delta [b][k][l][d] (bf16) ----------------
__global__ __launch_bounds__(256) void delta_kernel(
    const float* __restrict__ sp, const float* __restrict__ dtw,
    const float* __restrict__ dtb, unsigned short* __restrict__ delta) {
  int bk = blockIdx.x;
  int b = bk >> 2, k = bk & 3;
  int dc = blockIdx.y * 256;
  int l0 = blockIdx.z * 128;
  __shared__ float wl[32 * 257];
  __shared__ float rl[128 * 32];
  int tid = threadIdx.x;
  for (int i = tid; i < 256 * 32; i += 256) {
    int dl = i >> 5, r = i & 31;
    wl[r * 257 + dl] = dtw[((size_t)k * DI_ + dc + dl) * R_ + r];
  }
  for (int i = tid; i < 128 * 32; i += 256) {
    int ll = i >> 5, r = i & 31;
    rl[ll * 32 + r] = sp[((size_t)b * L_ + l0 + ll) * 384 + k * R_ + r];
  }
  __syncthreads();
  float bias = dtb[k * DI_ + dc + tid];
  for (int ll = 0; ll < 128; ++ll) {
    float acc = bias;
    #pragma unroll
    for (int r = 0; r < 32; ++r)
      acc = fmaf(rl[ll * 32 + r], wl[r * 257 + tid], acc);
    float dlt = (acc > 15.f) ? acc : log1pf(__expf(acc));
    delta[(((size_t)(b * 4 + k) * L_) + l0 + ll) * DI_ + dc + tid] = f2bf(dlt);
  }
}

// ---------------- selective scan: DS-minimized (2.5 DS/step), all-DPP reduce ----------------
// lane = dg*16 + ng: dg = lane>>4 (4 d per wave), ng = lane&15 (4 n per lane).
// Block: 512 thr = 8 waves = 32 d. Grid (DI/32, K, B) = 512 blocks -> 2 blk/CU, 4 wv/SIMD.
// DS per step: b128 B(f32) + b128 C(f32) + 0.5x b128 DLU (two steps per read). No swizzle.
// Reduce over 16 ng lanes: row_ror:4 + row_ror:8 + quad xor1 + quad xor2 (all VALU DPP).
#define CH 16
#define NCH (L_ / CH)
#define DLP 36  // DLU row stride in floats: 144B = 16B-aligned, banks shift 4/d
__global__ __launch_bounds__(512) void scan_kernel(
    unsigned short* __restrict__ ybuf, const unsigned short* __restrict__ xa,
    const float* __restrict__ sp, const float* __restrict__ Cs,
    const unsigned short* __restrict__ dltb,
    const float* __restrict__ A_logs, const float* __restrict__ Ds) {
  int dblk = blockIdx.x;  // 32 blocks of 32 d's
  int k = blockIdx.y, b = blockIdx.z;
  int tid = threadIdx.x, lane = tid & 63, wv = tid >> 6;
  int dg = lane >> 4, ng = lane & 15;
  int wd = wv * 4 + dg;                // d within block's 32
  int gd = k * DI_ + dblk * 32 + wd;
  float a2[4], h[4];
  #pragma unroll
  for (int j = 0; j < 4; ++j) {
    a2[j] = -__expf(A_logs[(size_t)gd * N_ + ng * 4 + j]) * 1.44269504f;
    h[j] = 0.f;
  }
  float dsv = Ds[gd];

  __shared__ float Bsh[2][CH][64];
  __shared__ float Csh[2][CH][64];
  __shared__ float DLU[2][32][DLP];  // per d: (dlt,u) pairs for CH steps (32 floats) + pad

  const size_t spB = (size_t)b * L_ * 384 + 128 + k * 64;
  const size_t csB = (size_t)b * L_ * 256 + k * 64;
  const size_t dlB = ((size_t)(b * 4 + k) * L_) * DI_ + dblk * 32;
  const size_t xaB = (size_t)b * L_ * DI_ + dblk * 32;

  // staging: liS = step row (16), js = 0..31 (n-pair for B/C, d for DLU)
  int liS = tid >> 5, js = tid & 31;
  auto posf = [&](int l) {
    int lr = 1023 - l;
    return (k == 0) ? l
         : (k == 1) ? ((l & 31) * 32 + (l >> 5))
         : (k == 2) ? lr
                    : ((lr & 31) * 32 + (lr >> 5));
  };

  // stage chunk 0
  {
    *(float2*)&Bsh[0][liS][js * 2] = *(const float2*)(sp + spB + (size_t)liS * 384 + js * 2);
    *(float2*)&Csh[0][liS][js * 2] = *(const float2*)(Cs + csB + (size_t)liS * 256 + js * 2);
    float dlt = bf2f(dltb[dlB + (size_t)liS * DI_ + js]);
    float u = bf2f(xa[xaB + (size_t)posf(liS) * DI_ + js]);
    float2 p; p.x = dlt; p.y = u;
    *(float2*)&DLU[0][js][liS * 2] = p;
  }
  __syncthreads();

  int cur = 0;
  for (int c = 0; c < NCH; ++c) {
    float2 pB, pC;
    unsigned short pD, pU;
    if (c < NCH - 1) {  // prefetch chunk c+1 into registers
      int lb = (c + 1) * CH + liS;
      pB = *(const float2*)(sp + spB + (size_t)lb * 384 + js * 2);
      pC = *(const float2*)(Cs + csB + (size_t)lb * 256 + js * 2);
      pD = dltb[dlB + (size_t)lb * DI_ + js];
      pU = xa[xaB + (size_t)posf(lb) * DI_ + js];
    }
    #pragma unroll
    for (int li2 = 0; li2 < CH; li2 += 2) {
      float4 duq = *(const float4*)&DLU[cur][wd][li2 * 2];  // (dlt,u) for li2, li2+1
      #pragma unroll
      for (int s = 0; s < 2; ++s) {
        int li = li2 + s;
        float dlt = s ? duq.z : duq.x;
        float u   = s ? duq.w : duq.y;
        float du = dlt * u;
        float4 bq = *(const float4*)&Bsh[cur][li][ng * 4];
        float4 cq = *(const float4*)&Csh[cur][li][ng * 4];
        float yp;
        {
          float e = __builtin_amdgcn_exp2f(dlt * a2[0]);
          h[0] = fmaf(e, h[0], du * bq.x); yp = h[0] * cq.x;
        }
        {
          float e = __builtin_amdgcn_exp2f(dlt * a2[1]);
          h[1] = fmaf(e, h[1], du * bq.y); yp = fmaf(h[1], cq.y, yp);
        }
        {
          float e = __builtin_amdgcn_exp2f(dlt * a2[2]);
          h[2] = fmaf(e, h[2], du * bq.z); yp = fmaf(h[2], cq.z, yp);
        }
        {
          float e = __builtin_amdgcn_exp2f(dlt * a2[3]);
          h[3] = fmaf(e, h[3], du * bq.w); yp = fmaf(h[3], cq.w, yp);
        }
        // 16-lane reduce, all on VALU: two row rotations + two quad perms
        yp = dpp_add<0x124>(yp);  // row_ror:4
        yp = dpp_add<0x128>(yp);  // row_ror:8
        yp = dpp_add<0xB1>(yp);   // quad_perm xor1
        yp = dpp_add<0x4E>(yp);   // quad_perm xor2
        if (ng == 0) {  // lanes 0,16,32,48 -> d = wv*4 + 0..3
          ybuf[dlB + (size_t)(c * CH + li) * DI_ + wd] = f2bf(fmaf(u, dsv, yp));
        }
      }
    }
    __syncthreads();  // chunk consumed
    if (c < NCH - 1) {
      int nxt = cur ^ 1;
      *(float2*)&Bsh[nxt][liS][js * 2] = pB;
      *(float2*)&Csh[nxt][liS][js * 2] = pC;
      float2 p; p.x = bf2f(pD); p.y = bf2f(pU);
      *(float2*)&DLU[nxt][js][liS * 2] = p;
    }
    __syncthreads();  // staging visible
    cur ^= 1;
  }
}

// ---------------- fuse: ygz = (sum_k yk) * z  -> bf16 ----------------
__global__ __launch_bounds__(256) void fuse_ygz(
    const unsigned short* __restrict__ yk, const float* __restrict__ xz,
    unsigned short* __restrict__ ygz) {
  size_t i = ((size_t)blockIdx.x * 256 + threadIdx.x) * 8;  // 8 d per thread
  size_t b = i >> 20, ld = i & ((1u << 20) - 1);
  float acc[8] = {};
  #pragma unroll
  for (int k = 0; k < 4; ++k) {
    uint4 v = *(const uint4*)(yk + ((size_t)(b * 4 + k) << 20) + ld);
    unsigned int w[4] = {v.x, v.y, v.z, v.w};
    #pragma unroll
    for (int t = 0; t < 4; ++t) {
      acc[t * 2 + 0] += __builtin_bit_cast(float, w[t] << 16);
      acc[t * 2 + 1] += __builtin_bit_cast(float, w[t] & 0xFFFF0000u);
    }
  }
  const float* zp = xz + (i >> 10) * (2 * DI_) + DI_ + (i & (DI_ - 1));
  float4 z0 = *(const float4*)zp;
  float4 z1 = *(const float4*)(zp + 4);
  uint4 o;
  o.x = (unsigned int)f2bf(acc[0] * z0.x) | ((unsigned int)f2bf(acc[1] * z0.y) << 16);
  o.y = (unsigned int)f2bf(acc[2] * z0.z) | ((unsigned int)f2bf(acc[3] * z0.w) << 16);
  o.z = (unsigned int)f2bf(acc[4] * z1.x) | ((unsigned int)f2bf(acc[5] * z1.y) << 16);
  o.w = (unsigned int)f2bf(acc[6] * z1.z) | ((unsigned int)f2bf(acc[7] * z1.w) << 16);
  *(uint4*)(ygz + i) = o;
}

// ---------------- host ----------------
extern "C" void kernel_launch(void* const* d_in, const int* in_sizes, int n_in,
                              void* d_out, int out_size, void* d_ws, size_t ws_size,
                              hipStream_t stream) {
  (void)in_sizes; (void)n_in; (void)out_size; (void)ws_size;
  const float* content   = (const float*)d_in[0];
  const float* style     = (const float*)d_in[1];
  const float* norm1_w   = (const float*)d_in[2];
  const float* norm1_b   = (const float*)d_in[3];
  const float* in_proj_w = (const float*)d_in[4];
  const float* conv_w    = (const float*)d_in[5];
  const float* conv_b    = (const float*)d_in[6];
  const float* style_proj_w   = (const float*)d_in[7];
  const float* content_proj_w = (const float*)d_in[8];
  const float* dtw       = (const float*)d_in[9];
  const float* dtb       = (const float*)d_in[10];
  const float* A_logs    = (const float*)d_in[11];
  const float* Ds        = (const float*)d_in[12];
  const float* out_proj_w = (const float*)d_in[13];
  const float* norm2_w   = (const float*)d_in[14];
  const float* norm2_b   = (const float*)d_in[15];
  const float* mlp_w1    = (const float*)d_in[16];
  const float* mlp_b1    = (const float*)d_in[17];
  const float* mlp_w2    = (const float*)d_in[18];
  const float* mlp_b2    = (const float*)d_in[19];
  float* out = (float*)d_out;

  float* ws = (float*)d_ws;
  const size_t ROWS = (size_t)B_ * L_;  // 4096
  const size_t SCAN_ELEMS = (size_t)B_ * K_ * L_ * DI_;  // 16.78M
  size_t o = 0;
  unsigned short* cn  = (unsigned short*)(ws + o); o += ROWS * HID_ / 2;  // bf16
  unsigned short* sn  = (unsigned short*)(ws + o); o += ROWS * HID_ / 2;  // bf16
  unsigned short* xn  = (unsigned short*)(ws + o); o += ROWS * HID_ / 2;  // bf16
  float* xz    = ws + o; o += ROWS * 2 * DI_;
  float* sp    = ws + o; o += ROWS * 384;
  unsigned short* xa = (unsigned short*)(ws + o); o += ROWS * DI_ / 2;   // bf16
  float* csb   = ws + o; o += ROWS * 256;
  float* x1    = ws + o; o += ROWS * HID_;                                // f32
  unsigned short* dltb = (unsigned short*)(ws + o); o += SCAN_ELEMS / 2;  // bf16
  unsigned short* ybuf = (unsigned short*)(ws + o); o += SCAN_ELEMS / 2;  // bf16; hmid overlays
  unsigned short* ygz  = (unsigned short*)(ws + o); o += ROWS * DI_ / 2;  // bf16
  unsigned short* wt = (unsigned short*)(ws + o);
  unsigned short* inpT = wt;                    // (2048,512)
  unsigned short* styT = inpT + 2048 * 512;     // (384,512)
  unsigned short* conT = styT + 384 * 512;      // (256,1024)
  unsigned short* outT = conT + 256 * 1024;     // (512,1024)
  unsigned short* w1T  = outT + 512 * 1024;     // (2048,512)
  unsigned short* w2T  = w1T + 2048 * 512;      // (512,2048)
  unsigned short* hmid = ybuf;  // 4096x2048 bf16 = 16 MB fits in ybuf's 32 MB

  // all weight transposes in one launch
  transpose_all<<<4032, 256, 0, stream>>>(
      in_proj_w, style_proj_w, content_proj_w, out_proj_w, mlp_w1, mlp_w2,
      inpT, styT, conT, outT, w1T, w2T);

  // norm1 on content and style (one launch, bf16 out)
  ln_kernel<<<dim3(ROWS / 4, 2), 256, 0, stream>>>(content, cn, style, sn, norm1_w, norm1_b);

  // xz = cn @ in_proj (f32 out)
  gemm_kernel<0, 0><<<dim3(2048 / BN, ROWS / BM), 256, 0, stream>>>(
      cn, inpT, xz, ROWS, 2048, 512, nullptr, nullptr);
  // sp = sn @ style_proj (f32 out)
  gemm64_kernel<0, 0><<<dim3(384 / BN, ROWS / 64), 256, 0, stream>>>(
      sn, styT, sp, ROWS, 384, 512, nullptr, nullptr);
  // conv + silu -> xa (bf16)
  conv_kernel<<<(ROWS * DI_) / 256, 256, 0, stream>>>(xz, conv_w, conv_b, xa);
  // Cs = xa @ content_proj (f32 out)
  gemm64_kernel<0, 0><<<dim3(256 / BN, ROWS / 64), 256, 0, stream>>>(
      xa, conT, csb, ROWS, 256, 1024, nullptr, nullptr);
  // delta = softplus(rank @ dtw + bias) -> bf16
  delta_kernel<<<dim3(B_ * K_, DI_ / 256, L_ / 128), 256, 0, stream>>>(sp, dtw, dtb, dltb);
  // selective scan -> ybuf (bf16)
  scan_kernel<<<dim3(DI_ / 32, K_, B_), 512, 0, stream>>>(
      ybuf, xa, sp, csb, dltb, A_logs, Ds);
  // ygz = (sum_k y) * z -> bf16
  fuse_ygz<<<(ROWS * DI_) / (256 * 8), 256, 0, stream>>>(ybuf, xz, ygz);
  // x1 = content + ygz @ out_proj (f32 out)
  gemm64_kernel<1, 0><<<dim3(512 / BN, ROWS / 64), 256, 0, stream>>>(
      ygz, outT, x1, ROWS, 512, 1024, nullptr, content);
  // norm2 (bf16 out)
  ln_kernel<<<dim3(ROWS / 4, 1), 256, 0, stream>>>(x1, xn, nullptr, nullptr, norm2_w, norm2_b);
  // mlp: hmid = gelu(xn @ w1 + b1) (bf16 out); out = x1 + hmid @ w2 + b2 (f32)
  gemm_kernel<2, 1><<<dim3(2048 / BN, ROWS / BM), 256, 0, stream>>>(
      xn, w1T, hmid, ROWS, 2048, 512, mlp_b1, nullptr);
  gemm64_kernel<3, 0><<<dim3(512 / BN, ROWS / 64), 256, 0, stream>>>(
      hmid, w2T, out, ROWS, 512, 2048, mlp_b2, x1);
}

// Round 9
// 546.958 us; speedup vs baseline: 1.2300x; 1.0228x over previous
//
#include <hip/hip_runtime.h>

// ---------------- constants ----------------
#define B_ 4
#define Hh_ 32
#define Ww_ 32
#define L_ 1024
#define HID_ 512
#define DI_ 1024
#define N_ 64
#define R_ 32
#define K_ 4
#define MLP_ 2048

typedef __bf16 bf16x8 __attribute__((ext_vector_type(8)));
typedef float f32x4 __attribute__((ext_vector_type(4)));
typedef float v2f __attribute__((ext_vector_type(2)));

__device__ __forceinline__ unsigned short f2bf(float f) {
  unsigned int u = __builtin_bit_cast(unsigned int, f);
  return (unsigned short)((u + 0x7FFFu + ((u >> 16) & 1u)) >> 16);
}
__device__ __forceinline__ float bf2f(unsigned short h) {
  return __builtin_bit_cast(float, (unsigned int)h << 16);
}

// DPP add: x + x[perm(lane)] on the VALU pipe (no DS traffic)
template <int CTRL>
__device__ __forceinline__ float dpp_add(float x) {
  int i = __builtin_bit_cast(int, x);
  int j = __builtin_amdgcn_update_dpp(i, i, CTRL, 0xF, 0xF, false);
  return x + __builtin_bit_cast(float, j);
}

// ---------------- all 6 weight transposes in ONE launch ----------------
__global__ __launch_bounds__(256) void transpose_all(
    const float* __restrict__ s0, const float* __restrict__ s1,
    const float* __restrict__ s2, const float* __restrict__ s3,
    const float* __restrict__ s4, const float* __restrict__ s5,
    unsigned short* __restrict__ t0, unsigned short* __restrict__ t1,
    unsigned short* __restrict__ t2, unsigned short* __restrict__ t3,
    unsigned short* __restrict__ t4, unsigned short* __restrict__ t5) {
  __shared__ float t[32][33];
  int bid = blockIdx.x;
  const float* src; unsigned short* dst; int K, N, bx, by;
  if (bid < 1024)      { src = s0; dst = t0; K = 512;  N = 2048; int r = bid;        bx = r & 63; by = r >> 6; }
  else if (bid < 1216) { src = s1; dst = t1; K = 512;  N = 384;  int r = bid - 1024; bx = r % 12; by = r / 12; }
  else if (bid < 1472) { src = s2; dst = t2; K = 1024; N = 256;  int r = bid - 1216; bx = r & 7;  by = r >> 3; }
  else if (bid < 1984) { src = s3; dst = t3; K = 1024; N = 512;  int r = bid - 1472; bx = r & 15; by = r >> 4; }
  else if (bid < 3008) { src = s4; dst = t4; K = 512;  N = 2048; int r = bid - 1984; bx = r & 63; by = r >> 6; }
  else                 { src = s5; dst = t5; K = 2048; N = 512;  int r = bid - 3008; bx = r & 15; by = r >> 4; }
  int nb = bx * 32, kb = by * 32;
  int tx = threadIdx.x & 31, ty = threadIdx.x >> 5;
  for (int r = ty; r < 32; r += 8) t[r][tx] = src[(size_t)(kb + r) * N + nb + tx];
  __syncthreads();
  for (int r = ty; r < 32; r += 8) dst[(size_t)(nb + r) * K + kb + tx] = f2bf(t[tx][r]);
}

// ---------------- LayerNorm over 512, wave per row; writes bf16 ----------------
__global__ __launch_bounds__(256) void ln_kernel(
    const float* __restrict__ in0, unsigned short* __restrict__ out0,
    const float* __restrict__ in1, unsigned short* __restrict__ out1,
    const float* __restrict__ w, const float* __restrict__ bb) {
  const float* in = blockIdx.y ? in1 : in0;
  unsigned short* out = blockIdx.y ? out1 : out0;
  int row = blockIdx.x * 4 + (threadIdx.x >> 6);
  int lane = threadIdx.x & 63;
  const float* p = in + (size_t)row * HID_;
  float4 v0 = *(const float4*)(p + lane * 4);
  float4 v1 = *(const float4*)(p + 256 + lane * 4);
  float s = v0.x + v0.y + v0.z + v0.w + v1.x + v1.y + v1.z + v1.w;
  float q = v0.x * v0.x + v0.y * v0.y + v0.z * v0.z + v0.w * v0.w +
            v1.x * v1.x + v1.y * v1.y + v1.z * v1.z + v1.w * v1.w;
  #pragma unroll
  for (int m = 1; m < 64; m <<= 1) { s += __shfl_xor(s, m, 64); q += __shfl_xor(q, m, 64); }
  float mean = s * (1.f / 512.f);
  float var = q * (1.f / 512.f) - mean * mean;
  float rstd = rsqrtf(var + 1e-5f);
  float4 w0 = *(const float4*)(w + lane * 4);
  float4 w1 = *(const float4*)(w + 256 + lane * 4);
  float4 b0 = *(const float4*)(bb + lane * 4);
  float4 b1 = *(const float4*)(bb + 256 + lane * 4);
  unsigned short* o = out + (size_t)row * HID_;
  ushort4 r0, r1;
  r0.x = f2bf((v0.x - mean) * rstd * w0.x + b0.x);
  r0.y = f2bf((v0.y - mean) * rstd * w0.y + b0.y);
  r0.z = f2bf((v0.z - mean) * rstd * w0.z + b0.z);
  r0.w = f2bf((v0.w - mean) * rstd * w0.w + b0.w);
  r1.x = f2bf((v1.x - mean) * rstd * w1.x + b1.x);
  r1.y = f2bf((v1.y - mean) * rstd * w1.y + b1.y);
  r1.z = f2bf((v1.z - mean) * rstd * w1.z + b1.z);
  r1.w = f2bf((v1.w - mean) * rstd * w1.w + b1.w);
  *(ushort4*)(o + lane * 4) = r0;
  *(ushort4*)(o + 256 + lane * 4) = r1;
}

// ---------------- MFMA GEMM 128x128, BK=64: A (M,K) bf16, BT (N,K) bf16 ----------------
// EPI: 0 = plain, 1 = +resid, 2 = +bias exact gelu, 3 = +bias +resid; OUTBF: bf16 C
#define BM 128
#define BN 128
#define BK 64
#define LST 72  // LDS row stride in bf16 units (144B; 2-way bank pattern, free)

template <int EPI, int OUTBF>
__global__ __launch_bounds__(256) void gemm_kernel(
    const unsigned short* __restrict__ A, const unsigned short* __restrict__ BT,
    void* __restrict__ Cv, int M, int N, int K,
    const float* __restrict__ bias, const float* __restrict__ resid) {
  __shared__ __align__(16) unsigned short As[BM * LST];
  __shared__ __align__(16) unsigned short Bs[BN * LST];
  int tid = threadIdx.x;
  int lane = tid & 63, wv = tid >> 6;
  int wm = wv >> 1, wn = wv & 1;
  int m0 = blockIdx.y * BM, n0 = blockIdx.x * BN;
  f32x4 acc[4][4] = {};
  int sr = tid >> 1, sc = (tid & 1) * 32;
  int rA = wm * 64 + (lane & 15);
  int rB = wn * 64 + (lane & 15);
  for (int k0 = 0; k0 < K; k0 += BK) {
    __syncthreads();
    {
      const unsigned short* Ap = A + (size_t)(m0 + sr) * K + k0 + sc;
      uint4 a0 = *(const uint4*)(Ap);
      uint4 a1 = *(const uint4*)(Ap + 8);
      uint4 a2 = *(const uint4*)(Ap + 16);
      uint4 a3 = *(const uint4*)(Ap + 24);
      unsigned short* Asp = &As[sr * LST + sc];
      *(uint4*)(Asp) = a0; *(uint4*)(Asp + 8) = a1;
      *(uint4*)(Asp + 16) = a2; *(uint4*)(Asp + 24) = a3;
      const unsigned short* Bp = BT + (size_t)(n0 + sr) * K + k0 + sc;
      uint4 b0 = *(const uint4*)(Bp);
      uint4 b1 = *(const uint4*)(Bp + 8);
      uint4 b2 = *(const uint4*)(Bp + 16);
      uint4 b3 = *(const uint4*)(Bp + 24);
      unsigned short* Bsp = &Bs[sr * LST + sc];
      *(uint4*)(Bsp) = b0; *(uint4*)(Bsp + 8) = b1;
      *(uint4*)(Bsp + 16) = b2; *(uint4*)(Bsp + 24) = b3;
    }
    __syncthreads();
    #pragma unroll
    for (int kx = 0; kx < 2; ++kx) {
      int kk = (lane >> 4) * 8 + kx * 32;
      bf16x8 fa[4], fb[4];
      #pragma unroll
      for (int i = 0; i < 4; ++i) {
        fa[i] = *(const bf16x8*)&As[(rA + i * 16) * LST + kk];
        fb[i] = *(const bf16x8*)&Bs[(rB + i * 16) * LST + kk];
      }
      #pragma unroll
      for (int i = 0; i < 4; ++i)
        #pragma unroll
        for (int j = 0; j < 4; ++j)
          acc[i][j] = __builtin_amdgcn_mfma_f32_16x16x32_bf16(fa[i], fb[j], acc[i][j], 0, 0, 0);
    }
  }
  int crow0 = m0 + wm * 64 + (lane >> 4) * 4, ccol0 = n0 + wn * 64 + (lane & 15);
  #pragma unroll
  for (int i = 0; i < 4; ++i) {
    #pragma unroll
    for (int j = 0; j < 4; ++j) {
      int col = ccol0 + j * 16;
      #pragma unroll
      for (int r = 0; r < 4; ++r) {
        int row = crow0 + i * 16 + r;
        float v = acc[i][j][r];
        if (EPI == 1) v += resid[(size_t)row * N + col];
        if (EPI == 2) { v += bias[col]; v = 0.5f * v * (1.f + erff(v * 0.70710678f)); }
        if (EPI == 3) v += bias[col] + resid[(size_t)row * N + col];
        if (OUTBF) ((unsigned short*)Cv)[(size_t)row * N + col] = f2bf(v);
        else       ((float*)Cv)[(size_t)row * N + col] = v;
      }
    }
  }
}

// ---------------- MFMA GEMM 64x128, BK=64 ----------------
template <int EPI, int OUTBF>
__global__ __launch_bounds__(256) void gemm64_kernel(
    const unsigned short* __restrict__ A, const unsigned short* __restrict__ BT,
    void* __restrict__ Cv, int M, int N, int K,
    const float* __restrict__ bias, const float* __restrict__ resid) {
  __shared__ __align__(16) unsigned short As[64 * LST];
  __shared__ __align__(16) unsigned short Bs[128 * LST];
  int tid = threadIdx.x;
  int lane = tid & 63, wv = tid >> 6;
  int wm = wv >> 1, wn = wv & 1;
  int m0 = blockIdx.y * 64, n0 = blockIdx.x * BN;
  f32x4 acc[2][4] = {};
  int srA = tid >> 2, scA = (tid & 3) * 16;
  int srB = tid >> 1, scB = (tid & 1) * 32;
  int rA = wm * 32 + (lane & 15);
  int rB = wn * 64 + (lane & 15);
  for (int k0 = 0; k0 < K; k0 += BK) {
    __syncthreads();
    {
      const unsigned short* Ap = A + (size_t)(m0 + srA) * K + k0 + scA;
      uint4 a0 = *(const uint4*)(Ap);
      uint4 a1 = *(const uint4*)(Ap + 8);
      unsigned short* Asp = &As[srA * LST + scA];
      *(uint4*)(Asp) = a0; *(uint4*)(Asp + 8) = a1;
      const unsigned short* Bp = BT + (size_t)(n0 + srB) * K + k0 + scB;
      uint4 b0 = *(const uint4*)(Bp);
      uint4 b1 = *(const uint4*)(Bp + 8);
      uint4 b2 = *(const uint4*)(Bp + 16);
      uint4 b3 = *(const uint4*)(Bp + 24);
      unsigned short* Bsp = &Bs[srB * LST + scB];
      *(uint4*)(Bsp) = b0; *(uint4*)(Bsp + 8) = b1;
      *(uint4*)(Bsp + 16) = b2; *(uint4*)(Bsp + 24) = b3;
    }
    __syncthreads();
    #pragma unroll
    for (int kx = 0; kx < 2; ++kx) {
      int kk = (lane >> 4) * 8 + kx * 32;
      bf16x8 fa[2], fb[4];
      #pragma unroll
      for (int i = 0; i < 2; ++i) fa[i] = *(const bf16x8*)&As[(rA + i * 16) * LST + kk];
      #pragma unroll
      for (int j = 0; j < 4; ++j) fb[j] = *(const bf16x8*)&Bs[(rB + j * 16) * LST + kk];
      #pragma unroll
      for (int i = 0; i < 2; ++i)
        #pragma unroll
        for (int j = 0; j < 4; ++j)
          acc[i][j] = __builtin_amdgcn_mfma_f32_16x16x32_bf16(fa[i], fb[j], acc[i][j], 0, 0, 0);
    }
  }
  int crow0 = m0 + wm * 32 + (lane >> 4) * 4, ccol0 = n0 + wn * 64 + (lane & 15);
  #pragma unroll
  for (int i = 0; i < 2; ++i) {
    #pragma unroll
    for (int j = 0; j < 4; ++j) {
      int col = ccol0 + j * 16;
      #pragma unroll
      for (int r = 0; r < 4; ++r) {
        int row = crow0 + i * 16 + r;
        float v = acc[i][j][r];
        if (EPI == 1) v += resid[(size_t)row * N + col];
        if (EPI == 2) { v += bias[col]; v = 0.5f * v * (1.f + erff(v * 0.70710678f)); }
        if (EPI == 3) v += bias[col] + resid[(size_t)row * N + col];
        if (OUTBF) ((unsigned short*)Cv)[(size_t)row * N + col] = f2bf(v);
        else       ((float*)Cv)[(size_t)row * N + col] = v;
      }
    }
  }
}

// ---------------- depthwise 3x3 conv + bias + SiLU; writes bf16 xa ----------------
__global__ __launch_bounds__(256) void conv_kernel(
    const float* __restrict__ xz, const float* __restrict__ cw,
    const float* __restrict__ cb, unsigned short* __restrict__ xa) {
  int idx = blockIdx.x * 256 + threadIdx.x;
  int d = idx & (DI_ - 1);
  int l = (idx >> 10) & (L_ - 1);
  int b = idx >> 20;
  int hh = l >> 5, ww = l & 31;
  float acc = cb[d];
  #pragma unroll
  for (int dh = -1; dh <= 1; ++dh) {
    int y = hh + dh;
    if ((unsigned)y >= 32u) continue;
    #pragma unroll
    for (int dw = -1; dw <= 1; ++dw) {
      int x = ww + dw;
      if ((unsigned)x >= 32u) continue;
      acc = fmaf(xz[((size_t)b * L_ + y * 32 + x) * (2 * DI_) + d],
                 cw[d * 9 + (dh + 1) * 3 + (dw + 1)], acc);
    }
  }
  float sv = acc / (1.f + __expf(-acc));
  xa[idx] = f2bf(sv);
}

// ---------------- dt projection + softplus -> delta [b][k][l][d] (bf16) ----------------
__global__ __launch_bounds__(256) void delta_kernel(
    const float* __restrict__ sp, const float* __restrict__ dtw,
    const float* __restrict__ dtb, unsigned short* __restrict__ delta) {
  int bk = blockIdx.x;
  int b = bk >> 2, k = bk & 3;
  int dc = blockIdx.y * 256;
  int l0 = blockIdx.z * 128;
  __shared__ float wl[32 * 257];
  __shared__ float rl[128 * 32];
  int tid = threadIdx.x;
  for (int i = tid; i < 256 * 32; i += 256) {
    int dl = i >> 5, r = i & 31;
    wl[r * 257 + dl] = dtw[((size_t)k * DI_ + dc + dl) * R_ + r];
  }
  for (int i = tid; i < 128 * 32; i += 256) {
    int ll = i >> 5, r = i & 31;
    rl[ll * 32 + r] = sp[((size_t)b * L_ + l0 + ll) * 384 + k * R_ + r];
  }
  __syncthreads();
  float bias = dtb[k * DI_ + dc + tid];
  for (int ll = 0; ll < 128; ++ll) {
    float acc = bias;
    #pragma unroll
    for (int r = 0; r < 32; ++r)
      acc = fmaf(rl[ll * 32 + r], wl[r * 257 + tid], acc);
    float dlt = (acc > 15.f) ? acc : log1pf(__expf(acc));
    delta[(((size_t)(b * 4 + k) * L_) + l0 + ll) * DI_ + dc + tid] = f2bf(dlt);
  }
}

// ---------------- selective scan: packed-f32 math + deferred y store ----------------
// lane = dg*16 + ng: dg = lane>>4 (4 d per wave), ng = lane&15 (4 n per lane).
// Block 512 thr = 8 waves = 32 d. Grid (DI/32, K, B) = 512 blocks -> 4 wv/SIMD.
// Inner step: float2 pk mul/fma (8 VALU vs 16 scalar), 4 exp, all-DPP reduce,
// y held in register lane ng==li; ONE coalesced bf16 store + f2bf per 16 steps.
#define CH 16
#define NCH (L_ / CH)
#define DLP 36
__global__ __launch_bounds__(512) void scan_kernel(
    unsigned short* __restrict__ ybuf, const unsigned short* __restrict__ xa,
    const float* __restrict__ sp, const float* __restrict__ Cs,
    const unsigned short* __restrict__ dltb,
    const float* __restrict__ A_logs, const float* __restrict__ Ds) {
  int dblk = blockIdx.x;
  int k = blockIdx.y, b = blockIdx.z;
  int tid = threadIdx.x, lane = tid & 63, wv = tid >> 6;
  int dg = lane >> 4, ng = lane & 15;
  int wd = wv * 4 + dg;
  int gd = k * DI_ + dblk * 32 + wd;
  v2f a2p[2], h2[2];
  #pragma unroll
  for (int j = 0; j < 2; ++j) {
    a2p[j].x = -__expf(A_logs[(size_t)gd * N_ + ng * 4 + 2 * j]) * 1.44269504f;
    a2p[j].y = -__expf(A_logs[(size_t)gd * N_ + ng * 4 + 2 * j + 1]) * 1.44269504f;
    h2[j].x = 0.f; h2[j].y = 0.f;
  }
  float dsv = Ds[gd];

  __shared__ float Bsh[2][CH][64];
  __shared__ float Csh[2][CH][64];
  __shared__ float DLU[2][32][DLP];

  const size_t spB = (size_t)b * L_ * 384 + 128 + k * 64;
  const size_t csB = (size_t)b * L_ * 256 + k * 64;
  const size_t dlB = ((size_t)(b * 4 + k) * L_) * DI_ + dblk * 32;
  const size_t xaB = (size_t)b * L_ * DI_ + dblk * 32;

  int liS = tid >> 5, js = tid & 31;
  auto posf = [&](int l) {
    int lr = 1023 - l;
    return (k == 0) ? l
         : (k == 1) ? ((l & 31) * 32 + (l >> 5))
         : (k == 2) ? lr
                    : ((lr & 31) * 32 + (lr >> 5));
  };

  // stage chunk 0
  {
    *(float2*)&Bsh[0][liS][js * 2] = *(const float2*)(sp + spB + (size_t)liS * 384 + js * 2);
    *(float2*)&Csh[0][liS][js * 2] = *(const float2*)(Cs + csB + (size_t)liS * 256 + js * 2);
    float2 p;
    p.x = bf2f(dltb[dlB + (size_t)liS * DI_ + js]);
    p.y = bf2f(xa[xaB + (size_t)posf(liS) * DI_ + js]);
    *(float2*)&DLU[0][js][liS * 2] = p;
  }
  __syncthreads();

  int cur = 0;
  for (int c = 0; c < NCH; ++c) {
    float2 pB, pC;
    unsigned short pD, pU;
    if (c < NCH - 1) {
      int lb = (c + 1) * CH + liS;
      pB = *(const float2*)(sp + spB + (size_t)lb * 384 + js * 2);
      pC = *(const float2*)(Cs + csB + (size_t)lb * 256 + js * 2);
      pD = dltb[dlB + (size_t)lb * DI_ + js];
      pU = xa[xaB + (size_t)posf(lb) * DI_ + js];
    }
    float yhold = 0.f;
    #pragma unroll
    for (int li2 = 0; li2 < CH; li2 += 2) {
      f32x4 duq = *(const f32x4*)&DLU[cur][wd][li2 * 2];
      #pragma unroll
      for (int s = 0; s < 2; ++s) {
        int li = li2 + s;
        float dlt = s ? duq[2] : duq[0];
        float u   = s ? duq[3] : duq[1];
        float du = dlt * u;
        f32x4 bq = *(const f32x4*)&Bsh[cur][li][ng * 4];
        f32x4 cq = *(const f32x4*)&Csh[cur][li][ng * 4];
        v2f b01 = __builtin_shufflevector(bq, bq, 0, 1);
        v2f b23 = __builtin_shufflevector(bq, bq, 2, 3);
        v2f c01 = __builtin_shufflevector(cq, cq, 0, 1);
        v2f c23 = __builtin_shufflevector(cq, cq, 2, 3);
        v2f dlt2; dlt2.x = dlt; dlt2.y = dlt;
        v2f du2;  du2.x = du;  du2.y = du;
        v2f arg0 = dlt2 * a2p[0];
        v2f arg1 = dlt2 * a2p[1];
        v2f e0, e1;
        e0.x = __builtin_amdgcn_exp2f(arg0.x);
        e0.y = __builtin_amdgcn_exp2f(arg0.y);
        e1.x = __builtin_amdgcn_exp2f(arg1.x);
        e1.y = __builtin_amdgcn_exp2f(arg1.y);
        h2[0] = e0 * h2[0] + du2 * b01;
        h2[1] = e1 * h2[1] + du2 * b23;
        v2f yv = h2[0] * c01 + h2[1] * c23;
        float yp = yv.x + yv.y;
        yp = dpp_add<0x124>(yp);  // row_ror:4
        yp = dpp_add<0x128>(yp);  // row_ror:8
        yp = dpp_add<0xB1>(yp);   // quad xor1
        yp = dpp_add<0x4E>(yp);   // quad xor2
        yhold = (ng == li) ? fmaf(u, dsv, yp) : yhold;  // lane ng keeps step ng
      }
    }
    // one coalesced store per chunk: lane (wv,dg,ng) -> y[step c*16+ng][d wd]
    ybuf[dlB + (size_t)(c * CH + ng) * DI_ + wd] = f2bf(yhold);
    __syncthreads();
    if (c < NCH - 1) {
      int nxt = cur ^ 1;
      *(float2*)&Bsh[nxt][liS][js * 2] = pB;
      *(float2*)&Csh[nxt][liS][js * 2] = pC;
      float2 p; p.x = bf2f(pD); p.y = bf2f(pU);
      *(float2*)&DLU[nxt][js][liS * 2] = p;
    }
    __syncthreads();
    cur ^= 1;
  }
}

// ---------------- fuse: ygz = (sum_k yk) * z  -> bf16 ----------------
__global__ __launch_bounds__(256) void fuse_ygz(
    const unsigned short* __restrict__ yk, const float* __restrict__ xz,
    unsigned short* __restrict__ ygz) {
  size_t i = ((size_t)blockIdx.x * 256 + threadIdx.x) * 8;
  size_t b = i >> 20, ld = i & ((1u << 20) - 1);
  float acc[8] = {};
  #pragma unroll
  for (int k = 0; k < 4; ++k) {
    uint4 v = *(const uint4*)(yk + ((size_t)(b * 4 + k) << 20) + ld);
    unsigned int w[4] = {v.x, v.y, v.z, v.w};
    #pragma unroll
    for (int t = 0; t < 4; ++t) {
      acc[t * 2 + 0] += __builtin_bit_cast(float, w[t] << 16);
      acc[t * 2 + 1] += __builtin_bit_cast(float, w[t] & 0xFFFF0000u);
    }
  }
  const float* zp = xz + (i >> 10) * (2 * DI_) + DI_ + (i & (DI_ - 1));
  float4 z0 = *(const float4*)zp;
  float4 z1 = *(const float4*)(zp + 4);
  uint4 o;
  o.x = (unsigned int)f2bf(acc[0] * z0.x) | ((unsigned int)f2bf(acc[1] * z0.y) << 16);
  o.y = (unsigned int)f2bf(acc[2] * z0.z) | ((unsigned int)f2bf(acc[3] * z0.w) << 16);
  o.z = (unsigned int)f2bf(acc[4] * z1.x) | ((unsigned int)f2bf(acc[5] * z1.y) << 16);
  o.w = (unsigned int)f2bf(acc[6] * z1.z) | ((unsigned int)f2bf(acc[7] * z1.w) << 16);
  *(uint4*)(ygz + i) = o;
}

// ---------------- host ----------------
extern "C" void kernel_launch(void* const* d_in, const int* in_sizes, int n_in,
                              void* d_out, int out_size, void* d_ws, size_t ws_size,
                              hipStream_t stream) {
  (void)in_sizes; (void)n_in; (void)out_size; (void)ws_size;
  const float* content   = (const float*)d_in[0];
  const float* style     = (const float*)d_in[1];
  const float* norm1_w   = (const float*)d_in[2];
  const float* norm1_b   = (const float*)d_in[3];
  const float* in_proj_w = (const float*)d_in[4];
  const float* conv_w    = (const float*)d_in[5];
  const float* conv_b    = (const float*)d_in[6];
  const float* style_proj_w   = (const float*)d_in[7];
  const float* content_proj_w = (const float*)d_in[8];
  const float* dtw       = (const float*)d_in[9];
  const float* dtb       = (const float*)d_in[10];
  const float* A_logs    = (const float*)d_in[11];
  const float* Ds        = (const float*)d_in[12];
  const float* out_proj_w = (const float*)d_in[13];
  const float* norm2_w   = (const float*)d_in[14];
  const float* norm2_b   = (const float*)d_in[15];
  const float* mlp_w1    = (const float*)d_in[16];
  const float* mlp_b1    = (const float*)d_in[17];
  const float* mlp_w2    = (const float*)d_in[18];
  const float* mlp_b2    = (const float*)d_in[19];
  float* out = (float*)d_out;

  float* ws = (float*)d_ws;
  const size_t ROWS = (size_t)B_ * L_;
  const size_t SCAN_ELEMS = (size_t)B_ * K_ * L_ * DI_;
  size_t o = 0;
  unsigned short* cn  = (unsigned short*)(ws + o); o += ROWS * HID_ / 2;
  unsigned short* sn  = (unsigned short*)(ws + o); o += ROWS * HID_ / 2;
  unsigned short* xn  = (unsigned short*)(ws + o); o += ROWS * HID_ / 2;
  float* xz    = ws + o; o += ROWS * 2 * DI_;
  float* sp    = ws + o; o += ROWS * 384;
  unsigned short* xa = (unsigned short*)(ws + o); o += ROWS * DI_ / 2;
  float* csb   = ws + o; o += ROWS * 256;
  float* x1    = ws + o; o += ROWS * HID_;
  unsigned short* dltb = (unsigned short*)(ws + o); o += SCAN_ELEMS / 2;
  unsigned short* ybuf = (unsigned short*)(ws + o); o += SCAN_ELEMS / 2;
  unsigned short* ygz  = (unsigned short*)(ws + o); o += ROWS * DI_ / 2;
  unsigned short* wt = (unsigned short*)(ws + o);
  unsigned short* inpT = wt;
  unsigned short* styT = inpT + 2048 * 512;
  unsigned short* conT = styT + 384 * 512;
  unsigned short* outT = conT + 256 * 1024;
  unsigned short* w1T  = outT + 512 * 1024;
  unsigned short* w2T  = w1T + 2048 * 512;
  unsigned short* hmid = ybuf;

  transpose_all<<<4032, 256, 0, stream>>>(
      in_proj_w, style_proj_w, content_proj_w, out_proj_w, mlp_w1, mlp_w2,
      inpT, styT, conT, outT, w1T, w2T);

  ln_kernel<<<dim3(ROWS / 4, 2), 256, 0, stream>>>(content, cn, style, sn, norm1_w, norm1_b);

  gemm_kernel<0, 0><<<dim3(2048 / BN, ROWS / BM), 256, 0, stream>>>(
      cn, inpT, xz, ROWS, 2048, 512, nullptr, nullptr);
  gemm64_kernel<0, 0><<<dim3(384 / BN, ROWS / 64), 256, 0, stream>>>(
      sn, styT, sp, ROWS, 384, 512, nullptr, nullptr);
  conv_kernel<<<(ROWS * DI_) / 256, 256, 0, stream>>>(xz, conv_w, conv_b, xa);
  gemm64_kernel<0, 0><<<dim3(256 / BN, ROWS / 64), 256, 0, stream>>>(
      xa, conT, csb, ROWS, 256, 1024, nullptr, nullptr);
  delta_kernel<<<dim3(B_ * K_, DI_ / 256, L_ / 128), 256, 0, stream>>>(sp, dtw, dtb, dltb);
  scan_kernel<<<dim3(DI_ / 32, K_, B_), 512, 0, stream>>>(
      ybuf, xa, sp, csb, dltb, A_logs, Ds);
  fuse_ygz<<<(ROWS * DI_) / (256 * 8), 256, 0, stream>>>(ybuf, xz, ygz);
  gemm64_kernel<1, 0><<<dim3(512 / BN, ROWS / 64), 256, 0, stream>>>(
      ygz, outT, x1, ROWS, 512, 1024, nullptr, content);
  ln_kernel<<<dim3(ROWS / 4, 1), 256, 0, stream>>>(x1, xn, nullptr, nullptr, norm2_w, norm2_b);
  gemm_kernel<2, 1><<<dim3(2048 / BN, ROWS / BM), 256, 0, stream>>>(
      xn, w1T, hmid, ROWS, 2048, 512, mlp_b1, nullptr);
  gemm64_kernel<3, 0><<<dim3(512 / BN, ROWS / 64), 256, 0, stream>>>(
      hmid, w2T, out, ROWS, 512, 2048, mlp_b2, x1);
}

// Round 10
// 493.743 us; speedup vs baseline: 1.3625x; 1.1078x over previous
//
#include <hip/hip_runtime.h>

// ---------------- constants ----------------
#define B_ 4
#define Hh_ 32
#define Ww_ 32
#define L_ 1024
#define HID_ 512
#define DI_ 1024
#define N_ 64
#define R_ 32
#define K_ 4
#define MLP_ 2048

typedef __bf16 bf16x8 __attribute__((ext_vector_type(8)));
typedef float f32x4 __attribute__((ext_vector_type(4)));
typedef float v2f __attribute__((ext_vector_type(2)));

__device__ __forceinline__ unsigned short f2bf(float f) {
  unsigned int u = __builtin_bit_cast(unsigned int, f);
  return (unsigned short)((u + 0x7FFFu + ((u >> 16) & 1u)) >> 16);
}
__device__ __forceinline__ float bf2f(unsigned short h) {
  return __builtin_bit_cast(float, (unsigned int)h << 16);
}

// DPP add: x + x[perm(lane)] on the VALU pipe (no DS traffic)
template <int CTRL>
__device__ __forceinline__ float dpp_add(float x) {
  int i = __builtin_bit_cast(int, x);
  int j = __builtin_amdgcn_update_dpp(i, i, CTRL, 0xF, 0xF, false);
  return x + __builtin_bit_cast(float, j);
}

// ---------------- all 6 weight transposes in ONE launch ----------------
__global__ __launch_bounds__(256) void transpose_all(
    const float* __restrict__ s0, const float* __restrict__ s1,
    const float* __restrict__ s2, const float* __restrict__ s3,
    const float* __restrict__ s4, const float* __restrict__ s5,
    unsigned short* __restrict__ t0, unsigned short* __restrict__ t1,
    unsigned short* __restrict__ t2, unsigned short* __restrict__ t3,
    unsigned short* __restrict__ t4, unsigned short* __restrict__ t5) {
  __shared__ float t[32][33];
  int bid = blockIdx.x;
  const float* src; unsigned short* dst; int K, N, bx, by;
  if (bid < 1024)      { src = s0; dst = t0; K = 512;  N = 2048; int r = bid;        bx = r & 63; by = r >> 6; }
  else if (bid < 1216) { src = s1; dst = t1; K = 512;  N = 384;  int r = bid - 1024; bx = r % 12; by = r / 12; }
  else if (bid < 1472) { src = s2; dst = t2; K = 1024; N = 256;  int r = bid - 1216; bx = r & 7;  by = r >> 3; }
  else if (bid < 1984) { src = s3; dst = t3; K = 1024; N = 512;  int r = bid - 1472; bx = r & 15; by = r >> 4; }
  else if (bid < 3008) { src = s4; dst = t4; K = 512;  N = 2048; int r = bid - 1984; bx = r & 63; by = r >> 6; }
  else                 { src = s5; dst = t5; K = 2048; N = 512;  int r = bid - 3008; bx = r & 15; by = r >> 4; }
  int nb = bx * 32, kb = by * 32;
  int tx = threadIdx.x & 31, ty = threadIdx.x >> 5;
  for (int r = ty; r < 32; r += 8) t[r][tx] = src[(size_t)(kb + r) * N + nb + tx];
  __syncthreads();
  for (int r = ty; r < 32; r += 8) dst[(size_t)(nb + r) * K + kb + tx] = f2bf(t[tx][r]);
}

// ---------------- LayerNorm over 512, wave per row; writes bf16 ----------------
__global__ __launch_bounds__(256) void ln_kernel(
    const float* __restrict__ in0, unsigned short* __restrict__ out0,
    const float* __restrict__ in1, unsigned short* __restrict__ out1,
    const float* __restrict__ w, const float* __restrict__ bb) {
  const float* in = blockIdx.y ? in1 : in0;
  unsigned short* out = blockIdx.y ? out1 : out0;
  int row = blockIdx.x * 4 + (threadIdx.x >> 6);
  int lane = threadIdx.x & 63;
  const float* p = in + (size_t)row * HID_;
  float4 v0 = *(const float4*)(p + lane * 4);
  float4 v1 = *(const float4*)(p + 256 + lane * 4);
  float s = v0.x + v0.y + v0.z + v0.w + v1.x + v1.y + v1.z + v1.w;
  float q = v0.x * v0.x + v0.y * v0.y + v0.z * v0.z + v0.w * v0.w +
            v1.x * v1.x + v1.y * v1.y + v1.z * v1.z + v1.w * v1.w;
  #pragma unroll
  for (int m = 1; m < 64; m <<= 1) { s += __shfl_xor(s, m, 64); q += __shfl_xor(q, m, 64); }
  float mean = s * (1.f / 512.f);
  float var = q * (1.f / 512.f) - mean * mean;
  float rstd = rsqrtf(var + 1e-5f);
  float4 w0 = *(const float4*)(w + lane * 4);
  float4 w1 = *(const float4*)(w + 256 + lane * 4);
  float4 b0 = *(const float4*)(bb + lane * 4);
  float4 b1 = *(const float4*)(bb + 256 + lane * 4);
  unsigned short* o = out + (size_t)row * HID_;
  ushort4 r0, r1;
  r0.x = f2bf((v0.x - mean) * rstd * w0.x + b0.x);
  r0.y = f2bf((v0.y - mean) * rstd * w0.y + b0.y);
  r0.z = f2bf((v0.z - mean) * rstd * w0.z + b0.z);
  r0.w = f2bf((v0.w - mean) * rstd * w0.w + b0.w);
  r1.x = f2bf((v1.x - mean) * rstd * w1.x + b1.x);
  r1.y = f2bf((v1.y - mean) * rstd * w1.y + b1.y);
  r1.z = f2bf((v1.z - mean) * rstd * w1.z + b1.z);
  r1.w = f2bf((v1.w - mean) * rstd * w1.w + b1.w);
  *(ushort4*)(o + lane * 4) = r0;
  *(ushort4*)(o + 256 + lane * 4) = r1;
}

// ---------------- MFMA GEMM 128x128, BK=64, XCD-swizzled ----------------
#define BM 128
#define BN 128
#define BK 64
#define LST 72

template <int EPI, int OUTBF>
__global__ __launch_bounds__(256) void gemm_kernel(
    const unsigned short* __restrict__ A, const unsigned short* __restrict__ BT,
    void* __restrict__ Cv, int M, int N, int K,
    const float* __restrict__ bias, const float* __restrict__ resid) {
  __shared__ __align__(16) unsigned short As[BM * LST];
  __shared__ __align__(16) unsigned short Bs[BN * LST];
  int tid = threadIdx.x;
  int lane = tid & 63, wv = tid >> 6;
  int wm = wv >> 1, wn = wv & 1;
  int nwg = gridDim.x * gridDim.y;
  int flat = blockIdx.y * gridDim.x + blockIdx.x;
  int swz = (flat & 7) * (nwg >> 3) + (flat >> 3);   // nwg % 8 == 0 for all call sites
  int bx = swz % gridDim.x, by = swz / gridDim.x;
  int m0 = by * BM, n0 = bx * BN;
  f32x4 acc[4][4] = {};
  int sr = tid >> 1, sc = (tid & 1) * 32;
  int rA = wm * 64 + (lane & 15);
  int rB = wn * 64 + (lane & 15);
  for (int k0 = 0; k0 < K; k0 += BK) {
    __syncthreads();
    {
      const unsigned short* Ap = A + (size_t)(m0 + sr) * K + k0 + sc;
      uint4 a0 = *(const uint4*)(Ap);
      uint4 a1 = *(const uint4*)(Ap + 8);
      uint4 a2 = *(const uint4*)(Ap + 16);
      uint4 a3 = *(const uint4*)(Ap + 24);
      unsigned short* Asp = &As[sr * LST + sc];
      *(uint4*)(Asp) = a0; *(uint4*)(Asp + 8) = a1;
      *(uint4*)(Asp + 16) = a2; *(uint4*)(Asp + 24) = a3;
      const unsigned short* Bp = BT + (size_t)(n0 + sr) * K + k0 + sc;
      uint4 b0 = *(const uint4*)(Bp);
      uint4 b1 = *(const uint4*)(Bp + 8);
      uint4 b2 = *(const uint4*)(Bp + 16);
      uint4 b3 = *(const uint4*)(Bp + 24);
      unsigned short* Bsp = &Bs[sr * LST + sc];
      *(uint4*)(Bsp) = b0; *(uint4*)(Bsp + 8) = b1;
      *(uint4*)(Bsp + 16) = b2; *(uint4*)(Bsp + 24) = b3;
    }
    __syncthreads();
    #pragma unroll
    for (int kx = 0; kx < 2; ++kx) {
      int kk = (lane >> 4) * 8 + kx * 32;
      bf16x8 fa[4], fb[4];
      #pragma unroll
      for (int i = 0; i < 4; ++i) {
        fa[i] = *(const bf16x8*)&As[(rA + i * 16) * LST + kk];
        fb[i] = *(const bf16x8*)&Bs[(rB + i * 16) * LST + kk];
      }
      #pragma unroll
      for (int i = 0; i < 4; ++i)
        #pragma unroll
        for (int j = 0; j < 4; ++j)
          acc[i][j] = __builtin_amdgcn_mfma_f32_16x16x32_bf16(fa[i], fb[j], acc[i][j], 0, 0, 0);
    }
  }
  int crow0 = m0 + wm * 64 + (lane >> 4) * 4, ccol0 = n0 + wn * 64 + (lane & 15);
  #pragma unroll
  for (int i = 0; i < 4; ++i) {
    #pragma unroll
    for (int j = 0; j < 4; ++j) {
      int col = ccol0 + j * 16;
      #pragma unroll
      for (int r = 0; r < 4; ++r) {
        int row = crow0 + i * 16 + r;
        float v = acc[i][j][r];
        if (EPI == 1) v += resid[(size_t)row * N + col];
        if (EPI == 2) { v += bias[col]; v = 0.5f * v * (1.f + erff(v * 0.70710678f)); }
        if (EPI == 3) v += bias[col] + resid[(size_t)row * N + col];
        if (OUTBF) ((unsigned short*)Cv)[(size_t)row * N + col] = f2bf(v);
        else       ((float*)Cv)[(size_t)row * N + col] = v;
      }
    }
  }
}

// ---------------- MFMA GEMM 64x128, BK=64, XCD-swizzled ----------------
template <int EPI, int OUTBF>
__global__ __launch_bounds__(256) void gemm64_kernel(
    const unsigned short* __restrict__ A, const unsigned short* __restrict__ BT,
    void* __restrict__ Cv, int M, int N, int K,
    const float* __restrict__ bias, const float* __restrict__ resid) {
  __shared__ __align__(16) unsigned short As[64 * LST];
  __shared__ __align__(16) unsigned short Bs[128 * LST];
  int tid = threadIdx.x;
  int lane = tid & 63, wv = tid >> 6;
  int wm = wv >> 1, wn = wv & 1;
  int nwg = gridDim.x * gridDim.y;
  int flat = blockIdx.y * gridDim.x + blockIdx.x;
  int swz = (flat & 7) * (nwg >> 3) + (flat >> 3);
  int bx = swz % gridDim.x, by = swz / gridDim.x;
  int m0 = by * 64, n0 = bx * BN;
  f32x4 acc[2][4] = {};
  int srA = tid >> 2, scA = (tid & 3) * 16;
  int srB = tid >> 1, scB = (tid & 1) * 32;
  int rA = wm * 32 + (lane & 15);
  int rB = wn * 64 + (lane & 15);
  for (int k0 = 0; k0 < K; k0 += BK) {
    __syncthreads();
    {
      const unsigned short* Ap = A + (size_t)(m0 + srA) * K + k0 + scA;
      uint4 a0 = *(const uint4*)(Ap);
      uint4 a1 = *(const uint4*)(Ap + 8);
      unsigned short* Asp = &As[srA * LST + scA];
      *(uint4*)(Asp) = a0; *(uint4*)(Asp + 8) = a1;
      const unsigned short* Bp = BT + (size_t)(n0 + srB) * K + k0 + scB;
      uint4 b0 = *(const uint4*)(Bp);
      uint4 b1 = *(const uint4*)(Bp + 8);
      uint4 b2 = *(const uint4*)(Bp + 16);
      uint4 b3 = *(const uint4*)(Bp + 24);
      unsigned short* Bsp = &Bs[srB * LST + scB];
      *(uint4*)(Bsp) = b0; *(uint4*)(Bsp + 8) = b1;
      *(uint4*)(Bsp + 16) = b2; *(uint4*)(Bsp + 24) = b3;
    }
    __syncthreads();
    #pragma unroll
    for (int kx = 0; kx < 2; ++kx) {
      int kk = (lane >> 4) * 8 + kx * 32;
      bf16x8 fa[2], fb[4];
      #pragma unroll
      for (int i = 0; i < 2; ++i) fa[i] = *(const bf16x8*)&As[(rA + i * 16) * LST + kk];
      #pragma unroll
      for (int j = 0; j < 4; ++j) fb[j] = *(const bf16x8*)&Bs[(rB + j * 16) * LST + kk];
      #pragma unroll
      for (int i = 0; i < 2; ++i)
        #pragma unroll
        for (int j = 0; j < 4; ++j)
          acc[i][j] = __builtin_amdgcn_mfma_f32_16x16x32_bf16(fa[i], fb[j], acc[i][j], 0, 0, 0);
    }
  }
  int crow0 = m0 + wm * 32 + (lane >> 4) * 4, ccol0 = n0 + wn * 64 + (lane & 15);
  #pragma unroll
  for (int i = 0; i < 2; ++i) {
    #pragma unroll
    for (int j = 0; j < 4; ++j) {
      int col = ccol0 + j * 16;
      #pragma unroll
      for (int r = 0; r < 4; ++r) {
        int row = crow0 + i * 16 + r;
        float v = acc[i][j][r];
        if (EPI == 1) v += resid[(size_t)row * N + col];
        if (EPI == 2) { v += bias[col]; v = 0.5f * v * (1.f + erff(v * 0.70710678f)); }
        if (EPI == 3) v += bias[col] + resid[(size_t)row * N + col];
        if (OUTBF) ((unsigned short*)Cv)[(size_t)row * N + col] = f2bf(v);
        else       ((float*)Cv)[(size_t)row * N + col] = v;
      }
    }
  }
}

// ---------------- depthwise 3x3 conv + bias + SiLU; bf16 in (xz), bf16 out ----------------
__global__ __launch_bounds__(256) void conv_kernel(
    const unsigned short* __restrict__ xz, const float* __restrict__ cw,
    const float* __restrict__ cb, unsigned short* __restrict__ xa) {
  int idx = blockIdx.x * 256 + threadIdx.x;
  int d = idx & (DI_ - 1);
  int l = (idx >> 10) & (L_ - 1);
  int b = idx >> 20;
  int hh = l >> 5, ww = l & 31;
  float acc = cb[d];
  #pragma unroll
  for (int dh = -1; dh <= 1; ++dh) {
    int y = hh + dh;
    if ((unsigned)y >= 32u) continue;
    #pragma unroll
    for (int dw = -1; dw <= 1; ++dw) {
      int x = ww + dw;
      if ((unsigned)x >= 32u) continue;
      acc = fmaf(bf2f(xz[((size_t)b * L_ + y * 32 + x) * (2 * DI_) + d]),
                 cw[d * 9 + (dh + 1) * 3 + (dw + 1)], acc);
    }
  }
  float sv = acc / (1.f + __expf(-acc));
  xa[idx] = f2bf(sv);
}

// ---------------- dt projection + softplus -> delta [b][k][l][d] (bf16) ----------------
__global__ __launch_bounds__(256) void delta_kernel(
    const float* __restrict__ sp, const float* __restrict__ dtw,
    const float* __restrict__ dtb, unsigned short* __restrict__ delta) {
  int bk = blockIdx.x;
  int b = bk >> 2, k = bk & 3;
  int dc = blockIdx.y * 256;
  int l0 = blockIdx.z * 128;
  __shared__ float wl[32 * 257];
  __shared__ float rl[128 * 32];
  int tid = threadIdx.x;
  for (int i = tid; i < 256 * 32; i += 256) {
    int dl = i >> 5, r = i & 31;
    wl[r * 257 + dl] = dtw[((size_t)k * DI_ + dc + dl) * R_ + r];
  }
  for (int i = tid; i < 128 * 32; i += 256) {
    int ll = i >> 5, r = i & 31;
    rl[ll * 32 + r] = sp[((size_t)b * L_ + l0 + ll) * 384 + k * R_ + r];
  }
  __syncthreads();
  float bias = dtb[k * DI_ + dc + tid];
  for (int ll = 0; ll < 128; ++ll) {
    float acc = bias;
    #pragma unroll
    for (int r = 0; r < 32; ++r)
      acc = fmaf(rl[ll * 32 + r], wl[r * 257 + tid], acc);
    float dlt = (acc > 15.f) ? acc : log1pf(__expf(acc));
    delta[(((size_t)(b * 4 + k) * L_) + l0 + ll) * DI_ + dc + tid] = f2bf(dlt);
  }
}

// ---------------- selective scan: quad-partial LDS reduce + chunk epilogue ----------------
// lane = dg*16 + ng: dg = lane>>4 (4 d per wave), ng = lane&15 (4 n per lane).
// Per step: pk math + 2 quad DPP adds + 1 ds_write of quad partial (same-addr x4 lanes).
// Per chunk: transpose-reduce epilogue (2x float2 LDS read + 3 add + fma + bf16 store).
#define CH 16
#define NCH (L_ / CH)
#define DLP 36
#define YQP 6
__global__ __launch_bounds__(512) void scan_kernel(
    unsigned short* __restrict__ ybuf, const unsigned short* __restrict__ xa,
    const float* __restrict__ sp, const float* __restrict__ Cs,
    const unsigned short* __restrict__ dltb,
    const float* __restrict__ A_logs, const float* __restrict__ Ds) {
  int dblk = blockIdx.x;
  int k = blockIdx.y, b = blockIdx.z;
  int tid = threadIdx.x, lane = tid & 63, wv = tid >> 6;
  int dg = lane >> 4, ng = lane & 15;
  int qp = (lane >> 2) & 3;          // quad index within 16-lane group
  int wd = wv * 4 + dg;
  int gd = k * DI_ + dblk * 32 + wd;
  v2f a2p[2], h2[2];
  #pragma unroll
  for (int j = 0; j < 2; ++j) {
    a2p[j].x = -__expf(A_logs[(size_t)gd * N_ + ng * 4 + 2 * j]) * 1.44269504f;
    a2p[j].y = -__expf(A_logs[(size_t)gd * N_ + ng * 4 + 2 * j + 1]) * 1.44269504f;
    h2[j].x = 0.f; h2[j].y = 0.f;
  }

  __shared__ float Bsh[2][CH][64];
  __shared__ float Csh[2][CH][64];
  __shared__ float DLU[2][32][DLP];
  __shared__ float yq[CH][32][YQP];  // quad partials per (step, d)
  __shared__ float dsh[32];

  const size_t spB = (size_t)b * L_ * 384 + 128 + k * 64;
  const size_t csB = (size_t)b * L_ * 256 + k * 64;
  const size_t dlB = ((size_t)(b * 4 + k) * L_) * DI_ + dblk * 32;
  const size_t xaB = (size_t)b * L_ * DI_ + dblk * 32;

  if (tid < 32) dsh[tid] = Ds[k * DI_ + dblk * 32 + tid];

  int liS = tid >> 5, js = tid & 31;
  int liE = tid >> 5, dd = tid & 31;  // epilogue role
  auto posf = [&](int l) {
    int lr = 1023 - l;
    return (k == 0) ? l
         : (k == 1) ? ((l & 31) * 32 + (l >> 5))
         : (k == 2) ? lr
                    : ((lr & 31) * 32 + (lr >> 5));
  };

  // stage chunk 0
  {
    *(float2*)&Bsh[0][liS][js * 2] = *(const float2*)(sp + spB + (size_t)liS * 384 + js * 2);
    *(float2*)&Csh[0][liS][js * 2] = *(const float2*)(Cs + csB + (size_t)liS * 256 + js * 2);
    float2 p;
    p.x = bf2f(dltb[dlB + (size_t)liS * DI_ + js]);
    p.y = bf2f(xa[xaB + (size_t)posf(liS) * DI_ + js]);
    *(float2*)&DLU[0][js][liS * 2] = p;
  }
  __syncthreads();

  int cur = 0;
  for (int c = 0; c < NCH; ++c) {
    float2 pB, pC;
    unsigned short pD, pU;
    if (c < NCH - 1) {
      int lb = (c + 1) * CH + liS;
      pB = *(const float2*)(sp + spB + (size_t)lb * 384 + js * 2);
      pC = *(const float2*)(Cs + csB + (size_t)lb * 256 + js * 2);
      pD = dltb[dlB + (size_t)lb * DI_ + js];
      pU = xa[xaB + (size_t)posf(lb) * DI_ + js];
    }
    #pragma unroll
    for (int li2 = 0; li2 < CH; li2 += 2) {
      f32x4 duq = *(const f32x4*)&DLU[cur][wd][li2 * 2];
      #pragma unroll
      for (int s = 0; s < 2; ++s) {
        int li = li2 + s;
        float dlt = s ? duq[2] : duq[0];
        float u   = s ? duq[3] : duq[1];
        float du = dlt * u;
        f32x4 bq = *(const f32x4*)&Bsh[cur][li][ng * 4];
        f32x4 cq = *(const f32x4*)&Csh[cur][li][ng * 4];
        v2f b01 = __builtin_shufflevector(bq, bq, 0, 1);
        v2f b23 = __builtin_shufflevector(bq, bq, 2, 3);
        v2f c01 = __builtin_shufflevector(cq, cq, 0, 1);
        v2f c23 = __builtin_shufflevector(cq, cq, 2, 3);
        v2f dlt2; dlt2.x = dlt; dlt2.y = dlt;
        v2f du2;  du2.x = du;  du2.y = du;
        v2f arg0 = dlt2 * a2p[0];
        v2f arg1 = dlt2 * a2p[1];
        v2f e0, e1;
        e0.x = __builtin_amdgcn_exp2f(arg0.x);
        e0.y = __builtin_amdgcn_exp2f(arg0.y);
        e1.x = __builtin_amdgcn_exp2f(arg1.x);
        e1.y = __builtin_amdgcn_exp2f(arg1.y);
        h2[0] = e0 * h2[0] + du2 * b01;
        h2[1] = e1 * h2[1] + du2 * b23;
        v2f yv = h2[0] * c01 + h2[1] * c23;
        float yp = yv.x + yv.y;
        yp = dpp_add<0xB1>(yp);   // quad xor1
        yp = dpp_add<0x4E>(yp);   // quad xor2 -> quad partial (16 n)
        yq[li][wd][qp] = yp;      // all 4 quad lanes write same value/addr
      }
    }
    __syncthreads();  // compute done: yq complete, DLU[cur] still valid
    {  // epilogue: one y output per thread
      float2 q01 = *(const float2*)&yq[liE][dd][0];
      float2 q23 = *(const float2*)&yq[liE][dd][2];
      float y = (q01.x + q01.y) + (q23.x + q23.y);
      float u = DLU[cur][dd][liE * 2 + 1];
      y = fmaf(u, dsh[dd], y);
      ybuf[dlB + (size_t)(c * CH + liE) * DI_ + dd] = f2bf(y);
    }
    if (c < NCH - 1) {
      int nxt = cur ^ 1;
      *(float2*)&Bsh[nxt][liS][js * 2] = pB;
      *(float2*)&Csh[nxt][liS][js * 2] = pC;
      float2 p; p.x = bf2f(pD); p.y = bf2f(pU);
      *(float2*)&DLU[nxt][js][liS * 2] = p;
    }
    __syncthreads();  // staging visible; yq free for next chunk
    cur ^= 1;
  }
}

// ---------------- fuse: ygz = (sum_k yk) * z  (yk bf16, z bf16) -> bf16 ----------------
__global__ __launch_bounds__(256) void fuse_ygz(
    const unsigned short* __restrict__ yk, const unsigned short* __restrict__ xz,
    unsigned short* __restrict__ ygz) {
  size_t i = ((size_t)blockIdx.x * 256 + threadIdx.x) * 8;
  size_t b = i >> 20, ld = i & ((1u << 20) - 1);
  float acc[8] = {};
  #pragma unroll
  for (int k = 0; k < 4; ++k) {
    uint4 v = *(const uint4*)(yk + ((size_t)(b * 4 + k) << 20) + ld);
    unsigned int w[4] = {v.x, v.y, v.z, v.w};
    #pragma unroll
    for (int t = 0; t < 4; ++t) {
      acc[t * 2 + 0] += __builtin_bit_cast(float, w[t] << 16);
      acc[t * 2 + 1] += __builtin_bit_cast(float, w[t] & 0xFFFF0000u);
    }
  }
  uint4 zv = *(const uint4*)(xz + (i >> 10) * (2 * DI_) + DI_ + (i & (DI_ - 1)));
  unsigned int zw[4] = {zv.x, zv.y, zv.z, zv.w};
  float z[8];
  #pragma unroll
  for (int t = 0; t < 4; ++t) {
    z[t * 2 + 0] = __builtin_bit_cast(float, zw[t] << 16);
    z[t * 2 + 1] = __builtin_bit_cast(float, zw[t] & 0xFFFF0000u);
  }
  uint4 o;
  o.x = (unsigned int)f2bf(acc[0] * z[0]) | ((unsigned int)f2bf(acc[1] * z[1]) << 16);
  o.y = (unsigned int)f2bf(acc[2] * z[2]) | ((unsigned int)f2bf(acc[3] * z[3]) << 16);
  o.z = (unsigned int)f2bf(acc[4] * z[4]) | ((unsigned int)f2bf(acc[5] * z[5]) << 16);
  o.w = (unsigned int)f2bf(acc[6] * z[6]) | ((unsigned int)f2bf(acc[7] * z[7]) << 16);
  *(uint4*)(ygz + i) = o;
}

// ---------------- host ----------------
extern "C" void kernel_launch(void* const* d_in, const int* in_sizes, int n_in,
                              void* d_out, int out_size, void* d_ws, size_t ws_size,
                              hipStream_t stream) {
  (void)in_sizes; (void)n_in; (void)out_size; (void)ws_size;
  const float* content   = (const float*)d_in[0];
  const float* style     = (const float*)d_in[1];
  const float* norm1_w   = (const float*)d_in[2];
  const float* norm1_b   = (const float*)d_in[3];
  const float* in_proj_w = (const float*)d_in[4];
  const float* conv_w    = (const float*)d_in[5];
  const float* conv_b    = (const float*)d_in[6];
  const float* style_proj_w   = (const float*)d_in[7];
  const float* content_proj_w = (const float*)d_in[8];
  const float* dtw       = (const float*)d_in[9];
  const float* dtb       = (const float*)d_in[10];
  const float* A_logs    = (const float*)d_in[11];
  const float* Ds        = (const float*)d_in[12];
  const float* out_proj_w = (const float*)d_in[13];
  const float* norm2_w   = (const float*)d_in[14];
  const float* norm2_b   = (const float*)d_in[15];
  const float* mlp_w1    = (const float*)d_in[16];
  const float* mlp_b1    = (const float*)d_in[17];
  const float* mlp_w2    = (const float*)d_in[18];
  const float* mlp_b2    = (const float*)d_in[19];
  float* out = (float*)d_out;

  float* ws = (float*)d_ws;
  const size_t ROWS = (size_t)B_ * L_;
  const size_t SCAN_ELEMS = (size_t)B_ * K_ * L_ * DI_;
  size_t o = 0;
  unsigned short* cn  = (unsigned short*)(ws + o); o += ROWS * HID_ / 2;
  unsigned short* sn  = (unsigned short*)(ws + o); o += ROWS * HID_ / 2;
  unsigned short* xn  = (unsigned short*)(ws + o); o += ROWS * HID_ / 2;
  unsigned short* xz  = (unsigned short*)(ws + o); o += ROWS * 2 * DI_ / 2;  // bf16
  float* sp    = ws + o; o += ROWS * 384;
  unsigned short* xa = (unsigned short*)(ws + o); o += ROWS * DI_ / 2;
  float* csb   = ws + o; o += ROWS * 256;
  float* x1    = ws + o; o += ROWS * HID_;
  unsigned short* dltb = (unsigned short*)(ws + o); o += SCAN_ELEMS / 2;
  unsigned short* ybuf = (unsigned short*)(ws + o); o += SCAN_ELEMS / 2;
  unsigned short* ygz  = (unsigned short*)(ws + o); o += ROWS * DI_ / 2;
  unsigned short* wt = (unsigned short*)(ws + o);
  unsigned short* inpT = wt;
  unsigned short* styT = inpT + 2048 * 512;
  unsigned short* conT = styT + 384 * 512;
  unsigned short* outT = conT + 256 * 1024;
  unsigned short* w1T  = outT + 512 * 1024;
  unsigned short* w2T  = w1T + 2048 * 512;
  unsigned short* hmid = ybuf;

  transpose_all<<<4032, 256, 0, stream>>>(
      in_proj_w, style_proj_w, content_proj_w, out_proj_w, mlp_w1, mlp_w2,
      inpT, styT, conT, outT, w1T, w2T);

  ln_kernel<<<dim3(ROWS / 4, 2), 256, 0, stream>>>(content, cn, style, sn, norm1_w, norm1_b);

  // xz = cn @ in_proj -> bf16
  gemm_kernel<0, 1><<<dim3(2048 / BN, ROWS / BM), 256, 0, stream>>>(
      cn, inpT, xz, ROWS, 2048, 512, nullptr, nullptr);
  gemm64_kernel<0, 0><<<dim3(384 / BN, ROWS / 64), 256, 0, stream>>>(
      sn, styT, sp, ROWS, 384, 512, nullptr, nullptr);
  conv_kernel<<<(ROWS * DI_) / 256, 256, 0, stream>>>(xz, conv_w, conv_b, xa);
  gemm64_kernel<0, 0><<<dim3(256 / BN, ROWS / 64), 256, 0, stream>>>(
      xa, conT, csb, ROWS, 256, 1024, nullptr, nullptr);
  delta_kernel<<<dim3(B_ * K_, DI_ / 256, L_ / 128), 256, 0, stream>>>(sp, dtw, dtb, dltb);
  scan_kernel<<<dim3(DI_ / 32, K_, B_), 512, 0, stream>>>(
      ybuf, xa, sp, csb, dltb, A_logs, Ds);
  fuse_ygz<<<(ROWS * DI_) / (256 * 8), 256, 0, stream>>>(ybuf, xz, ygz);
  gemm64_kernel<1, 0><<<dim3(512 / BN, ROWS / 64), 256, 0, stream>>>(
      ygz, outT, x1, ROWS, 512, 1024, nullptr, content);
  ln_kernel<<<dim3(ROWS / 4, 1), 256, 0, stream>>>(x1, xn, nullptr, nullptr, norm2_w, norm2_b);
  gemm_kernel<2, 1><<<dim3(2048 / BN, ROWS / BM), 256, 0, stream>>>(
      xn, w1T, hmid, ROWS, 2048, 512, mlp_b1, nullptr);
  gemm64_kernel<3, 0><<<dim3(512 / BN, ROWS / 64), 256, 0, stream>>>(
      hmid, w2T, out, ROWS, 512, 2048, mlp_b2, x1);
}

// Round 11
// 464.046 us; speedup vs baseline: 1.4497x; 1.0640x over previous
//
#include <hip/hip_runtime.h>

// ---------------- constants ----------------
#define B_ 4
#define Hh_ 32
#define Ww_ 32
#define L_ 1024
#define HID_ 512
#define DI_ 1024
#define N_ 64
#define R_ 32
#define K_ 4
#define MLP_ 2048

typedef __bf16 bf16x8 __attribute__((ext_vector_type(8)));
typedef float f32x4 __attribute__((ext_vector_type(4)));
typedef float v2f __attribute__((ext_vector_type(2)));

__device__ __forceinline__ unsigned short f2bf(float f) {
  unsigned int u = __builtin_bit_cast(unsigned int, f);
  return (unsigned short)((u + 0x7FFFu + ((u >> 16) & 1u)) >> 16);
}
__device__ __forceinline__ float bf2f(unsigned short h) {
  return __builtin_bit_cast(float, (unsigned int)h << 16);
}

// async global->LDS, 16B per lane; lds base must be wave-uniform
__device__ __forceinline__ void gload16(const unsigned short* g, unsigned short* l) {
  __builtin_amdgcn_global_load_lds(
      (const __attribute__((address_space(1))) unsigned int*)g,
      (__attribute__((address_space(3))) unsigned int*)l, 16, 0, 0);
}

// DPP add: x + x[perm(lane)] on the VALU pipe (no DS traffic)
template <int CTRL>
__device__ __forceinline__ float dpp_add(float x) {
  int i = __builtin_bit_cast(int, x);
  int j = __builtin_amdgcn_update_dpp(i, i, CTRL, 0xF, 0xF, false);
  return x + __builtin_bit_cast(float, j);
}

// ---------------- all 6 weight transposes in ONE launch ----------------
__global__ __launch_bounds__(256) void transpose_all(
    const float* __restrict__ s0, const float* __restrict__ s1,
    const float* __restrict__ s2, const float* __restrict__ s3,
    const float* __restrict__ s4, const float* __restrict__ s5,
    unsigned short* __restrict__ t0, unsigned short* __restrict__ t1,
    unsigned short* __restrict__ t2, unsigned short* __restrict__ t3,
    unsigned short* __restrict__ t4, unsigned short* __restrict__ t5) {
  __shared__ float t[32][33];
  int bid = blockIdx.x;
  const float* src; unsigned short* dst; int K, N, bx, by;
  if (bid < 1024)      { src = s0; dst = t0; K = 512;  N = 2048; int r = bid;        bx = r & 63; by = r >> 6; }
  else if (bid < 1216) { src = s1; dst = t1; K = 512;  N = 384;  int r = bid - 1024; bx = r % 12; by = r / 12; }
  else if (bid < 1472) { src = s2; dst = t2; K = 1024; N = 256;  int r = bid - 1216; bx = r & 7;  by = r >> 3; }
  else if (bid < 1984) { src = s3; dst = t3; K = 1024; N = 512;  int r = bid - 1472; bx = r & 15; by = r >> 4; }
  else if (bid < 3008) { src = s4; dst = t4; K = 512;  N = 2048; int r = bid - 1984; bx = r & 63; by = r >> 6; }
  else                 { src = s5; dst = t5; K = 2048; N = 512;  int r = bid - 3008; bx = r & 15; by = r >> 4; }
  int nb = bx * 32, kb = by * 32;
  int tx = threadIdx.x & 31, ty = threadIdx.x >> 5;
  for (int r = ty; r < 32; r += 8) t[r][tx] = src[(size_t)(kb + r) * N + nb + tx];
  __syncthreads();
  for (int r = ty; r < 32; r += 8) dst[(size_t)(nb + r) * K + kb + tx] = f2bf(t[tx][r]);
}

// ---------------- LayerNorm over 512, wave per row; writes bf16 ----------------
__global__ __launch_bounds__(256) void ln_kernel(
    const float* __restrict__ in0, unsigned short* __restrict__ out0,
    const float* __restrict__ in1, unsigned short* __restrict__ out1,
    const float* __restrict__ w, const float* __restrict__ bb) {
  const float* in = blockIdx.y ? in1 : in0;
  unsigned short* out = blockIdx.y ? out1 : out0;
  int row = blockIdx.x * 4 + (threadIdx.x >> 6);
  int lane = threadIdx.x & 63;
  const float* p = in + (size_t)row * HID_;
  float4 v0 = *(const float4*)(p + lane * 4);
  float4 v1 = *(const float4*)(p + 256 + lane * 4);
  float s = v0.x + v0.y + v0.z + v0.w + v1.x + v1.y + v1.z + v1.w;
  float q = v0.x * v0.x + v0.y * v0.y + v0.z * v0.z + v0.w * v0.w +
            v1.x * v1.x + v1.y * v1.y + v1.z * v1.z + v1.w * v1.w;
  #pragma unroll
  for (int m = 1; m < 64; m <<= 1) { s += __shfl_xor(s, m, 64); q += __shfl_xor(q, m, 64); }
  float mean = s * (1.f / 512.f);
  float var = q * (1.f / 512.f) - mean * mean;
  float rstd = rsqrtf(var + 1e-5f);
  float4 w0 = *(const float4*)(w + lane * 4);
  float4 w1 = *(const float4*)(w + 256 + lane * 4);
  float4 b0 = *(const float4*)(bb + lane * 4);
  float4 b1 = *(const float4*)(bb + 256 + lane * 4);
  unsigned short* o = out + (size_t)row * HID_;
  ushort4 r0, r1;
  r0.x = f2bf((v0.x - mean) * rstd * w0.x + b0.x);
  r0.y = f2bf((v0.y - mean) * rstd * w0.y + b0.y);
  r0.z = f2bf((v0.z - mean) * rstd * w0.z + b0.z);
  r0.w = f2bf((v0.w - mean) * rstd * w0.w + b0.w);
  r1.x = f2bf((v1.x - mean) * rstd * w1.x + b1.x);
  r1.y = f2bf((v1.y - mean) * rstd * w1.y + b1.y);
  r1.z = f2bf((v1.z - mean) * rstd * w1.z + b1.z);
  r1.w = f2bf((v1.w - mean) * rstd * w1.w + b1.w);
  *(ushort4*)(o + lane * 4) = r0;
  *(ushort4*)(o + 256 + lane * 4) = r1;
}

// ---------------- MFMA GEMM 128x128, BK=64, global_load_lds + XOR swizzle ----------------
// LDS linear [row][64] bf16 (128B rows). LDS[r][blk] = G[r][blk ^ (r&7)] via pre-swizzled
// per-lane global source. ds_read applies the same XOR -> 2-way bank pattern (free).
#define BM 128
#define BN 128
#define BK 64

template <int EPI, int OUTBF>
__global__ __launch_bounds__(256) void gemm_kernel(
    const unsigned short* __restrict__ A, const unsigned short* __restrict__ BT,
    void* __restrict__ Cv, int M, int N, int K,
    const float* __restrict__ bias, const float* __restrict__ resid) {
  __shared__ __align__(16) unsigned short As[BM * BK];
  __shared__ __align__(16) unsigned short Bs[BN * BK];
  int tid = threadIdx.x;
  int lane = tid & 63, wv = tid >> 6;
  int wm = wv >> 1, wn = wv & 1;
  int nwg = gridDim.x * gridDim.y;
  int flat = blockIdx.y * gridDim.x + blockIdx.x;
  int swz = (flat & 7) * (nwg >> 3) + (flat >> 3);   // nwg % 8 == 0 at all call sites
  int bx = swz % gridDim.x, by = swz / gridDim.x;
  int m0 = by * BM, n0 = bx * BN;
  f32x4 acc[4][4] = {};
  int rowblk = lane >> 3;            // 0..7 row within 8-row group
  int sblk = (lane & 7) ^ rowblk;    // pre-swizzled 16B-block index in source row
  int rA = wm * 64 + (lane & 15);
  int rB = wn * 64 + (lane & 15);
  for (int k0 = 0; k0 < K; k0 += BK) {
    __syncthreads();
    #pragma unroll
    for (int it = 0; it < 4; ++it) {
      int r0 = wv * 32 + it * 8;
      gload16(A + (size_t)(m0 + r0 + rowblk) * K + k0 + sblk * 8, &As[r0 * BK]);
      gload16(BT + (size_t)(n0 + r0 + rowblk) * K + k0 + sblk * 8, &Bs[r0 * BK]);
    }
    __syncthreads();
    #pragma unroll
    for (int kx = 0; kx < 2; ++kx) {
      int bidx = (lane >> 4) + kx * 4;
      bf16x8 fa[4], fb[4];
      #pragma unroll
      for (int i = 0; i < 4; ++i) {
        int ra = rA + i * 16;
        int rb = rB + i * 16;
        fa[i] = *(const bf16x8*)&As[ra * BK + ((bidx ^ (ra & 7)) << 3)];
        fb[i] = *(const bf16x8*)&Bs[rb * BK + ((bidx ^ (rb & 7)) << 3)];
      }
      #pragma unroll
      for (int i = 0; i < 4; ++i)
        #pragma unroll
        for (int j = 0; j < 4; ++j)
          acc[i][j] = __builtin_amdgcn_mfma_f32_16x16x32_bf16(fa[i], fb[j], acc[i][j], 0, 0, 0);
    }
  }
  int crow0 = m0 + wm * 64 + (lane >> 4) * 4, ccol0 = n0 + wn * 64 + (lane & 15);
  #pragma unroll
  for (int i = 0; i < 4; ++i) {
    #pragma unroll
    for (int j = 0; j < 4; ++j) {
      int col = ccol0 + j * 16;
      #pragma unroll
      for (int r = 0; r < 4; ++r) {
        int row = crow0 + i * 16 + r;
        float v = acc[i][j][r];
        if (EPI == 1) v += resid[(size_t)row * N + col];
        if (EPI == 2) { v += bias[col]; v = 0.5f * v * (1.f + erff(v * 0.70710678f)); }
        if (EPI == 3) v += bias[col] + resid[(size_t)row * N + col];
        if (OUTBF) ((unsigned short*)Cv)[(size_t)row * N + col] = f2bf(v);
        else       ((float*)Cv)[(size_t)row * N + col] = v;
      }
    }
  }
}

// ---------------- MFMA GEMM 64x128, BK=64, global_load_lds + XOR swizzle ----------------
template <int EPI, int OUTBF>
__global__ __launch_bounds__(256) void gemm64_kernel(
    const unsigned short* __restrict__ A, const unsigned short* __restrict__ BT,
    void* __restrict__ Cv, int M, int N, int K,
    const float* __restrict__ bias, const float* __restrict__ resid) {
  __shared__ __align__(16) unsigned short As[64 * BK];
  __shared__ __align__(16) unsigned short Bs[128 * BK];
  int tid = threadIdx.x;
  int lane = tid & 63, wv = tid >> 6;
  int wm = wv >> 1, wn = wv & 1;
  int nwg = gridDim.x * gridDim.y;
  int flat = blockIdx.y * gridDim.x + blockIdx.x;
  int swz = (flat & 7) * (nwg >> 3) + (flat >> 3);
  int bx = swz % gridDim.x, by = swz / gridDim.x;
  int m0 = by * 64, n0 = bx * BN;
  f32x4 acc[2][4] = {};
  int rowblk = lane >> 3;
  int sblk = (lane & 7) ^ rowblk;
  int rA = wm * 32 + (lane & 15);
  int rB = wn * 64 + (lane & 15);
  for (int k0 = 0; k0 < K; k0 += BK) {
    __syncthreads();
    #pragma unroll
    for (int it = 0; it < 2; ++it) {
      int r0 = wv * 16 + it * 8;
      gload16(A + (size_t)(m0 + r0 + rowblk) * K + k0 + sblk * 8, &As[r0 * BK]);
    }
    #pragma unroll
    for (int it = 0; it < 4; ++it) {
      int r0 = wv * 32 + it * 8;
      gload16(BT + (size_t)(n0 + r0 + rowblk) * K + k0 + sblk * 8, &Bs[r0 * BK]);
    }
    __syncthreads();
    #pragma unroll
    for (int kx = 0; kx < 2; ++kx) {
      int bidx = (lane >> 4) + kx * 4;
      bf16x8 fa[2], fb[4];
      #pragma unroll
      for (int i = 0; i < 2; ++i) {
        int ra = rA + i * 16;
        fa[i] = *(const bf16x8*)&As[ra * BK + ((bidx ^ (ra & 7)) << 3)];
      }
      #pragma unroll
      for (int j = 0; j < 4; ++j) {
        int rb = rB + j * 16;
        fb[j] = *(const bf16x8*)&Bs[rb * BK + ((bidx ^ (rb & 7)) << 3)];
      }
      #pragma unroll
      for (int i = 0; i < 2; ++i)
        #pragma unroll
        for (int j = 0; j < 4; ++j)
          acc[i][j] = __builtin_amdgcn_mfma_f32_16x16x32_bf16(fa[i], fb[j], acc[i][j], 0, 0, 0);
    }
  }
  int crow0 = m0 + wm * 32 + (lane >> 4) * 4, ccol0 = n0 + wn * 64 + (lane & 15);
  #pragma unroll
  for (int i = 0; i < 2; ++i) {
    #pragma unroll
    for (int j = 0; j < 4; ++j) {
      int col = ccol0 + j * 16;
      #pragma unroll
      for (int r = 0; r < 4; ++r) {
        int row = crow0 + i * 16 + r;
        float v = acc[i][j][r];
        if (EPI == 1) v += resid[(size_t)row * N + col];
        if (EPI == 2) { v += bias[col]; v = 0.5f * v * (1.f + erff(v * 0.70710678f)); }
        if (EPI == 3) v += bias[col] + resid[(size_t)row * N + col];
        if (OUTBF) ((unsigned short*)Cv)[(size_t)row * N + col] = f2bf(v);
        else       ((float*)Cv)[(size_t)row * N + col] = v;
      }
    }
  }
}

// ---------------- depthwise 3x3 conv + bias + SiLU; bf16 in (xz), bf16 out ----------------
__global__ __launch_bounds__(256) void conv_kernel(
    const unsigned short* __restrict__ xz, const float* __restrict__ cw,
    const float* __restrict__ cb, unsigned short* __restrict__ xa) {
  int idx = blockIdx.x * 256 + threadIdx.x;
  int d = idx & (DI_ - 1);
  int l = (idx >> 10) & (L_ - 1);
  int b = idx >> 20;
  int hh = l >> 5, ww = l & 31;
  float acc = cb[d];
  #pragma unroll
  for (int dh = -1; dh <= 1; ++dh) {
    int y = hh + dh;
    if ((unsigned)y >= 32u) continue;
    #pragma unroll
    for (int dw = -1; dw <= 1; ++dw) {
      int x = ww + dw;
      if ((unsigned)x >= 32u) continue;
      acc = fmaf(bf2f(xz[((size_t)b * L_ + y * 32 + x) * (2 * DI_) + d]),
                 cw[d * 9 + (dh + 1) * 3 + (dw + 1)], acc);
    }
  }
  float sv = acc / (1.f + __expf(-acc));
  xa[idx] = f2bf(sv);
}

// ---------------- dt projection + softplus -> delta [b][k][l][d] (bf16) ----------------
__global__ __launch_bounds__(256) void delta_kernel(
    const float* __restrict__ sp, const float* __restrict__ dtw,
    const float* __restrict__ dtb, unsigned short* __restrict__ delta) {
  int bk = blockIdx.x;
  int b = bk >> 2, k = bk & 3;
  int dc = blockIdx.y * 256;
  int l0 = blockIdx.z * 128;
  __shared__ float wl[32 * 257];
  __shared__ float rl[128 * 32];
  int tid = threadIdx.x;
  for (int i = tid; i < 256 * 32; i += 256) {
    int dl = i >> 5, r = i & 31;
    wl[r * 257 + dl] = dtw[((size_t)k * DI_ + dc + dl) * R_ + r];
  }
  for (int i = tid; i < 128 * 32; i += 256) {
    int ll = i >> 5, r = i & 31;
    rl[ll * 32 + r] = sp[((size_t)b * L_ + l0 + ll) * 384 + k * R_ + r];
  }
  __syncthreads();
  float bias = dtb[k * DI_ + dc + tid];
  for (int ll = 0; ll < 128; ++ll) {
    float acc = bias;
    #pragma unroll
    for (int r = 0; r < 32; ++r)
      acc = fmaf(rl[ll * 32 + r], wl[r * 257 + tid], acc);
    float dlt = (acc > 15.f) ? acc : log1pf(__expf(acc));
    delta[(((size_t)(b * 4 + k) * L_) + l0 + ll) * DI_ + dc + tid] = f2bf(dlt);
  }
}

// ---------------- selective scan: quad-partial LDS reduce + chunk epilogue ----------------
#define CH 16
#define NCH (L_ / CH)
#define DLP 36
#define YQP 6
__global__ __launch_bounds__(512) void scan_kernel(
    unsigned short* __restrict__ ybuf, const unsigned short* __restrict__ xa,
    const float* __restrict__ sp, const float* __restrict__ Cs,
    const unsigned short* __restrict__ dltb,
    const float* __restrict__ A_logs, const float* __restrict__ Ds) {
  int dblk = blockIdx.x;
  int k = blockIdx.y, b = blockIdx.z;
  int tid = threadIdx.x, lane = tid & 63, wv = tid >> 6;
  int dg = lane >> 4, ng = lane & 15;
  int qp = (lane >> 2) & 3;
  int wd = wv * 4 + dg;
  int gd = k * DI_ + dblk * 32 + wd;
  v2f a2p[2], h2[2];
  #pragma unroll
  for (int j = 0; j < 2; ++j) {
    a2p[j].x = -__expf(A_logs[(size_t)gd * N_ + ng * 4 + 2 * j]) * 1.44269504f;
    a2p[j].y = -__expf(A_logs[(size_t)gd * N_ + ng * 4 + 2 * j + 1]) * 1.44269504f;
    h2[j].x = 0.f; h2[j].y = 0.f;
  }

  __shared__ float Bsh[2][CH][64];
  __shared__ float Csh[2][CH][64];
  __shared__ float DLU[2][32][DLP];
  __shared__ float yq[CH][32][YQP];
  __shared__ float dsh[32];

  const size_t spB = (size_t)b * L_ * 384 + 128 + k * 64;
  const size_t csB = (size_t)b * L_ * 256 + k * 64;
  const size_t dlB = ((size_t)(b * 4 + k) * L_) * DI_ + dblk * 32;
  const size_t xaB = (size_t)b * L_ * DI_ + dblk * 32;

  if (tid < 32) dsh[tid] = Ds[k * DI_ + dblk * 32 + tid];

  int liS = tid >> 5, js = tid & 31;
  int liE = tid >> 5, dd = tid & 31;
  auto posf = [&](int l) {
    int lr = 1023 - l;
    return (k == 0) ? l
         : (k == 1) ? ((l & 31) * 32 + (l >> 5))
         : (k == 2) ? lr
                    : ((lr & 31) * 32 + (lr >> 5));
  };

  {
    *(float2*)&Bsh[0][liS][js * 2] = *(const float2*)(sp + spB + (size_t)liS * 384 + js * 2);
    *(float2*)&Csh[0][liS][js * 2] = *(const float2*)(Cs + csB + (size_t)liS * 256 + js * 2);
    float2 p;
    p.x = bf2f(dltb[dlB + (size_t)liS * DI_ + js]);
    p.y = bf2f(xa[xaB + (size_t)posf(liS) * DI_ + js]);
    *(float2*)&DLU[0][js][liS * 2] = p;
  }
  __syncthreads();

  int cur = 0;
  for (int c = 0; c < NCH; ++c) {
    float2 pB, pC;
    unsigned short pD, pU;
    if (c < NCH - 1) {
      int lb = (c + 1) * CH + liS;
      pB = *(const float2*)(sp + spB + (size_t)lb * 384 + js * 2);
      pC = *(const float2*)(Cs + csB + (size_t)lb * 256 + js * 2);
      pD = dltb[dlB + (size_t)lb * DI_ + js];
      pU = xa[xaB + (size_t)posf(lb) * DI_ + js];
    }
    #pragma unroll
    for (int li2 = 0; li2 < CH; li2 += 2) {
      f32x4 duq = *(const f32x4*)&DLU[cur][wd][li2 * 2];
      #pragma unroll
      for (int s = 0; s < 2; ++s) {
        int li = li2 + s;
        float dlt = s ? duq[2] : duq[0];
        float u   = s ? duq[3] : duq[1];
        float du = dlt * u;
        f32x4 bq = *(const f32x4*)&Bsh[cur][li][ng * 4];
        f32x4 cq = *(const f32x4*)&Csh[cur][li][ng * 4];
        v2f b01 = __builtin_shufflevector(bq, bq, 0, 1);
        v2f b23 = __builtin_shufflevector(bq, bq, 2, 3);
        v2f c01 = __builtin_shufflevector(cq, cq, 0, 1);
        v2f c23 = __builtin_shufflevector(cq, cq, 2, 3);
        v2f dlt2; dlt2.x = dlt; dlt2.y = dlt;
        v2f du2;  du2.x = du;  du2.y = du;
        v2f arg0 = dlt2 * a2p[0];
        v2f arg1 = dlt2 * a2p[1];
        v2f e0, e1;
        e0.x = __builtin_amdgcn_exp2f(arg0.x);
        e0.y = __builtin_amdgcn_exp2f(arg0.y);
        e1.x = __builtin_amdgcn_exp2f(arg1.x);
        e1.y = __builtin_amdgcn_exp2f(arg1.y);
        h2[0] = e0 * h2[0] + du2 * b01;
        h2[1] = e1 * h2[1] + du2 * b23;
        v2f yv = h2[0] * c01 + h2[1] * c23;
        float yp = yv.x + yv.y;
        yp = dpp_add<0xB1>(yp);
        yp = dpp_add<0x4E>(yp);
        yq[li][wd][qp] = yp;
      }
    }
    __syncthreads();
    {
      float2 q01 = *(const float2*)&yq[liE][dd][0];
      float2 q23 = *(const float2*)&yq[liE][dd][2];
      float y = (q01.x + q01.y) + (q23.x + q23.y);
      float u = DLU[cur][dd][liE * 2 + 1];
      y = fmaf(u, dsh[dd], y);
      ybuf[dlB + (size_t)(c * CH + liE) * DI_ + dd] = f2bf(y);
    }
    if (c < NCH - 1) {
      int nxt = cur ^ 1;
      *(float2*)&Bsh[nxt][liS][js * 2] = pB;
      *(float2*)&Csh[nxt][liS][js * 2] = pC;
      float2 p; p.x = bf2f(pD); p.y = bf2f(pU);
      *(float2*)&DLU[nxt][js][liS * 2] = p;
    }
    __syncthreads();
    cur ^= 1;
  }
}

// ---------------- fuse: ygz = (sum_k yk) * z  (yk bf16, z bf16) -> bf16 ----------------
__global__ __launch_bounds__(256) void fuse_ygz(
    const unsigned short* __restrict__ yk, const unsigned short* __restrict__ xz,
    unsigned short* __restrict__ ygz) {
  size_t i = ((size_t)blockIdx.x * 256 + threadIdx.x) * 8;
  size_t b = i >> 20, ld = i & ((1u << 20) - 1);
  float acc[8] = {};
  #pragma unroll
  for (int k = 0; k < 4; ++k) {
    uint4 v = *(const uint4*)(yk + ((size_t)(b * 4 + k) << 20) + ld);
    unsigned int w[4] = {v.x, v.y, v.z, v.w};
    #pragma unroll
    for (int t = 0; t < 4; ++t) {
      acc[t * 2 + 0] += __builtin_bit_cast(float, w[t] << 16);
      acc[t * 2 + 1] += __builtin_bit_cast(float, w[t] & 0xFFFF0000u);
    }
  }
  uint4 zv = *(const uint4*)(xz + (i >> 10) * (2 * DI_) + DI_ + (i & (DI_ - 1)));
  unsigned int zw[4] = {zv.x, zv.y, zv.z, zv.w};
  float z[8];
  #pragma unroll
  for (int t = 0; t < 4; ++t) {
    z[t * 2 + 0] = __builtin_bit_cast(float, zw[t] << 16);
    z[t * 2 + 1] = __builtin_bit_cast(float, zw[t] & 0xFFFF0000u);
  }
  uint4 o;
  o.x = (unsigned int)f2bf(acc[0] * z[0]) | ((unsigned int)f2bf(acc[1] * z[1]) << 16);
  o.y = (unsigned int)f2bf(acc[2] * z[2]) | ((unsigned int)f2bf(acc[3] * z[3]) << 16);
  o.z = (unsigned int)f2bf(acc[4] * z[4]) | ((unsigned int)f2bf(acc[5] * z[5]) << 16);
  o.w = (unsigned int)f2bf(acc[6] * z[6]) | ((unsigned int)f2bf(acc[7] * z[7]) << 16);
  *(uint4*)(ygz + i) = o;
}

// ---------------- host ----------------
extern "C" void kernel_launch(void* const* d_in, const int* in_sizes, int n_in,
                              void* d_out, int out_size, void* d_ws, size_t ws_size,
                              hipStream_t stream) {
  (void)in_sizes; (void)n_in; (void)out_size; (void)ws_size;
  const float* content   = (const float*)d_in[0];
  const float* style     = (const float*)d_in[1];
  const float* norm1_w   = (const float*)d_in[2];
  const float* norm1_b   = (const float*)d_in[3];
  const float* in_proj_w = (const float*)d_in[4];
  const float* conv_w    = (const float*)d_in[5];
  const float* conv_b    = (const float*)d_in[6];
  const float* style_proj_w   = (const float*)d_in[7];
  const float* content_proj_w = (const float*)d_in[8];
  const float* dtw       = (const float*)d_in[9];
  const float* dtb       = (const float*)d_in[10];
  const float* A_logs    = (const float*)d_in[11];
  const float* Ds        = (const float*)d_in[12];
  const float* out_proj_w = (const float*)d_in[13];
  const float* norm2_w   = (const float*)d_in[14];
  const float* norm2_b   = (const float*)d_in[15];
  const float* mlp_w1    = (const float*)d_in[16];
  const float* mlp_b1    = (const float*)d_in[17];
  const float* mlp_w2    = (const float*)d_in[18];
  const float* mlp_b2    = (const float*)d_in[19];
  float* out = (float*)d_out;

  float* ws = (float*)d_ws;
  const size_t ROWS = (size_t)B_ * L_;
  const size_t SCAN_ELEMS = (size_t)B_ * K_ * L_ * DI_;
  size_t o = 0;
  unsigned short* cn  = (unsigned short*)(ws + o); o += ROWS * HID_ / 2;
  unsigned short* sn  = (unsigned short*)(ws + o); o += ROWS * HID_ / 2;
  unsigned short* xn  = (unsigned short*)(ws + o); o += ROWS * HID_ / 2;
  unsigned short* xz  = (unsigned short*)(ws + o); o += ROWS * 2 * DI_ / 2;
  float* sp    = ws + o; o += ROWS * 384;
  unsigned short* xa = (unsigned short*)(ws + o); o += ROWS * DI_ / 2;
  float* csb   = ws + o; o += ROWS * 256;
  float* x1    = ws + o; o += ROWS * HID_;
  unsigned short* dltb = (unsigned short*)(ws + o); o += SCAN_ELEMS / 2;
  unsigned short* ybuf = (unsigned short*)(ws + o); o += SCAN_ELEMS / 2;
  unsigned short* ygz  = (unsigned short*)(ws + o); o += ROWS * DI_ / 2;
  unsigned short* wt = (unsigned short*)(ws + o);
  unsigned short* inpT = wt;
  unsigned short* styT = inpT + 2048 * 512;
  unsigned short* conT = styT + 384 * 512;
  unsigned short* outT = conT + 256 * 1024;
  unsigned short* w1T  = outT + 512 * 1024;
  unsigned short* w2T  = w1T + 2048 * 512;
  unsigned short* hmid = ybuf;

  transpose_all<<<4032, 256, 0, stream>>>(
      in_proj_w, style_proj_w, content_proj_w, out_proj_w, mlp_w1, mlp_w2,
      inpT, styT, conT, outT, w1T, w2T);

  ln_kernel<<<dim3(ROWS / 4, 2), 256, 0, stream>>>(content, cn, style, sn, norm1_w, norm1_b);

  gemm_kernel<0, 1><<<dim3(2048 / BN, ROWS / BM), 256, 0, stream>>>(
      cn, inpT, xz, ROWS, 2048, 512, nullptr, nullptr);
  gemm64_kernel<0, 0><<<dim3(384 / BN, ROWS / 64), 256, 0, stream>>>(
      sn, styT, sp, ROWS, 384, 512, nullptr, nullptr);
  conv_kernel<<<(ROWS * DI_) / 256, 256, 0, stream>>>(xz, conv_w, conv_b, xa);
  gemm64_kernel<0, 0><<<dim3(256 / BN, ROWS / 64), 256, 0, stream>>>(
      xa, conT, csb, ROWS, 256, 1024, nullptr, nullptr);
  delta_kernel<<<dim3(B_ * K_, DI_ / 256, L_ / 128), 256, 0, stream>>>(sp, dtw, dtb, dltb);
  scan_kernel<<<dim3(DI_ / 32, K_, B_), 512, 0, stream>>>(
      ybuf, xa, sp, csb, dltb, A_logs, Ds);
  fuse_ygz<<<(ROWS * DI_) / (256 * 8), 256, 0, stream>>>(ybuf, xz, ygz);
  gemm64_kernel<1, 0><<<dim3(512 / BN, ROWS / 64), 256, 0, stream>>>(
      ygz, outT, x1, ROWS, 512, 1024, nullptr, content);
  ln_kernel<<<dim3(ROWS / 4, 1), 256, 0, stream>>>(x1, xn, nullptr, nullptr, norm2_w, norm2_b);
  gemm_kernel<2, 1><<<dim3(2048 / BN, ROWS / BM), 256, 0, stream>>>(
      xn, w1T, hmid, ROWS, 2048, 512, mlp_b1, nullptr);
  gemm64_kernel<3, 0><<<dim3(512 / BN, ROWS / 64), 256, 0, stream>>>(
      hmid, w2T, out, ROWS, 512, 2048, mlp_b2, x1);
}

// Round 12
// 461.185 us; speedup vs baseline: 1.4587x; 1.0062x over previous
//
#include <hip/hip_runtime.h>

// ---------------- constants ----------------
#define B_ 4
#define Hh_ 32
#define Ww_ 32
#define L_ 1024
#define HID_ 512
#define DI_ 1024
#define N_ 64
#define R_ 32
#define K_ 4
#define MLP_ 2048

typedef __bf16 bf16x8 __attribute__((ext_vector_type(8)));
typedef float f32x4 __attribute__((ext_vector_type(4)));
typedef float v2f __attribute__((ext_vector_type(2)));

__device__ __forceinline__ unsigned short f2bf(float f) {
  unsigned int u = __builtin_bit_cast(unsigned int, f);
  return (unsigned short)((u + 0x7FFFu + ((u >> 16) & 1u)) >> 16);
}
__device__ __forceinline__ float bf2f(unsigned short h) {
  return __builtin_bit_cast(float, (unsigned int)h << 16);
}
__device__ __forceinline__ float2 bfp2f(unsigned int u) {
  float2 r;
  r.x = __builtin_bit_cast(float, u << 16);
  r.y = __builtin_bit_cast(float, u & 0xFFFF0000u);
  return r;
}

// async global->LDS, 16B per lane; lds base must be wave-uniform
__device__ __forceinline__ void gload16(const unsigned short* g, unsigned short* l) {
  __builtin_amdgcn_global_load_lds(
      (const __attribute__((address_space(1))) unsigned int*)g,
      (__attribute__((address_space(3))) unsigned int*)l, 16, 0, 0);
}

// DPP add: x + x[perm(lane)] on the VALU pipe (no DS traffic)
template <int CTRL>
__device__ __forceinline__ float dpp_add(float x) {
  int i = __builtin_bit_cast(int, x);
  int j = __builtin_amdgcn_update_dpp(i, i, CTRL, 0xF, 0xF, false);
  return x + __builtin_bit_cast(float, j);
}

// ---------------- all 6 weight transposes in ONE launch ----------------
__global__ __launch_bounds__(256) void transpose_all(
    const float* __restrict__ s0, const float* __restrict__ s1,
    const float* __restrict__ s2, const float* __restrict__ s3,
    const float* __restrict__ s4, const float* __restrict__ s5,
    unsigned short* __restrict__ t0, unsigned short* __restrict__ t1,
    unsigned short* __restrict__ t2, unsigned short* __restrict__ t3,
    unsigned short* __restrict__ t4, unsigned short* __restrict__ t5) {
  __shared__ float t[32][33];
  int bid = blockIdx.x;
  const float* src; unsigned short* dst; int K, N, bx, by;
  if (bid < 1024)      { src = s0; dst = t0; K = 512;  N = 2048; int r = bid;        bx = r & 63; by = r >> 6; }
  else if (bid < 1216) { src = s1; dst = t1; K = 512;  N = 384;  int r = bid - 1024; bx = r % 12; by = r / 12; }
  else if (bid < 1472) { src = s2; dst = t2; K = 1024; N = 256;  int r = bid - 1216; bx = r & 7;  by = r >> 3; }
  else if (bid < 1984) { src = s3; dst = t3; K = 1024; N = 512;  int r = bid - 1472; bx = r & 15; by = r >> 4; }
  else if (bid < 3008) { src = s4; dst = t4; K = 512;  N = 2048; int r = bid - 1984; bx = r & 63; by = r >> 6; }
  else                 { src = s5; dst = t5; K = 2048; N = 512;  int r = bid - 3008; bx = r & 15; by = r >> 4; }
  int nb = bx * 32, kb = by * 32;
  int tx = threadIdx.x & 31, ty = threadIdx.x >> 5;
  for (int r = ty; r < 32; r += 8) t[r][tx] = src[(size_t)(kb + r) * N + nb + tx];
  __syncthreads();
  for (int r = ty; r < 32; r += 8) dst[(size_t)(nb + r) * K + kb + tx] = f2bf(t[tx][r]);
}

// ---------------- cast f32 -> bf16 (for dtw) ----------------
__global__ __launch_bounds__(256) void cast_bf(
    const float* __restrict__ src, unsigned short* __restrict__ dst) {
  int i = (blockIdx.x * 256 + threadIdx.x) * 4;
  float4 v = *(const float4*)(src + i);
  ushort4 o = {f2bf(v.x), f2bf(v.y), f2bf(v.z), f2bf(v.w)};
  *(ushort4*)(dst + i) = o;
}

// ---------------- LayerNorm over 512, wave per row; writes bf16 ----------------
__global__ __launch_bounds__(256) void ln_kernel(
    const float* __restrict__ in0, unsigned short* __restrict__ out0,
    const float* __restrict__ in1, unsigned short* __restrict__ out1,
    const float* __restrict__ w, const float* __restrict__ bb) {
  const float* in = blockIdx.y ? in1 : in0;
  unsigned short* out = blockIdx.y ? out1 : out0;
  int row = blockIdx.x * 4 + (threadIdx.x >> 6);
  int lane = threadIdx.x & 63;
  const float* p = in + (size_t)row * HID_;
  float4 v0 = *(const float4*)(p + lane * 4);
  float4 v1 = *(const float4*)(p + 256 + lane * 4);
  float s = v0.x + v0.y + v0.z + v0.w + v1.x + v1.y + v1.z + v1.w;
  float q = v0.x * v0.x + v0.y * v0.y + v0.z * v0.z + v0.w * v0.w +
            v1.x * v1.x + v1.y * v1.y + v1.z * v1.z + v1.w * v1.w;
  #pragma unroll
  for (int m = 1; m < 64; m <<= 1) { s += __shfl_xor(s, m, 64); q += __shfl_xor(q, m, 64); }
  float mean = s * (1.f / 512.f);
  float var = q * (1.f / 512.f) - mean * mean;
  float rstd = rsqrtf(var + 1e-5f);
  float4 w0 = *(const float4*)(w + lane * 4);
  float4 w1 = *(const float4*)(w + 256 + lane * 4);
  float4 b0 = *(const float4*)(bb + lane * 4);
  float4 b1 = *(const float4*)(bb + 256 + lane * 4);
  unsigned short* o = out + (size_t)row * HID_;
  ushort4 r0, r1;
  r0.x = f2bf((v0.x - mean) * rstd * w0.x + b0.x);
  r0.y = f2bf((v0.y - mean) * rstd * w0.y + b0.y);
  r0.z = f2bf((v0.z - mean) * rstd * w0.z + b0.z);
  r0.w = f2bf((v0.w - mean) * rstd * w0.w + b0.w);
  r1.x = f2bf((v1.x - mean) * rstd * w1.x + b1.x);
  r1.y = f2bf((v1.y - mean) * rstd * w1.y + b1.y);
  r1.z = f2bf((v1.z - mean) * rstd * w1.z + b1.z);
  r1.w = f2bf((v1.w - mean) * rstd * w1.w + b1.w);
  *(ushort4*)(o + lane * 4) = r0;
  *(ushort4*)(o + 256 + lane * 4) = r1;
}

// ---------------- MFMA GEMM 128x128, BK=64, global_load_lds + XOR swizzle ----------------
#define BM 128
#define BN 128
#define BK 64

template <int EPI, int OUTBF>
__global__ __launch_bounds__(256) void gemm_kernel(
    const unsigned short* __restrict__ A, const unsigned short* __restrict__ BT,
    void* __restrict__ Cv, int M, int N, int K,
    const float* __restrict__ bias, const float* __restrict__ resid) {
  __shared__ __align__(16) unsigned short As[BM * BK];
  __shared__ __align__(16) unsigned short Bs[BN * BK];
  int tid = threadIdx.x;
  int lane = tid & 63, wv = tid >> 6;
  int wm = wv >> 1, wn = wv & 1;
  int nwg = gridDim.x * gridDim.y;
  int flat = blockIdx.y * gridDim.x + blockIdx.x;
  int swz = (flat & 7) * (nwg >> 3) + (flat >> 3);
  int bx = swz % gridDim.x, by = swz / gridDim.x;
  int m0 = by * BM, n0 = bx * BN;
  f32x4 acc[4][4] = {};
  int rowblk = lane >> 3;
  int sblk = (lane & 7) ^ rowblk;
  int rA = wm * 64 + (lane & 15);
  int rB = wn * 64 + (lane & 15);
  for (int k0 = 0; k0 < K; k0 += BK) {
    __syncthreads();
    #pragma unroll
    for (int it = 0; it < 4; ++it) {
      int r0 = wv * 32 + it * 8;
      gload16(A + (size_t)(m0 + r0 + rowblk) * K + k0 + sblk * 8, &As[r0 * BK]);
      gload16(BT + (size_t)(n0 + r0 + rowblk) * K + k0 + sblk * 8, &Bs[r0 * BK]);
    }
    __syncthreads();
    #pragma unroll
    for (int kx = 0; kx < 2; ++kx) {
      int bidx = (lane >> 4) + kx * 4;
      bf16x8 fa[4], fb[4];
      #pragma unroll
      for (int i = 0; i < 4; ++i) {
        int ra = rA + i * 16;
        int rb = rB + i * 16;
        fa[i] = *(const bf16x8*)&As[ra * BK + ((bidx ^ (ra & 7)) << 3)];
        fb[i] = *(const bf16x8*)&Bs[rb * BK + ((bidx ^ (rb & 7)) << 3)];
      }
      #pragma unroll
      for (int i = 0; i < 4; ++i)
        #pragma unroll
        for (int j = 0; j < 4; ++j)
          acc[i][j] = __builtin_amdgcn_mfma_f32_16x16x32_bf16(fa[i], fb[j], acc[i][j], 0, 0, 0);
    }
  }
  int crow0 = m0 + wm * 64 + (lane >> 4) * 4, ccol0 = n0 + wn * 64 + (lane & 15);
  #pragma unroll
  for (int i = 0; i < 4; ++i) {
    #pragma unroll
    for (int j = 0; j < 4; ++j) {
      int col = ccol0 + j * 16;
      #pragma unroll
      for (int r = 0; r < 4; ++r) {
        int row = crow0 + i * 16 + r;
        float v = acc[i][j][r];
        if (EPI == 1) v += resid[(size_t)row * N + col];
        if (EPI == 2) { v += bias[col]; v = 0.5f * v * (1.f + erff(v * 0.70710678f)); }
        if (EPI == 3) v += bias[col] + resid[(size_t)row * N + col];
        if (OUTBF) ((unsigned short*)Cv)[(size_t)row * N + col] = f2bf(v);
        else       ((float*)Cv)[(size_t)row * N + col] = v;
      }
    }
  }
}

// ---------------- MFMA GEMM 64x128, BK=64, global_load_lds + XOR swizzle ----------------
template <int EPI, int OUTBF>
__global__ __launch_bounds__(256) void gemm64_kernel(
    const unsigned short* __restrict__ A, const unsigned short* __restrict__ BT,
    void* __restrict__ Cv, int M, int N, int K,
    const float* __restrict__ bias, const float* __restrict__ resid) {
  __shared__ __align__(16) unsigned short As[64 * BK];
  __shared__ __align__(16) unsigned short Bs[128 * BK];
  int tid = threadIdx.x;
  int lane = tid & 63, wv = tid >> 6;
  int wm = wv >> 1, wn = wv & 1;
  int nwg = gridDim.x * gridDim.y;
  int flat = blockIdx.y * gridDim.x + blockIdx.x;
  int swz = (flat & 7) * (nwg >> 3) + (flat >> 3);
  int bx = swz % gridDim.x, by = swz / gridDim.x;
  int m0 = by * 64, n0 = bx * BN;
  f32x4 acc[2][4] = {};
  int rowblk = lane >> 3;
  int sblk = (lane & 7) ^ rowblk;
  int rA = wm * 32 + (lane & 15);
  int rB = wn * 64 + (lane & 15);
  for (int k0 = 0; k0 < K; k0 += BK) {
    __syncthreads();
    #pragma unroll
    for (int it = 0; it < 2; ++it) {
      int r0 = wv * 16 + it * 8;
      gload16(A + (size_t)(m0 + r0 + rowblk) * K + k0 + sblk * 8, &As[r0 * BK]);
    }
    #pragma unroll
    for (int it = 0; it < 4; ++it) {
      int r0 = wv * 32 + it * 8;
      gload16(BT + (size_t)(n0 + r0 + rowblk) * K + k0 + sblk * 8, &Bs[r0 * BK]);
    }
    __syncthreads();
    #pragma unroll
    for (int kx = 0; kx < 2; ++kx) {
      int bidx = (lane >> 4) + kx * 4;
      bf16x8 fa[2], fb[4];
      #pragma unroll
      for (int i = 0; i < 2; ++i) {
        int ra = rA + i * 16;
        fa[i] = *(const bf16x8*)&As[ra * BK + ((bidx ^ (ra & 7)) << 3)];
      }
      #pragma unroll
      for (int j = 0; j < 4; ++j) {
        int rb = rB + j * 16;
        fb[j] = *(const bf16x8*)&Bs[rb * BK + ((bidx ^ (rb & 7)) << 3)];
      }
      #pragma unroll
      for (int i = 0; i < 2; ++i)
        #pragma unroll
        for (int j = 0; j < 4; ++j)
          acc[i][j] = __builtin_amdgcn_mfma_f32_16x16x32_bf16(fa[i], fb[j], acc[i][j], 0, 0, 0);
    }
  }
  int crow0 = m0 + wm * 32 + (lane >> 4) * 4, ccol0 = n0 + wn * 64 + (lane & 15);
  #pragma unroll
  for (int i = 0; i < 2; ++i) {
    #pragma unroll
    for (int j = 0; j < 4; ++j) {
      int col = ccol0 + j * 16;
      #pragma unroll
      for (int r = 0; r < 4; ++r) {
        int row = crow0 + i * 16 + r;
        float v = acc[i][j][r];
        if (EPI == 1) v += resid[(size_t)row * N + col];
        if (EPI == 2) { v += bias[col]; v = 0.5f * v * (1.f + erff(v * 0.70710678f)); }
        if (EPI == 3) v += bias[col] + resid[(size_t)row * N + col];
        if (OUTBF) ((unsigned short*)Cv)[(size_t)row * N + col] = f2bf(v);
        else       ((float*)Cv)[(size_t)row * N + col] = v;
      }
    }
  }
}

// ---------------- delta GEMM: softplus(spRank @ dtw^T + dtb) -> bf16 ----------------
// A = sp (bf16, row stride 384, offset kq*32), BT = dtwB[kq] (DI x 32 bf16), K=32.
__global__ __launch_bounds__(256) void dtgemm_kernel(
    const unsigned short* __restrict__ sp, const unsigned short* __restrict__ dtwB,
    const float* __restrict__ dtb, unsigned short* __restrict__ delta) {
  int kq = blockIdx.z;
  int m0 = blockIdx.y * 64, n0 = blockIdx.x * 128;
  __shared__ __align__(16) unsigned short As[64 * 32];
  __shared__ __align__(16) unsigned short Bs[128 * 32];
  int tid = threadIdx.x, lane = tid & 63, wv = tid >> 6;
  int wm = wv >> 1, wn = wv & 1;
  {
    int r = tid >> 2, c = (tid & 3) * 8;
    *(uint4*)&As[r * 32 + c] = *(const uint4*)(sp + (size_t)(m0 + r) * 384 + kq * 32 + c);
  }
  {
    int r = tid >> 1, c = (tid & 1) * 16;
    const unsigned short* p = dtwB + (size_t)(kq * DI_ + n0 + r) * 32 + c;
    *(uint4*)&Bs[r * 32 + c] = *(const uint4*)(p);
    *(uint4*)&Bs[r * 32 + c + 8] = *(const uint4*)(p + 8);
  }
  __syncthreads();
  int kk = (lane >> 4) * 8;
  int rA = wm * 32 + (lane & 15);
  int rB = wn * 64 + (lane & 15);
  f32x4 acc[2][4] = {};
  bf16x8 fa[2], fb[4];
  #pragma unroll
  for (int i = 0; i < 2; ++i) fa[i] = *(const bf16x8*)&As[(rA + i * 16) * 32 + kk];
  #pragma unroll
  for (int j = 0; j < 4; ++j) fb[j] = *(const bf16x8*)&Bs[(rB + j * 16) * 32 + kk];
  #pragma unroll
  for (int i = 0; i < 2; ++i)
    #pragma unroll
    for (int j = 0; j < 4; ++j)
      acc[i][j] = __builtin_amdgcn_mfma_f32_16x16x32_bf16(fa[i], fb[j], acc[i][j], 0, 0, 0);
  int crow0 = m0 + wm * 32 + (lane >> 4) * 4, ccol0 = n0 + wn * 64 + (lane & 15);
  #pragma unroll
  for (int i = 0; i < 2; ++i) {
    #pragma unroll
    for (int j = 0; j < 4; ++j) {
      int col = ccol0 + j * 16;
      float bias = dtb[kq * DI_ + col];
      #pragma unroll
      for (int r = 0; r < 4; ++r) {
        int row = crow0 + i * 16 + r;
        float v = acc[i][j][r] + bias;
        v = (v > 15.f) ? v : log1pf(__expf(v));
        int bb = row >> 10, l = row & 1023;
        delta[(((size_t)(bb * 4 + kq)) << 20) + ((size_t)l << 10) + col] = f2bf(v);
      }
    }
  }
}

// ---------------- depthwise 3x3 conv + bias + SiLU; bf16 in (xz), bf16 out ----------------
__global__ __launch_bounds__(256) void conv_kernel(
    const unsigned short* __restrict__ xz, const float* __restrict__ cw,
    const float* __restrict__ cb, unsigned short* __restrict__ xa) {
  int idx = blockIdx.x * 256 + threadIdx.x;
  int d = idx & (DI_ - 1);
  int l = (idx >> 10) & (L_ - 1);
  int b = idx >> 20;
  int hh = l >> 5, ww = l & 31;
  float acc = cb[d];
  #pragma unroll
  for (int dh = -1; dh <= 1; ++dh) {
    int y = hh + dh;
    if ((unsigned)y >= 32u) continue;
    #pragma unroll
    for (int dw = -1; dw <= 1; ++dw) {
      int x = ww + dw;
      if ((unsigned)x >= 32u) continue;
      acc = fmaf(bf2f(xz[((size_t)b * L_ + y * 32 + x) * (2 * DI_) + d]),
                 cw[d * 9 + (dh + 1) * 3 + (dw + 1)], acc);
    }
  }
  float sv = acc / (1.f + __expf(-acc));
  xa[idx] = f2bf(sv);
}

// ---------------- selective scan: 2 d x 4 n per lane (halved DS per unit work) ----------------
// lane = dg*16 + ng; dg = lane>>4 (4), ng = lane&15. Lane owns d = wv*8+dg and d+4.
// Block 512 thr = 8 waves = 64 d. Grid (DI/64, K, B) = 256 blocks.
// Per step DS: DLUp b128 + B b128 + C b128 + 1 yq b64 write (both d partials packed).
#define CH 16
#define NCH (L_ / CH)
__global__ __launch_bounds__(512) void scan_kernel(
    unsigned short* __restrict__ ybuf, const unsigned short* __restrict__ xa,
    const unsigned short* __restrict__ sp, const unsigned short* __restrict__ Cs,
    const unsigned short* __restrict__ dltb,
    const float* __restrict__ A_logs, const float* __restrict__ Ds) {
  int dblk = blockIdx.x;           // 16 blocks of 64 d
  int k = blockIdx.y, b = blockIdx.z;
  int tid = threadIdx.x, lane = tid & 63, wv = tid >> 6;
  int dg = lane >> 4, ng = lane & 15;
  int qp = (lane >> 2) & 3;
  int wd0 = wv * 8 + dg;           // first d of this lane (second is +4)
  int slot = wv * 4 + dg;
  int gd0 = k * DI_ + dblk * 64 + wd0;
  v2f a2p[2][2], h2[2][2];
  {
    f32x4 al0 = *(const f32x4*)(A_logs + (size_t)gd0 * N_ + ng * 4);
    f32x4 al1 = *(const f32x4*)(A_logs + (size_t)(gd0 + 4) * N_ + ng * 4);
    a2p[0][0].x = -__expf(al0[0]) * 1.44269504f; a2p[0][0].y = -__expf(al0[1]) * 1.44269504f;
    a2p[0][1].x = -__expf(al0[2]) * 1.44269504f; a2p[0][1].y = -__expf(al0[3]) * 1.44269504f;
    a2p[1][0].x = -__expf(al1[0]) * 1.44269504f; a2p[1][0].y = -__expf(al1[1]) * 1.44269504f;
    a2p[1][1].x = -__expf(al1[2]) * 1.44269504f; a2p[1][1].y = -__expf(al1[3]) * 1.44269504f;
    #pragma unroll
    for (int di = 0; di < 2; ++di)
      #pragma unroll
      for (int j = 0; j < 2; ++j) { h2[di][j].x = 0.f; h2[di][j].y = 0.f; }
  }

  __shared__ float Bsh[2][CH][64];
  __shared__ float Csh[2][CH][64];
  __shared__ float DLUp[2][CH][32][4];  // {dlt0,u0,dlt1,u1} per (li, slot)
  __shared__ float yq[CH][32][4][2];    // partials [li][slot][qp][di]
  __shared__ float dsh[64];

  const size_t spB = (size_t)b * L_ * 384 + 128 + k * 64;  // bf16 elems
  const size_t csB = (size_t)b * L_ * 256 + k * 64;        // bf16 elems
  const size_t dlB = ((size_t)(b * 4 + k) * L_) * DI_ + dblk * 64;
  const size_t xaB = (size_t)b * L_ * DI_ + dblk * 64;

  if (tid < 64) dsh[tid] = Ds[k * DI_ + dblk * 64 + tid];

  int liS = tid >> 5, js = tid & 31;
  int d0S = (js >> 2) * 8 + (js & 3);  // DLU/epilogue d (and +4)
  auto posf = [&](int l) {
    int lr = 1023 - l;
    return (k == 0) ? l
         : (k == 1) ? ((l & 31) * 32 + (l >> 5))
         : (k == 2) ? lr
                    : ((lr & 31) * 32 + (lr >> 5));
  };

  // stage chunk 0
  {
    float2 fB = bfp2f(*(const unsigned int*)(sp + spB + (size_t)liS * 384 + js * 2));
    float2 fC = bfp2f(*(const unsigned int*)(Cs + csB + (size_t)liS * 256 + js * 2));
    *(float2*)&Bsh[0][liS][js * 2] = fB;
    *(float2*)&Csh[0][liS][js * 2] = fC;
    int pp = posf(liS);
    f32x4 w;
    w[0] = bf2f(dltb[dlB + (size_t)liS * DI_ + d0S]);
    w[1] = bf2f(xa[xaB + (size_t)pp * DI_ + d0S]);
    w[2] = bf2f(dltb[dlB + (size_t)liS * DI_ + d0S + 4]);
    w[3] = bf2f(xa[xaB + (size_t)pp * DI_ + d0S + 4]);
    *(f32x4*)&DLUp[0][liS][js][0] = w;
  }
  __syncthreads();

  int cur = 0;
  for (int c = 0; c < NCH; ++c) {
    unsigned int pB, pC;
    unsigned short pD0, pD1, pU0, pU1;
    if (c < NCH - 1) {
      int lb = (c + 1) * CH + liS;
      pB = *(const unsigned int*)(sp + spB + (size_t)lb * 384 + js * 2);
      pC = *(const unsigned int*)(Cs + csB + (size_t)lb * 256 + js * 2);
      pD0 = dltb[dlB + (size_t)lb * DI_ + d0S];
      pD1 = dltb[dlB + (size_t)lb * DI_ + d0S + 4];
      int pp = posf(lb);
      pU0 = xa[xaB + (size_t)pp * DI_ + d0S];
      pU1 = xa[xaB + (size_t)pp * DI_ + d0S + 4];
    }
    #pragma unroll
    for (int li = 0; li < CH; ++li) {
      f32x4 duq = *(const f32x4*)&DLUp[cur][li][slot][0];
      f32x4 bq = *(const f32x4*)&Bsh[cur][li][ng * 4];
      f32x4 cq = *(const f32x4*)&Csh[cur][li][ng * 4];
      v2f b01 = __builtin_shufflevector(bq, bq, 0, 1);
      v2f b23 = __builtin_shufflevector(bq, bq, 2, 3);
      v2f c01 = __builtin_shufflevector(cq, cq, 0, 1);
      v2f c23 = __builtin_shufflevector(cq, cq, 2, 3);
      float yps0, yps1;
      #pragma unroll
      for (int di = 0; di < 2; ++di) {
        float dlt = di ? duq[2] : duq[0];
        float u   = di ? duq[3] : duq[1];
        float du = dlt * u;
        v2f dlt2; dlt2.x = dlt; dlt2.y = dlt;
        v2f du2;  du2.x = du;  du2.y = du;
        v2f arg0 = dlt2 * a2p[di][0];
        v2f arg1 = dlt2 * a2p[di][1];
        v2f e0, e1;
        e0.x = __builtin_amdgcn_exp2f(arg0.x);
        e0.y = __builtin_amdgcn_exp2f(arg0.y);
        e1.x = __builtin_amdgcn_exp2f(arg1.x);
        e1.y = __builtin_amdgcn_exp2f(arg1.y);
        h2[di][0] = e0 * h2[di][0] + du2 * b01;
        h2[di][1] = e1 * h2[di][1] + du2 * b23;
        v2f yv = h2[di][0] * c01 + h2[di][1] * c23;
        float yp = yv.x + yv.y;
        yp = dpp_add<0xB1>(yp);   // quad xor1
        yp = dpp_add<0x4E>(yp);   // quad xor2 -> 16-n quad partial
        if (di) yps1 = yp; else yps0 = yp;
      }
      float2 pr; pr.x = yps0; pr.y = yps1;
      *(float2*)&yq[li][slot][qp][0] = pr;  // 4 lanes same addr (benign)
    }
    __syncthreads();  // yq complete; DLUp[cur] still valid
    {  // epilogue: thread (liS, js) -> y for (d0S, d0S+4) at step c*CH+liS
      f32x4 q0 = *(const f32x4*)&yq[liS][js][0][0];
      f32x4 q1 = *(const f32x4*)&yq[liS][js][2][0];
      float y0 = (q0[0] + q0[2]) + (q1[0] + q1[2]);
      float y1 = (q0[1] + q0[3]) + (q1[1] + q1[3]);
      f32x4 du4 = *(const f32x4*)&DLUp[cur][liS][js][0];
      y0 = fmaf(du4[1], dsh[d0S], y0);
      y1 = fmaf(du4[3], dsh[d0S + 4], y1);
      size_t yb = dlB + (size_t)(c * CH + liS) * DI_;
      ybuf[yb + d0S] = f2bf(y0);
      ybuf[yb + d0S + 4] = f2bf(y1);
    }
    if (c < NCH - 1) {
      int nxt = cur ^ 1;
      *(float2*)&Bsh[nxt][liS][js * 2] = bfp2f(pB);
      *(float2*)&Csh[nxt][liS][js * 2] = bfp2f(pC);
      f32x4 w;
      w[0] = bf2f(pD0); w[1] = bf2f(pU0); w[2] = bf2f(pD1); w[3] = bf2f(pU1);
      *(f32x4*)&DLUp[nxt][liS][js][0] = w;
    }
    __syncthreads();  // staging visible; yq free for next chunk
    cur ^= 1;
  }
}

// ---------------- fuse: ygz = (sum_k yk) * z  (yk bf16, z bf16) -> bf16 ----------------
__global__ __launch_bounds__(256) void fuse_ygz(
    const unsigned short* __restrict__ yk, const unsigned short* __restrict__ xz,
    unsigned short* __restrict__ ygz) {
  size_t i = ((size_t)blockIdx.x * 256 + threadIdx.x) * 8;
  size_t b = i >> 20, ld = i & ((1u << 20) - 1);
  float acc[8] = {};
  #pragma unroll
  for (int k = 0; k < 4; ++k) {
    uint4 v = *(const uint4*)(yk + ((size_t)(b * 4 + k) << 20) + ld);
    unsigned int w[4] = {v.x, v.y, v.z, v.w};
    #pragma unroll
    for (int t = 0; t < 4; ++t) {
      acc[t * 2 + 0] += __builtin_bit_cast(float, w[t] << 16);
      acc[t * 2 + 1] += __builtin_bit_cast(float, w[t] & 0xFFFF0000u);
    }
  }
  uint4 zv = *(const uint4*)(xz + (i >> 10) * (2 * DI_) + DI_ + (i & (DI_ - 1)));
  unsigned int zw[4] = {zv.x, zv.y, zv.z, zv.w};
  float z[8];
  #pragma unroll
  for (int t = 0; t < 4; ++t) {
    z[t * 2 + 0] = __builtin_bit_cast(float, zw[t] << 16);
    z[t * 2 + 1] = __builtin_bit_cast(float, zw[t] & 0xFFFF0000u);
  }
  uint4 o;
  o.x = (unsigned int)f2bf(acc[0] * z[0]) | ((unsigned int)f2bf(acc[1] * z[1]) << 16);
  o.y = (unsigned int)f2bf(acc[2] * z[2]) | ((unsigned int)f2bf(acc[3] * z[3]) << 16);
  o.z = (unsigned int)f2bf(acc[4] * z[4]) | ((unsigned int)f2bf(acc[5] * z[5]) << 16);
  o.w = (unsigned int)f2bf(acc[6] * z[6]) | ((unsigned int)f2bf(acc[7] * z[7]) << 16);
  *(uint4*)(ygz + i) = o;
}

// ---------------- host ----------------
extern "C" void kernel_launch(void* const* d_in, const int* in_sizes, int n_in,
                              void* d_out, int out_size, void* d_ws, size_t ws_size,
                              hipStream_t stream) {
  (void)in_sizes; (void)n_in; (void)out_size; (void)ws_size;
  const float* content   = (const float*)d_in[0];
  const float* style     = (const float*)d_in[1];
  const float* norm1_w   = (const float*)d_in[2];
  const float* norm1_b   = (const float*)d_in[3];
  const float* in_proj_w = (const float*)d_in[4];
  const float* conv_w    = (const float*)d_in[5];
  const float* conv_b    = (const float*)d_in[6];
  const float* style_proj_w   = (const float*)d_in[7];
  const float* content_proj_w = (const float*)d_in[8];
  const float* dtw       = (const float*)d_in[9];
  const float* dtb       = (const float*)d_in[10];
  const float* A_logs    = (const float*)d_in[11];
  const float* Ds        = (const float*)d_in[12];
  const float* out_proj_w = (const float*)d_in[13];
  const float* norm2_w   = (const float*)d_in[14];
  const float* norm2_b   = (const float*)d_in[15];
  const float* mlp_w1    = (const float*)d_in[16];
  const float* mlp_b1    = (const float*)d_in[17];
  const float* mlp_w2    = (const float*)d_in[18];
  const float* mlp_b2    = (const float*)d_in[19];
  float* out = (float*)d_out;

  float* ws = (float*)d_ws;
  const size_t ROWS = (size_t)B_ * L_;
  const size_t SCAN_ELEMS = (size_t)B_ * K_ * L_ * DI_;
  size_t o = 0;
  unsigned short* cn  = (unsigned short*)(ws + o); o += ROWS * HID_ / 2;
  unsigned short* sn  = (unsigned short*)(ws + o); o += ROWS * HID_ / 2;
  unsigned short* xn  = (unsigned short*)(ws + o); o += ROWS * HID_ / 2;
  unsigned short* xz  = (unsigned short*)(ws + o); o += ROWS * 2 * DI_ / 2;
  unsigned short* sp  = (unsigned short*)(ws + o); o += ROWS * 384 / 2;   // bf16
  unsigned short* xa  = (unsigned short*)(ws + o); o += ROWS * DI_ / 2;
  unsigned short* csb = (unsigned short*)(ws + o); o += ROWS * 256 / 2;   // bf16
  float* x1    = ws + o; o += ROWS * HID_;
  unsigned short* dltb = (unsigned short*)(ws + o); o += SCAN_ELEMS / 2;
  unsigned short* ybuf = (unsigned short*)(ws + o); o += SCAN_ELEMS / 2;
  unsigned short* ygz  = (unsigned short*)(ws + o); o += ROWS * DI_ / 2;
  unsigned short* wt = (unsigned short*)(ws + o);
  unsigned short* inpT = wt;
  unsigned short* styT = inpT + 2048 * 512;
  unsigned short* conT = styT + 384 * 512;
  unsigned short* outT = conT + 256 * 1024;
  unsigned short* w1T  = outT + 512 * 1024;
  unsigned short* w2T  = w1T + 2048 * 512;
  unsigned short* dtwB = w2T + 512 * 2048;   // (K*DI, 32) bf16
  unsigned short* hmid = ybuf;

  transpose_all<<<4032, 256, 0, stream>>>(
      in_proj_w, style_proj_w, content_proj_w, out_proj_w, mlp_w1, mlp_w2,
      inpT, styT, conT, outT, w1T, w2T);
  cast_bf<<<(K_ * DI_ * R_) / 1024, 256, 0, stream>>>(dtw, dtwB);

  ln_kernel<<<dim3(ROWS / 4, 2), 256, 0, stream>>>(content, cn, style, sn, norm1_w, norm1_b);

  gemm_kernel<0, 1><<<dim3(2048 / BN, ROWS / BM), 256, 0, stream>>>(
      cn, inpT, xz, ROWS, 2048, 512, nullptr, nullptr);
  gemm64_kernel<0, 1><<<dim3(384 / BN, ROWS / 64), 256, 0, stream>>>(
      sn, styT, sp, ROWS, 384, 512, nullptr, nullptr);
  conv_kernel<<<(ROWS * DI_) / 256, 256, 0, stream>>>(xz, conv_w, conv_b, xa);
  gemm64_kernel<0, 1><<<dim3(256 / BN, ROWS / 64), 256, 0, stream>>>(
      xa, conT, csb, ROWS, 256, 1024, nullptr, nullptr);
  dtgemm_kernel<<<dim3(DI_ / 128, ROWS / 64, K_), 256, 0, stream>>>(sp, dtwB, dtb, dltb);
  scan_kernel<<<dim3(DI_ / 64, K_, B_), 512, 0, stream>>>(
      ybuf, xa, sp, csb, dltb, A_logs, Ds);
  fuse_ygz<<<(ROWS * DI_) / (256 * 8), 256, 0, stream>>>(ybuf, xz, ygz);
  gemm64_kernel<1, 0><<<dim3(512 / BN, ROWS / 64), 256, 0, stream>>>(
      ygz, outT, x1, ROWS, 512, 1024, nullptr, content);
  ln_kernel<<<dim3(ROWS / 4, 1), 256, 0, stream>>>(x1, xn, nullptr, nullptr, norm2_w, norm2_b);
  gemm_kernel<2, 1><<<dim3(2048 / BN, ROWS / BM), 256, 0, stream>>>(
      xn, w1T, hmid, ROWS, 2048, 512, mlp_b1, nullptr);
  gemm64_kernel<3, 0><<<dim3(512 / BN, ROWS / 64), 256, 0, stream>>>(
      hmid, w2T, out, ROWS, 512, 2048, mlp_b2, x1);
}